// Round 1
// 3739.787 us; speedup vs baseline: 1.3359x; 1.3359x over previous
//
#include <hip/hip_runtime.h>
#include <hip/hip_bf16.h>

using bf = __hip_bfloat16;

#define B_   16
#define L_   12
#define N_   358
#define D_   152
#define TOK_ (B_*L_*N_)   /* 68736 */
#define FF_  256
#define HD_  38
#define SCALE_ 0.16222142113076254f  /* 38^-0.5 */

__device__ __forceinline__ float bf2f(bf x) { return __bfloat162float(x); }
__device__ __forceinline__ bf f2bf(float f) { return __float2bfloat16(f); }
__device__ __forceinline__ float lo_bf(unsigned u) { return __uint_as_float(u << 16); }
__device__ __forceinline__ float hi_bf(unsigned u) { return __uint_as_float(u & 0xffff0000u); }
__device__ __forceinline__ float us2f(ushort u) { return __uint_as_float((unsigned)u << 16); }
__device__ __forceinline__ unsigned pk_bf(float a, float b) {
  union { bf h; unsigned short u; } A, Bu;
  A.h = f2bf(a); Bu.h = f2bf(b);
  return ((unsigned)Bu.u << 16) | A.u;
}
__device__ __forceinline__ ushort f2bf_u(float f) {
  union { bf h; ushort u; } t; t.h = f2bf(f); return t.u;
}

using short8  = __attribute__((ext_vector_type(8))) short;
using float4v = __attribute__((ext_vector_type(4))) float;

/* 16B logical load from a 4B-aligned (not necessarily 16B-aligned) address */
__device__ __forceinline__ short8 ld_g8(const ushort* p) {
  union { unsigned u[4]; short8 v; } t;
  t.u[0] = *(const unsigned*)(p);
  t.u[1] = *(const unsigned*)(p + 2);
  t.u[2] = *(const unsigned*)(p + 4);
  t.u[3] = *(const unsigned*)(p + 6);
  return t.v;
}

__device__ __forceinline__ float redmax16(float x) {
  x = fmaxf(x, __shfl_xor(x, 1, 64));
  x = fmaxf(x, __shfl_xor(x, 2, 64));
  x = fmaxf(x, __shfl_xor(x, 4, 64));
  x = fmaxf(x, __shfl_xor(x, 8, 64));
  return x;
}
__device__ __forceinline__ float redsum16(float x) {
  x += __shfl_xor(x, 1, 64);
  x += __shfl_xor(x, 2, 64);
  x += __shfl_xor(x, 4, 64);
  x += __shfl_xor(x, 8, 64);
  return x;
}

/* ------------------------------------------------------------------ */
__global__ void k_beacon(float* out, int n, float val) {
  int i = blockIdx.x * 256 + threadIdx.x;
  if (i < n) out[i] = val;
}

/* ------------------------------------------------------------------ */
/* Embed: x[b,l,n,:] = [x_in@W_in+b_in | tod_emb | dow_emb | adaptive] */
__global__ __launch_bounds__(256) void k_embed2(
    const float* __restrict__ var_x, const float* __restrict__ marker,
    const float* __restrict__ W_in, const float* __restrict__ b_in,
    const float* __restrict__ tod_emb, const float* __restrict__ dow_emb,
    const float* __restrict__ adap, bf* __restrict__ x) {
  int t = blockIdx.x * 256 + threadIdx.x;
  if (t >= TOK_) return;
  int n = t % N_;
  int l = (t / N_) % L_;
  float var = var_x[t];
  float m0 = marker[t*4 + 0];
  float m1 = marker[t*4 + 1];
  int tod = (int)(m0 * 144.f); tod = tod < 0 ? 0 : (tod > 143 ? 143 : tod);
  int dw  = (int)(m1 * 7.f);   dw  = dw  < 0 ? 0 : (dw  > 6   ? 6   : dw);
  bf* xp = x + (long)t * D_;
  for (int d = 0; d < 24; ++d)
    xp[d] = f2bf(var * W_in[d] + m0 * W_in[24 + d] + m1 * W_in[48 + d] + b_in[d]);
  for (int d = 0; d < 24; ++d) xp[24 + d] = f2bf(tod_emb[tod*24 + d]);
  for (int d = 0; d < 24; ++d) xp[48 + d] = f2bf(dow_emb[dw*24 + d]);
  for (int d = 0; d < 80; ++d) xp[72 + d] = f2bf(adap[(l*N_ + n)*80 + d]);
}

/* ------------------------------------------------------------------ */
/* GEMM v5 (MFMA): Y = f(X @ W + bias [+Res -> LayerNorm]).
   64 tokens/block, 4 waves; wave w owns token rows 16w..16w+15.
   mfma_f32_16x16x32_bf16 per 16-col tile per 32-k chunk.
   A-frag: lane l -> row (l&15), k = kc + 8*(l>>4)+e  (b128 from Xs)
   B-frag: lane l -> col (l&15), k = kc + 8*(l>>4)+e  (b128 from Wt[d][k])
   C/D:    lane l -> col (l&15), row = 4*(l>>4)+reg   (m89-verified)  */
template<int K, int Nd, bool RELU, bool LN>
__global__ __launch_bounds__(256) void k_gemm5(
    const bf* __restrict__ X, const float* __restrict__ W,
    const float* __restrict__ bias, const bf* __restrict__ Res,
    const float* __restrict__ g, const float* __restrict__ bb,
    bf* __restrict__ Y) {
  constexpr int NJ  = (Nd + 15) / 16;
  constexpr int NdP = NJ * 16;
  constexpr int KC  = (K + 31) / 32;
  constexpr int KX  = KC * 32;
  constexpr int XSTR = KX + 8;     /* ushort stride; bytes % 16 == 0 */
  __shared__ ushort Xs[64 * XSTR];
  __shared__ ushort Wt[NdP * 40];  /* 40-ushort rows: b128 reads 2-way-free */
  long row0 = (long)blockIdx.x * 64;
  int tid = threadIdx.x;
  /* stage X (coalesced uint reads of bf16 rows) */
  const unsigned* Xg = (const unsigned*)(X + row0 * K);
  for (int i = tid; i < 64*(K/2); i += 256) {
    int r = i / (K/2), cp = i % (K/2);
    *(unsigned*)&Xs[r*XSTR + 2*cp] = Xg[i];
  }
  if (KX > K) {
    constexpr int TU = (KX - K) / 2;
    for (int i = tid; i < 64*TU; i += 256) {
      int r = i / TU, u = i % TU;
      *(unsigned*)&Xs[r*XSTR + K + 2*u] = 0u;
    }
  }
  int lane = tid & 63, w = tid >> 6;
  int cl = lane & 15, gr = lane >> 4;
  float4v acc[NJ];
#pragma unroll
  for (int j = 0; j < NJ; ++j) acc[j] = (float4v){0.f, 0.f, 0.f, 0.f};
  for (int kc = 0; kc < K; kc += 32) {
    int kcn = K - kc; if (kcn > 32) kcn = 32;
    __syncthreads();                 /* Xs ready (1st) / Wt reuse safe */
    /* stage W chunk transposed+bf16: Wt[d][k], k-major writes (no conflicts) */
    for (int e = tid; e < NdP*16; e += 256) {
      int d = e >> 4, ku = e & 15;
      int k0 = 2*ku, k1 = k0 + 1;
      float w0 = (d < Nd && k0 < kcn) ? W[(long)(kc + k0)*Nd + d] : 0.f;
      float w1 = (d < Nd && k1 < kcn) ? W[(long)(kc + k1)*Nd + d] : 0.f;
      *(unsigned*)&Wt[d*40 + 2*ku] = pk_bf(w0, w1);
    }
    __syncthreads();
    short8 af = *(const short8*)&Xs[(16*w + cl)*XSTR + kc + 8*gr];
#pragma unroll
    for (int j = 0; j < NJ; ++j) {
      short8 bfv = *(const short8*)&Wt[(16*j + cl)*40 + 8*gr];
      acc[j] = __builtin_amdgcn_mfma_f32_16x16x32_bf16(af, bfv, acc[j], 0, 0, 0);
    }
  }
  int rowb = 16*w + 4*gr;            /* + r gives row within block */
  if constexpr (!LN) {
#pragma unroll
    for (int j = 0; j < NJ; ++j) {
      int d = 16*j + cl;
      if (d < Nd) {
        float bv = bias[d];
#pragma unroll
        for (int r = 0; r < 4; ++r) {
          float val = acc[j][r] + bv;
          if (RELU) val = fmaxf(val, 0.f);
          Y[(row0 + rowb + r) * Nd + d] = f2bf(val);
        }
      }
    }
  } else {
    /* fused residual + LayerNorm; rows 4gr..4gr+3 of this wave's stripe */
#pragma unroll
    for (int j = 0; j < NJ; ++j) {
      int d = 16*j + cl;
      if (d < Nd) {
        float bv = bias[d];
#pragma unroll
        for (int r = 0; r < 4; ++r)
          acc[j][r] += bv + bf2f(Res[(row0 + rowb + r) * Nd + d]);
      }
    }
#pragma unroll
    for (int r = 0; r < 4; ++r) {
      float s = 0.f;
#pragma unroll
      for (int j = 0; j < NJ; ++j)
        if (16*j + cl < Nd) s += acc[j][r];
      s += __shfl_xor(s, 1, 64); s += __shfl_xor(s, 2, 64);
      s += __shfl_xor(s, 4, 64); s += __shfl_xor(s, 8, 64);
      float mean = s / (float)Nd;
      float s2 = 0.f;
#pragma unroll
      for (int j = 0; j < NJ; ++j)
        if (16*j + cl < Nd) { float dv = acc[j][r] - mean; s2 += dv*dv; }
      s2 += __shfl_xor(s2, 1, 64); s2 += __shfl_xor(s2, 2, 64);
      s2 += __shfl_xor(s2, 4, 64); s2 += __shfl_xor(s2, 8, 64);
      float rs = rsqrtf(s2 / (float)Nd + 1e-5f);
#pragma unroll
      for (int j = 0; j < NJ; ++j) {
        int d = 16*j + cl;
        if (d < Nd)
          Y[(row0 + rowb + r) * Nd + d] =
              f2bf((acc[j][r] - mean) * rs * g[d] + bb[d]);
      }
    }
  }
}

/* ------------------------------------------------------------------ */
/* Temporal attention: block per (b,n); S=12; all 4 heads; LDS tiles. */
__global__ __launch_bounds__(256) void k_attn_t(
    const bf* __restrict__ q, const bf* __restrict__ kk,
    const bf* __restrict__ v, bf* __restrict__ a) {
  int s = blockIdx.x; int b = s / N_; int n = s % N_;
  __shared__ float Qs[12][152], Ks[12][152], Vs[12][152];
  __shared__ float Sc[4][12][12];
  int tid = threadIdx.x;
  for (int i = tid; i < 12*152; i += 256) {
    int l = i / 152, d = i % 152;
    long tok = ((long)(b*L_ + l) * N_ + n) * 152 + d;
    Qs[l][d] = bf2f(q[tok]); Ks[l][d] = bf2f(kk[tok]); Vs[l][d] = bf2f(v[tok]);
  }
  __syncthreads();
  for (int e = tid; e < 576; e += 256) {
    int hh = e / 144, r = e % 144, qi = r / 12, kj = r % 12;
    float sc = 0.f;
#pragma unroll
    for (int d = 0; d < HD_; ++d) sc += Qs[qi][hh*HD_ + d] * Ks[kj][hh*HD_ + d];
    Sc[hh][qi][kj] = sc * SCALE_;
  }
  __syncthreads();
  if (tid < 48) {
    int hh = tid / 12, qi = tid % 12;
    float m = Sc[hh][qi][0];
    for (int j = 1; j < 12; ++j) m = fmaxf(m, Sc[hh][qi][j]);
    float sum = 0.f;
    for (int j = 0; j < 12; ++j) {
      float p = __expf(Sc[hh][qi][j] - m);
      Sc[hh][qi][j] = p; sum += p;
    }
    float inv = 1.f / sum;
    for (int j = 0; j < 12; ++j) Sc[hh][qi][j] *= inv;
  }
  __syncthreads();
  for (int e = tid; e < 12*152; e += 256) {
    int qi = e / 152, dd = e % 152, hh = dd / HD_;
    float o = 0.f;
#pragma unroll
    for (int j = 0; j < 12; ++j) o += Sc[hh][qi][j] * Vs[j][dd];
    a[((long)(b*L_ + qi) * N_ + n) * 152 + dd] = f2bf(o);
  }
}

/* ------------------------------------------------------------------ */
/* Spatial attention v4: MFMA flash. Block per (b,l,h); 4 waves.
   Ks[368][40] bf16 row-major (cols 38..39 + rows 358..367 zeroed):
     QK B-frag = short8 at Ks[key][kc+8*gr]; kc=32 chunk valid only gr==0.
   Vt[38][392] = V transposed (keys 358..383 zeroed):
     PV B-frag = short8 at Vt[16*dt+cl][k0+8*gr]; rows>=38 masked to 0 in regs.
   Pb[w][16][40]: per-wave P tile (bf16); re-read as PV A-frag (row=q, k=key).
   Fragment layouts identical to k_gemm5 (m89-verified). No inner barriers. */
__global__ __launch_bounds__(256) void k_attn_s4(
    const ushort* __restrict__ qg, const ushort* __restrict__ kg,
    const ushort* __restrict__ vg, bf* __restrict__ a) {
  int id = blockIdx.x; int h = id & 3; int s = id >> 2;
  int b = s / L_; int l = s % L_;
  long base = (long)(b*L_ + l) * N_;
  __shared__ ushort Ks[368][40];      /* 29440 B */
  __shared__ ushort Vt[38][392];      /* 29792 B */
  __shared__ ushort Pb[4][16][40];    /*  5120 B -> 64352 total */
  int tid = threadIdx.x;
  /* stage K row-major, zero-padded */
  for (int i = tid; i < 368*20; i += 256) {
    int j = i / 20, t2 = i % 20;
    unsigned u = 0u;
    if (j < N_ && t2 < 19)
      u = *(const unsigned*)(kg + (base + j)*D_ + h*HD_ + 2*t2);
    *(unsigned*)&Ks[j][2*t2] = u;
  }
  /* stage V transposed */
  for (int i = tid; i < N_*19; i += 256) {
    int j = i / 19, t2 = i % 19;
    unsigned u = *(const unsigned*)(vg + (base + j)*D_ + h*HD_ + 2*t2);
    Vt[2*t2][j]     = (ushort)(u & 0xffffu);
    Vt[2*t2 + 1][j] = (ushort)(u >> 16);
  }
  for (int i = tid; i < 38*26; i += 256)
    Vt[i / 26][N_ + i % 26] = 0;
  __syncthreads();

  int lane = tid & 63, w = tid >> 6;
  int cl = lane & 15, gr = lane >> 4;
  bool g0 = (gr == 0);
  const short8 z8 = {0,0,0,0,0,0,0,0};

  for (int qt = w; qt < 23; qt += 4) {
    const ushort* qp = qg + (base + 16*qt + cl) * D_ + h*HD_;
    short8 qA0 = ld_g8(qp + 8*gr);        /* k = 8gr..8gr+7   */
    short8 qA1 = ld_g8(qp + 32 + 8*gr);   /* k = 32+8gr..  (tail; B side zeroed) */
    float m_[4]   = {-1e30f, -1e30f, -1e30f, -1e30f};
    float sum_[4] = {0.f, 0.f, 0.f, 0.f};
    float4v accO[3];
    accO[0] = (float4v){0,0,0,0};
    accO[1] = (float4v){0,0,0,0};
    accO[2] = (float4v){0,0,0,0};
#pragma unroll 1
    for (int pr = 0; pr < 12; ++pr) {
      int k0 = 32*pr;
      int kr0 = k0 + cl;
      int kr1 = k0 + 16 + cl; if (kr1 > 367) kr1 = 367;
      float4v s0a = (float4v){0,0,0,0}, s1a = (float4v){0,0,0,0};
      {
        short8 b00 = *(const short8*)&Ks[kr0][8*gr];
        short8 b10 = *(const short8*)&Ks[kr1][8*gr];
        s0a = __builtin_amdgcn_mfma_f32_16x16x32_bf16(qA0, b00, s0a, 0, 0, 0);
        s1a = __builtin_amdgcn_mfma_f32_16x16x32_bf16(qA0, b10, s1a, 0, 0, 0);
        short8 b01 = g0 ? *(const short8*)&Ks[kr0][32] : z8;
        short8 b11 = g0 ? *(const short8*)&Ks[kr1][32] : z8;
        s0a = __builtin_amdgcn_mfma_f32_16x16x32_bf16(qA1, b01, s0a, 0, 0, 0);
        s1a = __builtin_amdgcn_mfma_f32_16x16x32_bf16(qA1, b11, s1a, 0, 0, 0);
      }
      bool v0k = (k0 + cl) < N_;
      bool v1k = (k0 + 16 + cl) < N_;
      float p0[4], p1[4], fac[4];
#pragma unroll
      for (int r = 0; r < 4; ++r) {
        float x0 = v0k ? s0a[r]*SCALE_ : -1e30f;
        float x1 = v1k ? s1a[r]*SCALE_ : -1e30f;
        float t = fmaxf(x0, x1);
        t = redmax16(t);
        float mn = fmaxf(m_[r], t);
        fac[r] = __expf(m_[r] - mn);
        m_[r] = mn;
        p0[r] = __expf(x0 - mn);
        p1[r] = __expf(x1 - mn);
        float ts = redsum16(p0[r] + p1[r]);
        sum_[r] = sum_[r]*fac[r] + ts;
      }
#pragma unroll
      for (int dt = 0; dt < 3; ++dt)
#pragma unroll
        for (int r = 0; r < 4; ++r) accO[dt][r] *= fac[r];
      /* stage P tile (bf16) for PV A-frag */
#pragma unroll
      for (int r = 0; r < 4; ++r) {
        Pb[w][4*gr + r][cl]      = f2bf_u(p0[r]);
        Pb[w][4*gr + r][16 + cl] = f2bf_u(p1[r]);
      }
      __asm__ volatile("s_waitcnt lgkmcnt(0)" ::: "memory");
      __builtin_amdgcn_sched_barrier(0);
      short8 aP = *(const short8*)&Pb[w][cl][8*gr];
#pragma unroll
      for (int dt = 0; dt < 3; ++dt) {
        short8 bV = (dt < 2 || cl < 6)
            ? *(const short8*)&Vt[16*dt + cl][k0 + 8*gr] : z8;
        accO[dt] = __builtin_amdgcn_mfma_f32_16x16x32_bf16(aP, bV, accO[dt], 0, 0, 0);
      }
    }
#pragma unroll
    for (int r = 0; r < 4; ++r) {
      int qi = 16*qt + 4*gr + r;
      if (qi < N_) {
        float inv = 1.f / sum_[r];
        bf* ap = a + (base + qi)*D_ + h*HD_;
#pragma unroll
        for (int dt = 0; dt < 3; ++dt) {
          int d = 16*dt + cl;
          if (d < HD_) ap[d] = f2bf(accO[dt][r] * inv);
        }
      }
    }
  }
}

/* ------------------------------------------------------------------ */
/* wcomb[r][p] = W_mm[(l*408+256+d)][p] + W_ts[r][p];
   wevtsum[e][p] = sum_l W_mm[l*408+e][p]                              */
__global__ __launch_bounds__(256) void k_wcomb(
    const float* __restrict__ W_mm, const float* __restrict__ W_ts,
    float* __restrict__ wcomb, float* __restrict__ wevtsum) {
  int i = blockIdx.x * 256 + threadIdx.x;
  if (i < 1824*12) {
    int r = i / 12, p = i % 12, l = r / 152, d = r % 152;
    wcomb[i] = W_mm[(l*408 + 256 + d)*12 + p] + W_ts[i];
  }
  if (i < 256*12) {
    int e = i / 12, p = i % 12;
    float s = 0.f;
    for (int l = 0; l < 12; ++l) s += W_mm[(l*408 + e)*12 + p];
    wevtsum[i] = s;
  }
}

/* ------------------------------------------------------------------ */
__global__ __launch_bounds__(256) void k_evt1(
    const float* __restrict__ marker, const int* __restrict__ doy_idx,
    const float* __restrict__ emb, const float* __restrict__ W_evt,
    const float* __restrict__ b_evt, float* __restrict__ evt_h) {
  int bk = blockIdx.x; int b = bk >> 3; int ks = bk & 7;
  float m3 = marker[((b*L_ + (L_-1))*N_ + 0)*4 + 3];
  int doy = (int)(m3 * 365.f); doy = doy < 0 ? 0 : (doy > 365 ? 365 : doy);
  int idx = doy_idx[doy*8 + ks];
  if (idx < 0 || idx > 4096) idx = 0;
  int d = threadIdx.x;
  float acc = b_evt[d];
  const float* er = emb + (long)idx * 1024;
  for (int e = 0; e < 1024; ++e)
    acc += er[e] * W_evt[e*256 + d];
  evt_h[bk*256 + d] = acc;
}

/* ------------------------------------------------------------------ */
__global__ __launch_bounds__(256) void k_evtpool(
    const float* __restrict__ marker, const void* __restrict__ doy_mask,
    const float* __restrict__ evt_h, float* __restrict__ evtp) {
  __shared__ int hasF32, hasBig;
  if (threadIdx.x == 0) { hasF32 = 0; hasBig = 0; }
  __syncthreads();
  const unsigned* mw = (const unsigned*)doy_mask;
  for (int w = threadIdx.x; w < 732; w += 256) {
    unsigned u = mw[w];
    if (u == 0x3F800000u) hasF32 = 1;
    else if (u > 1u) hasBig = 1;
  }
  __syncthreads();
  int fmt = hasF32 ? 2 : (hasBig ? 1 : 0);
  int b = blockIdx.x;
  float m3 = marker[((b*L_ + (L_-1))*N_ + 0)*4 + 3];
  int doy = (int)(m3 * 365.f); doy = doy < 0 ? 0 : (doy > 365 ? 365 : doy);
  int j = threadIdx.x;
  float mx = -1e30f;
  for (int kx = 0; kx < 8; ++kx) {
    bool mk;
    if (fmt == 2)      mk = ((const float*)doy_mask)[doy*8 + kx] != 0.f;
    else if (fmt == 1) mk = ((const unsigned char*)doy_mask)[doy*8 + kx] != 0;
    else               mk = ((const int*)doy_mask)[doy*8 + kx] != 0;
    if (mk) mx = fmaxf(mx, evt_h[(b*8 + kx)*256 + j]);
  }
  evtp[b*256 + j] = mx;
}

/* ------------------------------------------------------------------ */
/* Final: block per (b,n); x[b,:,n,:] staged in LDS; 16x12 partials.  */
__global__ __launch_bounds__(192) void k_final3(
    const bf* __restrict__ x, const float* __restrict__ wcomb,
    const float* __restrict__ wevtsum, const float* __restrict__ evtp,
    const float* __restrict__ b_mm, const float* __restrict__ b_ts,
    float* __restrict__ out) {
  int id = blockIdx.x; int b = id / N_; int n = id % N_;
  __shared__ float xs[1824];
  __shared__ float part[16][12];
  int tid = threadIdx.x;
  for (int e = tid; e < 1824; e += 192) {
    int l = e / 152, d = e % 152;
    xs[e] = bf2f(x[((long)(b*L_ + l) * N_ + n) * 152 + d]);
  }
  __syncthreads();
  int g2 = tid / 12, p = tid % 12;
  float acc = 0.f;
  for (int e = g2; e < 1824; e += 16)
    acc += xs[e] * wcomb[e*12 + p];
  part[g2][p] = acc;
  __syncthreads();
  if (tid < 12) {
    float s = b_mm[tid] + b_ts[tid];
    for (int e = 0; e < 256; ++e) s += evtp[b*256 + e] * wevtsum[e*12 + tid];
    for (int gg = 0; gg < 16; ++gg) s += part[gg][tid];
    out[(b*12 + tid) * N_ + n] = s;
  }
}

/* ------------------------------------------------------------------ */
extern "C" void kernel_launch(void* const* d_in, const int* in_sizes, int n_in,
                              void* d_out, int out_size, void* d_ws, size_t ws_size,
                              hipStream_t stream) {
  static const int expect[32] = {
    68736, 274944, 72, 24, 3456, 168, 343680,
    138624, 912, 138624, 912, 138624, 912, 138624, 912,
    233472, 1536, 233472, 912,
    912, 912, 912, 912,
    4195328, 262144, 256,
    58752, 12, 21888, 12,
    2928, 2928 };
  int nb = (out_size + 255)/256;
  if (n_in != 32) {
    k_beacon<<<nb, 256, 0, stream>>>((float*)d_out, out_size, 998.f);
    return;
  }
  for (int i = 0; i < 32; ++i) {
    if (in_sizes[i] != expect[i]) {
      k_beacon<<<nb, 256, 0, stream>>>((float*)d_out, out_size, 1000.f + i);
      return;
    }
  }
  if (out_size != 68736) {
    k_beacon<<<nb, 256, 0, stream>>>((float*)d_out, out_size, 997.f);
    return;
  }

  const float* var_x  = (const float*)d_in[0];
  const float* marker = (const float*)d_in[1];
  const float* W_in   = (const float*)d_in[2];
  const float* b_in   = (const float*)d_in[3];
  const float* tod    = (const float*)d_in[4];
  const float* dow    = (const float*)d_in[5];
  const float* adap   = (const float*)d_in[6];
  const float* Wq = (const float*)d_in[7];  const float* bq = (const float*)d_in[8];
  const float* Wk = (const float*)d_in[9];  const float* bk = (const float*)d_in[10];
  const float* Wv = (const float*)d_in[11]; const float* bv = (const float*)d_in[12];
  const float* Wo = (const float*)d_in[13]; const float* bo = (const float*)d_in[14];
  const float* W1 = (const float*)d_in[15]; const float* b1 = (const float*)d_in[16];
  const float* W2 = (const float*)d_in[17]; const float* b2 = (const float*)d_in[18];
  const float* g1 = (const float*)d_in[19]; const float* be1 = (const float*)d_in[20];
  const float* g2 = (const float*)d_in[21]; const float* be2 = (const float*)d_in[22];
  const float* emb   = (const float*)d_in[23];
  const float* W_evt = (const float*)d_in[24]; const float* b_evt = (const float*)d_in[25];
  const float* W_mm  = (const float*)d_in[26]; const float* b_mm  = (const float*)d_in[27];
  const float* W_ts  = (const float*)d_in[28]; const float* b_ts  = (const float*)d_in[29];
  const int* doyi = (const int*)d_in[30];
  const void* doym = d_in[31];

  const long TD = (long)TOK_ * D_;
  size_t need = (size_t)TD * 2 * 5 + (size_t)(32768 + 4096 + 3072 + 21888) * 4 + 4096;
  if (ws_size < need) {
    k_beacon<<<nb, 256, 0, stream>>>((float*)d_out, out_size, (float)(ws_size >> 20));
    return;
  }

  bf* x = (bf*)d_ws;
  bf* q = x + TD;
  bf* k = q + TD;
  bf* v = k + TD;
  bf* a = v + TD;
  float* evt_h   = (float*)(a + TD);
  float* evtp    = evt_h + 32768;
  float* wevtsum = evtp + 4096;
  float* wcomb   = wevtsum + 3072;

  k_embed2<<<(TOK_ + 255)/256, 256, 0, stream>>>(var_x, marker, W_in, b_in,
                                                 tod, dow, adap, x);
  for (int i = 0; i < 6; ++i) {
    const float *Wqi = Wq + i*23104, *Wki = Wk + i*23104,
                *Wvi = Wv + i*23104, *Woi = Wo + i*23104;
    const float *W1i = W1 + i*38912, *W2i = W2 + i*38912;
    k_gemm5<152,152,false,false><<<TOK_/64, 256, 0, stream>>>(
        x, Wqi, bq + i*152, nullptr, nullptr, nullptr, q);
    k_gemm5<152,152,false,false><<<TOK_/64, 256, 0, stream>>>(
        x, Wki, bk + i*152, nullptr, nullptr, nullptr, k);
    k_gemm5<152,152,false,false><<<TOK_/64, 256, 0, stream>>>(
        x, Wvi, bv + i*152, nullptr, nullptr, nullptr, v);
    if (i < 3)
      k_attn_t<<<B_*N_, 256, 0, stream>>>(q, k, v, a);
    else
      k_attn_s4<<<B_*L_*4, 256, 0, stream>>>(
          (const ushort*)q, (const ushort*)k, (const ushort*)v, a);
    /* o-proj + residual(x) + LN1 -> k (h) */
    k_gemm5<152,152,false,true><<<TOK_/64, 256, 0, stream>>>(
        a, Woi, bo + i*152, x, g1 + i*152, be1 + i*152, k);
    /* FF1 (ReLU): k -> v */
    k_gemm5<152,256,true,false><<<TOK_/64, 256, 0, stream>>>(
        k, W1i, b1 + i*256, nullptr, nullptr, nullptr, v);
    /* FF2 + residual(h=k) + LN2 -> x */
    k_gemm5<256,152,false,true><<<TOK_/64, 256, 0, stream>>>(
        v, W2i, b2 + i*152, k, g2 + i*152, be2 + i*152, x);
  }
  k_evt1<<<16*8, 256, 0, stream>>>(marker, doyi, emb, W_evt, b_evt, evt_h);
  k_evtpool<<<16, 256, 0, stream>>>(marker, doym, evt_h, evtp);
  k_wcomb<<<(1824*12 + 255)/256, 256, 0, stream>>>(W_mm, W_ts, wcomb, wevtsum);
  k_final3<<<B_*N_, 192, 0, stream>>>(x, wcomb, wevtsum, evtp, b_mm, b_ts,
                                      (float*)d_out);
}

// Round 2
// 1706.664 us; speedup vs baseline: 2.9273x; 2.1913x over previous
//
#include <hip/hip_runtime.h>
#include <hip/hip_bf16.h>

using bf = __hip_bfloat16;

#define B_   16
#define L_   12
#define N_   358
#define D_   152
#define TOK_ (B_*L_*N_)   /* 68736 */
#define FF_  256
#define HD_  38
#define SCALE_ 0.16222142113076254f  /* 38^-0.5 */

__device__ __forceinline__ float bf2f(bf x) { return __bfloat162float(x); }
__device__ __forceinline__ bf f2bf(float f) { return __float2bfloat16(f); }
__device__ __forceinline__ float lo_bf(unsigned u) { return __uint_as_float(u << 16); }
__device__ __forceinline__ float hi_bf(unsigned u) { return __uint_as_float(u & 0xffff0000u); }
__device__ __forceinline__ unsigned pk_bf(float a, float b) {
  union { bf h; unsigned short u; } A, Bu;
  A.h = f2bf(a); Bu.h = f2bf(b);
  return ((unsigned)Bu.u << 16) | A.u;
}
__device__ __forceinline__ ushort f2bf_u(float f) {
  union { bf h; ushort u; } t; t.h = f2bf(f); return t.u;
}

using short8  = __attribute__((ext_vector_type(8))) short;
using float4v = __attribute__((ext_vector_type(4))) float;

/* async global->LDS, 16B per lane; dst is wave-uniform base (HW adds lane*16) */
__device__ __forceinline__ void gl_lds16(const void* g, void* l) {
  __builtin_amdgcn_global_load_lds(
      (const __attribute__((address_space(1))) void*)g,
      (__attribute__((address_space(3))) void*)l, 16, 0, 0);
}

/* copy SUBCB bytes (chunk image) global->LDS; 4 waves interleave 1024B blocks */
template<int SUBCB>
__device__ __forceinline__ void issue_w(const char* gsrc, ushort* lds, int w, int lane) {
  constexpr int TB = SUBCB >> 10;
  constexpr int TAIL = SUBCB & 1023;   /* 0 or 512 */
#pragma unroll
  for (int blk0 = 0; blk0 < TB; blk0 += 4) {
    int blk = blk0 + w;
    if (blk < TB)
      gl_lds16(gsrc + blk*1024 + (size_t)lane*16, (char*)lds + blk*1024);
  }
  if (TAIL) {
    if (w == (TB & 3) && lane < 32)
      gl_lds16(gsrc + TB*1024 + (size_t)lane*16, (char*)lds + TB*1024);
  }
}

/* 16B logical load from a 4B-aligned (not necessarily 16B-aligned) address */
__device__ __forceinline__ short8 ld_g8(const ushort* p) {
  union { unsigned u[4]; short8 v; } t;
  t.u[0] = *(const unsigned*)(p);
  t.u[1] = *(const unsigned*)(p + 2);
  t.u[2] = *(const unsigned*)(p + 4);
  t.u[3] = *(const unsigned*)(p + 6);
  return t.v;
}

__device__ __forceinline__ float redmax16(float x) {
  x = fmaxf(x, __shfl_xor(x, 1, 64));
  x = fmaxf(x, __shfl_xor(x, 2, 64));
  x = fmaxf(x, __shfl_xor(x, 4, 64));
  x = fmaxf(x, __shfl_xor(x, 8, 64));
  return x;
}
__device__ __forceinline__ float redsum16(float x) {
  x += __shfl_xor(x, 1, 64);
  x += __shfl_xor(x, 2, 64);
  x += __shfl_xor(x, 4, 64);
  x += __shfl_xor(x, 8, 64);
  return x;
}

/* ------------------------------------------------------------------ */
__global__ void k_beacon(float* out, int n, float val) {
  int i = blockIdx.x * 256 + threadIdx.x;
  if (i < n) out[i] = val;
}

/* ------------------------------------------------------------------ */
/* Embed: x[b,l,n,:] = [x_in@W_in+b_in | tod_emb | dow_emb | adaptive] */
__global__ __launch_bounds__(256) void k_embed2(
    const float* __restrict__ var_x, const float* __restrict__ marker,
    const float* __restrict__ W_in, const float* __restrict__ b_in,
    const float* __restrict__ tod_emb, const float* __restrict__ dow_emb,
    const float* __restrict__ adap, bf* __restrict__ x) {
  int t = blockIdx.x * 256 + threadIdx.x;
  if (t >= TOK_) return;
  int n = t % N_;
  int l = (t / N_) % L_;
  float var = var_x[t];
  float m0 = marker[t*4 + 0];
  float m1 = marker[t*4 + 1];
  int tod = (int)(m0 * 144.f); tod = tod < 0 ? 0 : (tod > 143 ? 143 : tod);
  int dw  = (int)(m1 * 7.f);   dw  = dw  < 0 ? 0 : (dw  > 6   ? 6   : dw);
  bf* xp = x + (long)t * D_;
  for (int d = 0; d < 24; ++d)
    xp[d] = f2bf(var * W_in[d] + m0 * W_in[24 + d] + m1 * W_in[48 + d] + b_in[d]);
  for (int d = 0; d < 24; ++d) xp[24 + d] = f2bf(tod_emb[tod*24 + d]);
  for (int d = 0; d < 24; ++d) xp[48 + d] = f2bf(dow_emb[dw*24 + d]);
  for (int d = 0; d < 80; ++d) xp[72 + d] = f2bf(adap[(l*N_ + n)*80 + d]);
}

/* ------------------------------------------------------------------ */
/* Weight prep: convert all layer weights (f32, k-major) to the exact
   LDS chunk image: bf16 pairs, [chunk][matrix][NdP rows][40 ushorts].
   Per-layer uint map (115200 uints):
     [0,48000)      QKV: [c<5][m<3][d<160][20]
     [48000,64000)  Wo : [c<5][d<160][20]
     [64000,89600)  W1 : [c<5][d<256][20]
     [89600,115200) W2 : [c<8][d<160][20]                                */
__global__ __launch_bounds__(256) void k_wprep6(
    const float* __restrict__ Wq, const float* __restrict__ Wk,
    const float* __restrict__ Wv, const float* __restrict__ Wo,
    const float* __restrict__ W1, const float* __restrict__ W2,
    unsigned* __restrict__ out) {
  int i = blockIdx.x * 256 + threadIdx.x;
  if (i >= 6*115200) return;
  int layer = i / 115200, r = i % 115200;
  const float* src; int K, Nd, d, up, c;
  if (r < 48000) {
    c = r / 9600; int rr = r % 9600; int m = rr / 3200; int r2 = rr % 3200;
    d = r2 / 20; up = r2 % 20;
    src = (m == 0 ? Wq : (m == 1 ? Wk : Wv)) + layer*23104; K = 152; Nd = 152;
  } else if (r < 64000) {
    int rr = r - 48000; c = rr / 3200; int r2 = rr % 3200;
    d = r2 / 20; up = r2 % 20;
    src = Wo + layer*23104; K = 152; Nd = 152;
  } else if (r < 89600) {
    int rr = r - 64000; c = rr / 5120; int r2 = rr % 5120;
    d = r2 / 20; up = r2 % 20;
    src = W1 + layer*38912; K = 152; Nd = 256;
  } else {
    int rr = r - 89600; c = rr / 3200; int r2 = rr % 3200;
    d = r2 / 20; up = r2 % 20;
    src = W2 + layer*38912; K = 256; Nd = 152;
  }
  float v0 = 0.f, v1 = 0.f;
  int k0 = 32*c + 2*up;
  if (up < 16 && d < Nd) {
    if (k0 < K)     v0 = src[(long)k0*Nd + d];
    if (k0 + 1 < K) v1 = src[(long)(k0+1)*Nd + d];
  }
  out[i] = pk_bf(v0, v1);
}

/* ------------------------------------------------------------------ */
/* GEMM v6 (MFMA + prepped weights + global_load_lds double-buffer).
   64 tokens/block, 4 waves; wave w owns token rows 16w..16w+15.
   Step s = chunk(s/NW), matrix(s%NW); W image streamed flat from global.
   A-frag: lane l -> row (l&15), k = 32c + 8*(l>>4)+e  (b128 from Xs)
   B-frag: lane l -> col (l&15), same k            (b128 from Wb, 40-stride)
   C/D:    lane l -> col (l&15), row = 4*(l>>4)+reg   (m89-verified)  */
template<int K, int Nd, int NW, bool RELU, bool LN>
__global__ __launch_bounds__(256) void k_gemm6(
    const bf* __restrict__ X, const ushort* __restrict__ Wg,
    const float* __restrict__ bi0, const float* __restrict__ bi1,
    const float* __restrict__ bi2, const bf* __restrict__ Res,
    const float* __restrict__ g, const float* __restrict__ bb,
    bf* __restrict__ Y0, bf* __restrict__ Y1, bf* __restrict__ Y2) {
  constexpr int NJ   = (Nd + 15) / 16;
  constexpr int NdP  = NJ * 16;
  constexpr int KC   = (K + 31) / 32;
  constexpr int KX   = KC * 32;
  constexpr int XSTR = KX + 8;          /* ushort stride; bytes % 16 == 0 */
  constexpr int SUB_USH = NdP * 40;     /* ushorts per step image */
  constexpr int SUBCB   = SUB_USH * 2;  /* bytes per step image */
  constexpr int S    = KC * NW;
  __shared__ __align__(16) ushort Xs[64 * XSTR];
  __shared__ __align__(16) ushort Wb[2 * SUB_USH];
  long row0 = (long)blockIdx.x * 64;
  int tid = threadIdx.x;
  int lane = tid & 63, w = tid >> 6;
  /* stage X (coalesced uint reads of bf16 rows) */
  const unsigned* Xg = (const unsigned*)(X + row0 * K);
  for (int i = tid; i < 64*(K/2); i += 256) {
    int r = i / (K/2), cp = i % (K/2);
    *(unsigned*)&Xs[r*XSTR + 2*cp] = Xg[i];
  }
  if (KX > K) {
    constexpr int TU = (KX - K) / 2;
    for (int i = tid; i < 64*TU; i += 256) {
      int r = i / TU, u = i % TU;
      *(unsigned*)&Xs[r*XSTR + K + 2*u] = 0u;
    }
  }
  const char* gW = (const char*)Wg;
  issue_w<SUBCB>(gW, Wb, w, lane);
  __syncthreads();
  int cl = lane & 15, gr = lane >> 4;
  float4v acc[NW][NJ];
#pragma unroll
  for (int m = 0; m < NW; ++m)
#pragma unroll
    for (int j = 0; j < NJ; ++j) acc[m][j] = (float4v){0.f, 0.f, 0.f, 0.f};
#pragma unroll
  for (int s = 0; s < S; ++s) {
    if (s + 1 < S)
      issue_w<SUBCB>(gW + (size_t)(s+1)*SUBCB, Wb + ((s+1)&1)*SUB_USH, w, lane);
    short8 af = *(const short8*)&Xs[(16*w + cl)*XSTR + 32*(s/NW) + 8*gr];
    const ushort* wb = Wb + (s&1)*SUB_USH;
#pragma unroll
    for (int j = 0; j < NJ; ++j) {
      short8 bv = *(const short8*)&wb[(16*j + cl)*40 + 8*gr];
      acc[s % NW][j] =
          __builtin_amdgcn_mfma_f32_16x16x32_bf16(af, bv, acc[s % NW][j], 0, 0, 0);
    }
    __syncthreads();
  }
  int rowb = 16*w + 4*gr;            /* + r gives row within block */
  if constexpr (!LN) {
#pragma unroll
    for (int m = 0; m < NW; ++m) {
      bf* Y = (m == 0) ? Y0 : ((m == 1) ? Y1 : Y2);
      const float* bp = (m == 0) ? bi0 : ((m == 1) ? bi1 : bi2);
#pragma unroll
      for (int j = 0; j < NJ; ++j) {
        int d = 16*j + cl;
        if (d < Nd) {
          float bvs = bp[d];
#pragma unroll
          for (int r = 0; r < 4; ++r) {
            float val = acc[m][j][r] + bvs;
            if (RELU) val = fmaxf(val, 0.f);
            Y[(row0 + rowb + r) * Nd + d] = f2bf(val);
          }
        }
      }
    }
  } else {
    /* fused residual + LayerNorm (NW==1) */
#pragma unroll
    for (int j = 0; j < NJ; ++j) {
      int d = 16*j + cl;
      if (d < Nd) {
        float bvs = bi0[d];
#pragma unroll
        for (int r = 0; r < 4; ++r)
          acc[0][j][r] += bvs + bf2f(Res[(row0 + rowb + r) * Nd + d]);
      }
    }
#pragma unroll
    for (int r = 0; r < 4; ++r) {
      float s = 0.f;
#pragma unroll
      for (int j = 0; j < NJ; ++j)
        if (16*j + cl < Nd) s += acc[0][j][r];
      s += __shfl_xor(s, 1, 64); s += __shfl_xor(s, 2, 64);
      s += __shfl_xor(s, 4, 64); s += __shfl_xor(s, 8, 64);
      float mean = s / (float)Nd;
      float s2 = 0.f;
#pragma unroll
      for (int j = 0; j < NJ; ++j)
        if (16*j + cl < Nd) { float dv = acc[0][j][r] - mean; s2 += dv*dv; }
      s2 += __shfl_xor(s2, 1, 64); s2 += __shfl_xor(s2, 2, 64);
      s2 += __shfl_xor(s2, 4, 64); s2 += __shfl_xor(s2, 8, 64);
      float rs = rsqrtf(s2 / (float)Nd + 1e-5f);
#pragma unroll
      for (int j = 0; j < NJ; ++j) {
        int d = 16*j + cl;
        if (d < Nd)
          Y0[(row0 + rowb + r) * Nd + d] =
              f2bf((acc[0][j][r] - mean) * rs * g[d] + bb[d]);
      }
    }
  }
}

/* ------------------------------------------------------------------ */
/* Temporal attention: block per (b,n); S=12; all 4 heads; LDS tiles. */
__global__ __launch_bounds__(256) void k_attn_t(
    const bf* __restrict__ q, const bf* __restrict__ kk,
    const bf* __restrict__ v, bf* __restrict__ a) {
  int s = blockIdx.x; int b = s / N_; int n = s % N_;
  __shared__ float Qs[12][152], Ks[12][152], Vs[12][152];
  __shared__ float Sc[4][12][12];
  int tid = threadIdx.x;
  for (int i = tid; i < 12*152; i += 256) {
    int l = i / 152, d = i % 152;
    long tok = ((long)(b*L_ + l) * N_ + n) * 152 + d;
    Qs[l][d] = bf2f(q[tok]); Ks[l][d] = bf2f(kk[tok]); Vs[l][d] = bf2f(v[tok]);
  }
  __syncthreads();
  for (int e = tid; e < 576; e += 256) {
    int hh = e / 144, r = e % 144, qi = r / 12, kj = r % 12;
    float sc = 0.f;
#pragma unroll
    for (int d = 0; d < HD_; ++d) sc += Qs[qi][hh*HD_ + d] * Ks[kj][hh*HD_ + d];
    Sc[hh][qi][kj] = sc * SCALE_;
  }
  __syncthreads();
  if (tid < 48) {
    int hh = tid / 12, qi = tid % 12;
    float m = Sc[hh][qi][0];
    for (int j = 1; j < 12; ++j) m = fmaxf(m, Sc[hh][qi][j]);
    float sum = 0.f;
    for (int j = 0; j < 12; ++j) {
      float p = __expf(Sc[hh][qi][j] - m);
      Sc[hh][qi][j] = p; sum += p;
    }
    float inv = 1.f / sum;
    for (int j = 0; j < 12; ++j) Sc[hh][qi][j] *= inv;
  }
  __syncthreads();
  for (int e = tid; e < 12*152; e += 256) {
    int qi = e / 152, dd = e % 152, hh = dd / HD_;
    float o = 0.f;
#pragma unroll
    for (int j = 0; j < 12; ++j) o += Sc[hh][qi][j] * Vs[j][dd];
    a[((long)(b*L_ + qi) * N_ + n) * 152 + dd] = f2bf(o);
  }
}

/* ------------------------------------------------------------------ */
/* Spatial attention v4: MFMA flash. Block per (b,l,h); 4 waves.      */
__global__ __launch_bounds__(256) void k_attn_s4(
    const ushort* __restrict__ qg, const ushort* __restrict__ kg,
    const ushort* __restrict__ vg, bf* __restrict__ a) {
  int id = blockIdx.x; int h = id & 3; int s = id >> 2;
  int b = s / L_; int l = s % L_;
  long base = (long)(b*L_ + l) * N_;
  __shared__ ushort Ks[368][40];      /* 29440 B */
  __shared__ ushort Vt[38][392];      /* 29792 B */
  __shared__ ushort Pb[4][16][40];    /*  5120 B -> 64352 total */
  int tid = threadIdx.x;
  /* stage K row-major, zero-padded */
  for (int i = tid; i < 368*20; i += 256) {
    int j = i / 20, t2 = i % 20;
    unsigned u = 0u;
    if (j < N_ && t2 < 19)
      u = *(const unsigned*)(kg + (base + j)*D_ + h*HD_ + 2*t2);
    *(unsigned*)&Ks[j][2*t2] = u;
  }
  /* stage V transposed */
  for (int i = tid; i < N_*19; i += 256) {
    int j = i / 19, t2 = i % 19;
    unsigned u = *(const unsigned*)(vg + (base + j)*D_ + h*HD_ + 2*t2);
    Vt[2*t2][j]     = (ushort)(u & 0xffffu);
    Vt[2*t2 + 1][j] = (ushort)(u >> 16);
  }
  for (int i = tid; i < 38*26; i += 256)
    Vt[i / 26][N_ + i % 26] = 0;
  __syncthreads();

  int lane = tid & 63, w = tid >> 6;
  int cl = lane & 15, gr = lane >> 4;
  bool g0 = (gr == 0);
  const short8 z8 = {0,0,0,0,0,0,0,0};

  for (int qt = w; qt < 23; qt += 4) {
    const ushort* qp = qg + (base + 16*qt + cl) * D_ + h*HD_;
    short8 qA0 = ld_g8(qp + 8*gr);        /* k = 8gr..8gr+7   */
    short8 qA1 = ld_g8(qp + 32 + 8*gr);   /* tail k; B side zeroed */
    float m_[4]   = {-1e30f, -1e30f, -1e30f, -1e30f};
    float sum_[4] = {0.f, 0.f, 0.f, 0.f};
    float4v accO[3];
    accO[0] = (float4v){0,0,0,0};
    accO[1] = (float4v){0,0,0,0};
    accO[2] = (float4v){0,0,0,0};
#pragma unroll 1
    for (int pr = 0; pr < 12; ++pr) {
      int k0 = 32*pr;
      int kr0 = k0 + cl;
      int kr1 = k0 + 16 + cl; if (kr1 > 367) kr1 = 367;
      float4v s0a = (float4v){0,0,0,0}, s1a = (float4v){0,0,0,0};
      {
        short8 b00 = *(const short8*)&Ks[kr0][8*gr];
        short8 b10 = *(const short8*)&Ks[kr1][8*gr];
        s0a = __builtin_amdgcn_mfma_f32_16x16x32_bf16(qA0, b00, s0a, 0, 0, 0);
        s1a = __builtin_amdgcn_mfma_f32_16x16x32_bf16(qA0, b10, s1a, 0, 0, 0);
        short8 b01 = g0 ? *(const short8*)&Ks[kr0][32] : z8;
        short8 b11 = g0 ? *(const short8*)&Ks[kr1][32] : z8;
        s0a = __builtin_amdgcn_mfma_f32_16x16x32_bf16(qA1, b01, s0a, 0, 0, 0);
        s1a = __builtin_amdgcn_mfma_f32_16x16x32_bf16(qA1, b11, s1a, 0, 0, 0);
      }
      bool v0k = (k0 + cl) < N_;
      bool v1k = (k0 + 16 + cl) < N_;
      float p0[4], p1[4], fac[4];
#pragma unroll
      for (int r = 0; r < 4; ++r) {
        float x0 = v0k ? s0a[r]*SCALE_ : -1e30f;
        float x1 = v1k ? s1a[r]*SCALE_ : -1e30f;
        float t = fmaxf(x0, x1);
        t = redmax16(t);
        float mn = fmaxf(m_[r], t);
        fac[r] = __expf(m_[r] - mn);
        m_[r] = mn;
        p0[r] = __expf(x0 - mn);
        p1[r] = __expf(x1 - mn);
        float ts = redsum16(p0[r] + p1[r]);
        sum_[r] = sum_[r]*fac[r] + ts;
      }
#pragma unroll
      for (int dt = 0; dt < 3; ++dt)
#pragma unroll
        for (int r = 0; r < 4; ++r) accO[dt][r] *= fac[r];
      /* stage P tile (bf16) for PV A-frag */
#pragma unroll
      for (int r = 0; r < 4; ++r) {
        Pb[w][4*gr + r][cl]      = f2bf_u(p0[r]);
        Pb[w][4*gr + r][16 + cl] = f2bf_u(p1[r]);
      }
      __asm__ volatile("s_waitcnt lgkmcnt(0)" ::: "memory");
      __builtin_amdgcn_sched_barrier(0);
      short8 aP = *(const short8*)&Pb[w][cl][8*gr];
#pragma unroll
      for (int dt = 0; dt < 3; ++dt) {
        short8 bV = (dt < 2 || cl < 6)
            ? *(const short8*)&Vt[16*dt + cl][k0 + 8*gr] : z8;
        accO[dt] = __builtin_amdgcn_mfma_f32_16x16x32_bf16(aP, bV, accO[dt], 0, 0, 0);
      }
    }
#pragma unroll
    for (int r = 0; r < 4; ++r) {
      int qi = 16*qt + 4*gr + r;
      if (qi < N_) {
        float inv = 1.f / sum_[r];
        bf* ap = a + (base + qi)*D_ + h*HD_;
#pragma unroll
        for (int dt = 0; dt < 3; ++dt) {
          int d = 16*dt + cl;
          if (d < HD_) ap[d] = f2bf(accO[dt][r] * inv);
        }
      }
    }
  }
}

/* ------------------------------------------------------------------ */
__global__ __launch_bounds__(256) void k_wcomb(
    const float* __restrict__ W_mm, const float* __restrict__ W_ts,
    float* __restrict__ wcomb, float* __restrict__ wevtsum) {
  int i = blockIdx.x * 256 + threadIdx.x;
  if (i < 1824*12) {
    int r = i / 12, p = i % 12, l = r / 152, d = r % 152;
    wcomb[i] = W_mm[(l*408 + 256 + d)*12 + p] + W_ts[i];
  }
  if (i < 256*12) {
    int e = i / 12, p = i % 12;
    float s = 0.f;
    for (int l = 0; l < 12; ++l) s += W_mm[(l*408 + e)*12 + p];
    wevtsum[i] = s;
  }
}

/* ------------------------------------------------------------------ */
__global__ __launch_bounds__(256) void k_evt1(
    const float* __restrict__ marker, const int* __restrict__ doy_idx,
    const float* __restrict__ emb, const float* __restrict__ W_evt,
    const float* __restrict__ b_evt, float* __restrict__ evt_h) {
  int bk = blockIdx.x; int b = bk >> 3; int ks = bk & 7;
  float m3 = marker[((b*L_ + (L_-1))*N_ + 0)*4 + 3];
  int doy = (int)(m3 * 365.f); doy = doy < 0 ? 0 : (doy > 365 ? 365 : doy);
  int idx = doy_idx[doy*8 + ks];
  if (idx < 0 || idx > 4096) idx = 0;
  int d = threadIdx.x;
  float acc = b_evt[d];
  const float* er = emb + (long)idx * 1024;
  for (int e = 0; e < 1024; ++e)
    acc += er[e] * W_evt[e*256 + d];
  evt_h[bk*256 + d] = acc;
}

/* ------------------------------------------------------------------ */
__global__ __launch_bounds__(256) void k_evtpool(
    const float* __restrict__ marker, const void* __restrict__ doy_mask,
    const float* __restrict__ evt_h, float* __restrict__ evtp) {
  __shared__ int hasF32, hasBig;
  if (threadIdx.x == 0) { hasF32 = 0; hasBig = 0; }
  __syncthreads();
  const unsigned* mw = (const unsigned*)doy_mask;
  for (int w = threadIdx.x; w < 732; w += 256) {
    unsigned u = mw[w];
    if (u == 0x3F800000u) hasF32 = 1;
    else if (u > 1u) hasBig = 1;
  }
  __syncthreads();
  int fmt = hasF32 ? 2 : (hasBig ? 1 : 0);
  int b = blockIdx.x;
  float m3 = marker[((b*L_ + (L_-1))*N_ + 0)*4 + 3];
  int doy = (int)(m3 * 365.f); doy = doy < 0 ? 0 : (doy > 365 ? 365 : doy);
  int j = threadIdx.x;
  float mx = -1e30f;
  for (int kx = 0; kx < 8; ++kx) {
    bool mk;
    if (fmt == 2)      mk = ((const float*)doy_mask)[doy*8 + kx] != 0.f;
    else if (fmt == 1) mk = ((const unsigned char*)doy_mask)[doy*8 + kx] != 0;
    else               mk = ((const int*)doy_mask)[doy*8 + kx] != 0;
    if (mk) mx = fmaxf(mx, evt_h[(b*8 + kx)*256 + j]);
  }
  evtp[b*256 + j] = mx;
}

/* ------------------------------------------------------------------ */
__global__ __launch_bounds__(192) void k_final3(
    const bf* __restrict__ x, const float* __restrict__ wcomb,
    const float* __restrict__ wevtsum, const float* __restrict__ evtp,
    const float* __restrict__ b_mm, const float* __restrict__ b_ts,
    float* __restrict__ out) {
  int id = blockIdx.x; int b = id / N_; int n = id % N_;
  __shared__ float xs[1824];
  __shared__ float part[16][12];
  int tid = threadIdx.x;
  for (int e = tid; e < 1824; e += 192) {
    int l = e / 152, d = e % 152;
    xs[e] = bf2f(x[((long)(b*L_ + l) * N_ + n) * 152 + d]);
  }
  __syncthreads();
  int g2 = tid / 12, p = tid % 12;
  float acc = 0.f;
  for (int e = g2; e < 1824; e += 16)
    acc += xs[e] * wcomb[e*12 + p];
  part[g2][p] = acc;
  __syncthreads();
  if (tid < 12) {
    float s = b_mm[tid] + b_ts[tid];
    for (int e = 0; e < 256; ++e) s += evtp[b*256 + e] * wevtsum[e*12 + tid];
    for (int gg = 0; gg < 16; ++gg) s += part[gg][tid];
    out[(b*12 + tid) * N_ + n] = s;
  }
}

/* ------------------------------------------------------------------ */
extern "C" void kernel_launch(void* const* d_in, const int* in_sizes, int n_in,
                              void* d_out, int out_size, void* d_ws, size_t ws_size,
                              hipStream_t stream) {
  static const int expect[32] = {
    68736, 274944, 72, 24, 3456, 168, 343680,
    138624, 912, 138624, 912, 138624, 912, 138624, 912,
    233472, 1536, 233472, 912,
    912, 912, 912, 912,
    4195328, 262144, 256,
    58752, 12, 21888, 12,
    2928, 2928 };
  int nb = (out_size + 255)/256;
  if (n_in != 32) {
    k_beacon<<<nb, 256, 0, stream>>>((float*)d_out, out_size, 998.f);
    return;
  }
  for (int i = 0; i < 32; ++i) {
    if (in_sizes[i] != expect[i]) {
      k_beacon<<<nb, 256, 0, stream>>>((float*)d_out, out_size, 1000.f + i);
      return;
    }
  }
  if (out_size != 68736) {
    k_beacon<<<nb, 256, 0, stream>>>((float*)d_out, out_size, 997.f);
    return;
  }

  const float* var_x  = (const float*)d_in[0];
  const float* marker = (const float*)d_in[1];
  const float* W_in   = (const float*)d_in[2];
  const float* b_in   = (const float*)d_in[3];
  const float* tod    = (const float*)d_in[4];
  const float* dow    = (const float*)d_in[5];
  const float* adap   = (const float*)d_in[6];
  const float* Wq = (const float*)d_in[7];  const float* bq = (const float*)d_in[8];
  const float* Wk = (const float*)d_in[9];  const float* bk = (const float*)d_in[10];
  const float* Wv = (const float*)d_in[11]; const float* bv = (const float*)d_in[12];
  const float* Wo = (const float*)d_in[13]; const float* bo = (const float*)d_in[14];
  const float* W1 = (const float*)d_in[15]; const float* b1 = (const float*)d_in[16];
  const float* W2 = (const float*)d_in[17]; const float* b2 = (const float*)d_in[18];
  const float* g1 = (const float*)d_in[19]; const float* be1 = (const float*)d_in[20];
  const float* g2 = (const float*)d_in[21]; const float* be2 = (const float*)d_in[22];
  const float* emb   = (const float*)d_in[23];
  const float* W_evt = (const float*)d_in[24]; const float* b_evt = (const float*)d_in[25];
  const float* W_mm  = (const float*)d_in[26]; const float* b_mm  = (const float*)d_in[27];
  const float* W_ts  = (const float*)d_in[28]; const float* b_ts  = (const float*)d_in[29];
  const int* doyi = (const int*)d_in[30];
  const void* doym = d_in[31];

  const long TD = (long)TOK_ * D_;
  size_t need = (size_t)TD * 2 * 5
              + (size_t)(32768 + 4096 + 3072 + 21888) * 4
              + 2764800 /* prepped weights: 6 layers x 230400 ushorts */
              + 4096;
  if (ws_size < need) {
    k_beacon<<<nb, 256, 0, stream>>>((float*)d_out, out_size, (float)(ws_size >> 20));
    return;
  }

  bf* x = (bf*)d_ws;
  bf* q = x + TD;
  bf* k = q + TD;
  bf* v = k + TD;
  bf* a = v + TD;
  float* evt_h   = (float*)(a + TD);
  float* evtp    = evt_h + 32768;
  float* wevtsum = evtp + 4096;
  float* wcomb   = wevtsum + 3072;
  ushort* wprep  = (ushort*)(wcomb + 21888);   /* 16B-aligned by construction */

  k_wprep6<<<2700, 256, 0, stream>>>(Wq, Wk, Wv, Wo, W1, W2, (unsigned*)wprep);
  k_embed2<<<(TOK_ + 255)/256, 256, 0, stream>>>(var_x, marker, W_in, b_in,
                                                 tod, dow, adap, x);
  for (int i = 0; i < 6; ++i) {
    const ushort* pl = wprep + (size_t)i * 230400;
    /* fused QKV projection */
    k_gemm6<152,152,3,false,false><<<TOK_/64, 256, 0, stream>>>(
        x, pl, bq + i*152, bk + i*152, bv + i*152,
        nullptr, nullptr, nullptr, q, k, v);
    if (i < 3)
      k_attn_t<<<B_*N_, 256, 0, stream>>>(q, k, v, a);
    else
      k_attn_s4<<<B_*L_*4, 256, 0, stream>>>(
          (const ushort*)q, (const ushort*)k, (const ushort*)v, a);
    /* o-proj + residual(x) + LN1 -> k (h) */
    k_gemm6<152,152,1,false,true><<<TOK_/64, 256, 0, stream>>>(
        a, pl + 96000, bo + i*152, nullptr, nullptr,
        x, g1 + i*152, be1 + i*152, k, nullptr, nullptr);
    /* FF1 (ReLU): k -> v */
    k_gemm6<152,256,1,true,false><<<TOK_/64, 256, 0, stream>>>(
        k, pl + 128000, b1 + i*256, nullptr, nullptr,
        nullptr, nullptr, nullptr, v, nullptr, nullptr);
    /* FF2 + residual(h=k) + LN2 -> x */
    k_gemm6<256,152,1,false,true><<<TOK_/64, 256, 0, stream>>>(
        v, pl + 179200, b2 + i*152, nullptr, nullptr,
        k, g2 + i*152, be2 + i*152, x, nullptr, nullptr);
  }
  k_evt1<<<16*8, 256, 0, stream>>>(marker, doyi, emb, W_evt, b_evt, evt_h);
  k_evtpool<<<16, 256, 0, stream>>>(marker, doym, evt_h, evtp);
  k_wcomb<<<(1824*12 + 255)/256, 256, 0, stream>>>(W_mm, W_ts, wcomb, wevtsum);
  k_final3<<<B_*N_, 192, 0, stream>>>(x, wcomb, wevtsum, evtp, b_mm, b_ts,
                                      (float*)d_out);
}

// Round 3
// 1450.675 us; speedup vs baseline: 3.4438x; 1.1765x over previous
//
#include <hip/hip_runtime.h>
#include <hip/hip_bf16.h>

using bf = __hip_bfloat16;

#define B_   16
#define L_   12
#define N_   358
#define D_   152
#define TOK_ (B_*L_*N_)   /* 68736 */
#define FF_  256
#define HD_  38
#define SCALE_ 0.16222142113076254f  /* 38^-0.5 */

__device__ __forceinline__ float bf2f(bf x) { return __bfloat162float(x); }
__device__ __forceinline__ bf f2bf(float f) { return __float2bfloat16(f); }
__device__ __forceinline__ float lo_bf(unsigned u) { return __uint_as_float(u << 16); }
__device__ __forceinline__ float hi_bf(unsigned u) { return __uint_as_float(u & 0xffff0000u); }
__device__ __forceinline__ unsigned pk_bf(float a, float b) {
  union { bf h; unsigned short u; } A, Bu;
  A.h = f2bf(a); Bu.h = f2bf(b);
  return ((unsigned)Bu.u << 16) | A.u;
}

using short8  = __attribute__((ext_vector_type(8))) short;
using float4v = __attribute__((ext_vector_type(4))) float;

/* async global->LDS, 16B per lane; dst is wave-uniform base (HW adds lane*16) */
__device__ __forceinline__ void gl_lds16(const void* g, void* l) {
  __builtin_amdgcn_global_load_lds(
      (const __attribute__((address_space(1))) void*)g,
      (__attribute__((address_space(3))) void*)l, 16, 0, 0);
}

/* copy SUBCB bytes (chunk image) global->LDS; 4 waves interleave 1024B blocks */
template<int SUBCB>
__device__ __forceinline__ void issue_w(const char* gsrc, ushort* lds, int w, int lane) {
  constexpr int TB = SUBCB >> 10;
  constexpr int TAIL = SUBCB & 1023;   /* 0 or 512 */
#pragma unroll
  for (int blk0 = 0; blk0 < TB; blk0 += 4) {
    int blk = blk0 + w;
    if (blk < TB)
      gl_lds16(gsrc + blk*1024 + (size_t)lane*16, (char*)lds + blk*1024);
  }
  if (TAIL) {
    if (w == (TB & 3) && lane < 32)
      gl_lds16(gsrc + TB*1024 + (size_t)lane*16, (char*)lds + TB*1024);
  }
}

/* 16B logical load from a 4B-aligned (not necessarily 16B-aligned) address */
__device__ __forceinline__ short8 ld_g8(const ushort* p) {
  union { unsigned u[4]; short8 v; } t;
  t.u[0] = *(const unsigned*)(p);
  t.u[1] = *(const unsigned*)(p + 2);
  t.u[2] = *(const unsigned*)(p + 4);
  t.u[3] = *(const unsigned*)(p + 6);
  return t.v;
}

/* ------------------------------------------------------------------ */
__global__ void k_beacon(float* out, int n, float val) {
  int i = blockIdx.x * 256 + threadIdx.x;
  if (i < n) out[i] = val;
}

/* ------------------------------------------------------------------ */
/* Embed: x[b,l,n,:] = [x_in@W_in+b_in | tod_emb | dow_emb | adaptive] */
__global__ __launch_bounds__(256) void k_embed2(
    const float* __restrict__ var_x, const float* __restrict__ marker,
    const float* __restrict__ W_in, const float* __restrict__ b_in,
    const float* __restrict__ tod_emb, const float* __restrict__ dow_emb,
    const float* __restrict__ adap, bf* __restrict__ x) {
  int t = blockIdx.x * 256 + threadIdx.x;
  if (t >= TOK_) return;
  int n = t % N_;
  int l = (t / N_) % L_;
  float var = var_x[t];
  float m0 = marker[t*4 + 0];
  float m1 = marker[t*4 + 1];
  int tod = (int)(m0 * 144.f); tod = tod < 0 ? 0 : (tod > 143 ? 143 : tod);
  int dw  = (int)(m1 * 7.f);   dw  = dw  < 0 ? 0 : (dw  > 6   ? 6   : dw);
  bf* xp = x + (long)t * D_;
  for (int d = 0; d < 24; ++d)
    xp[d] = f2bf(var * W_in[d] + m0 * W_in[24 + d] + m1 * W_in[48 + d] + b_in[d]);
  for (int d = 0; d < 24; ++d) xp[24 + d] = f2bf(tod_emb[tod*24 + d]);
  for (int d = 0; d < 24; ++d) xp[48 + d] = f2bf(dow_emb[dw*24 + d]);
  for (int d = 0; d < 80; ++d) xp[72 + d] = f2bf(adap[(l*N_ + n)*80 + d]);
}

/* ------------------------------------------------------------------ */
/* Weight prep: convert all layer weights (f32, k-major) to the exact
   LDS chunk image: bf16 pairs, [chunk][matrix][NdP rows][40 ushorts].
   Per-layer uint map (115200 uints):
     [0,48000)      QKV: [c<5][m<3][d<160][20]
     [48000,64000)  Wo : [c<5][d<160][20]
     [64000,89600)  W1 : [c<5][d<256][20]
     [89600,115200) W2 : [c<8][d<160][20]                                */
__global__ __launch_bounds__(256) void k_wprep6(
    const float* __restrict__ Wq, const float* __restrict__ Wk,
    const float* __restrict__ Wv, const float* __restrict__ Wo,
    const float* __restrict__ W1, const float* __restrict__ W2,
    unsigned* __restrict__ out) {
  int i = blockIdx.x * 256 + threadIdx.x;
  if (i >= 6*115200) return;
  int layer = i / 115200, r = i % 115200;
  const float* src; int K, Nd, d, up, c;
  if (r < 48000) {
    c = r / 9600; int rr = r % 9600; int m = rr / 3200; int r2 = rr % 3200;
    d = r2 / 20; up = r2 % 20;
    src = (m == 0 ? Wq : (m == 1 ? Wk : Wv)) + layer*23104; K = 152; Nd = 152;
  } else if (r < 64000) {
    int rr = r - 48000; c = rr / 3200; int r2 = rr % 3200;
    d = r2 / 20; up = r2 % 20;
    src = Wo + layer*23104; K = 152; Nd = 152;
  } else if (r < 89600) {
    int rr = r - 64000; c = rr / 5120; int r2 = rr % 5120;
    d = r2 / 20; up = r2 % 20;
    src = W1 + layer*38912; K = 152; Nd = 256;
  } else {
    int rr = r - 89600; c = rr / 3200; int r2 = rr % 3200;
    d = r2 / 20; up = r2 % 20;
    src = W2 + layer*38912; K = 256; Nd = 152;
  }
  float v0 = 0.f, v1 = 0.f;
  int k0 = 32*c + 2*up;
  if (up < 16 && d < Nd) {
    if (k0 < K)     v0 = src[(long)k0*Nd + d];
    if (k0 + 1 < K) v1 = src[(long)(k0+1)*Nd + d];
  }
  out[i] = pk_bf(v0, v1);
}

/* ------------------------------------------------------------------ */
/* GEMM v6 (MFMA + prepped weights + global_load_lds double-buffer).  */
template<int K, int Nd, int NW, bool RELU, bool LN>
__global__ __launch_bounds__(256) void k_gemm6(
    const bf* __restrict__ X, const ushort* __restrict__ Wg,
    const float* __restrict__ bi0, const float* __restrict__ bi1,
    const float* __restrict__ bi2, const bf* __restrict__ Res,
    const float* __restrict__ g, const float* __restrict__ bb,
    bf* __restrict__ Y0, bf* __restrict__ Y1, bf* __restrict__ Y2) {
  constexpr int NJ   = (Nd + 15) / 16;
  constexpr int NdP  = NJ * 16;
  constexpr int KC   = (K + 31) / 32;
  constexpr int KX   = KC * 32;
  constexpr int XSTR = KX + 8;          /* ushort stride; bytes % 16 == 0 */
  constexpr int SUB_USH = NdP * 40;     /* ushorts per step image */
  constexpr int SUBCB   = SUB_USH * 2;  /* bytes per step image */
  constexpr int S    = KC * NW;
  __shared__ __align__(16) ushort Xs[64 * XSTR];
  __shared__ __align__(16) ushort Wb[2 * SUB_USH];
  long row0 = (long)blockIdx.x * 64;
  int tid = threadIdx.x;
  int lane = tid & 63, w = tid >> 6;
  /* stage X (coalesced uint reads of bf16 rows) */
  const unsigned* Xg = (const unsigned*)(X + row0 * K);
  for (int i = tid; i < 64*(K/2); i += 256) {
    int r = i / (K/2), cp = i % (K/2);
    *(unsigned*)&Xs[r*XSTR + 2*cp] = Xg[i];
  }
  if (KX > K) {
    constexpr int TU = (KX - K) / 2;
    for (int i = tid; i < 64*TU; i += 256) {
      int r = i / TU, u = i % TU;
      *(unsigned*)&Xs[r*XSTR + K + 2*u] = 0u;
    }
  }
  const char* gW = (const char*)Wg;
  issue_w<SUBCB>(gW, Wb, w, lane);
  __syncthreads();
  int cl = lane & 15, gr = lane >> 4;
  float4v acc[NW][NJ];
#pragma unroll
  for (int m = 0; m < NW; ++m)
#pragma unroll
    for (int j = 0; j < NJ; ++j) acc[m][j] = (float4v){0.f, 0.f, 0.f, 0.f};
#pragma unroll
  for (int s = 0; s < S; ++s) {
    if (s + 1 < S)
      issue_w<SUBCB>(gW + (size_t)(s+1)*SUBCB, Wb + ((s+1)&1)*SUB_USH, w, lane);
    short8 af = *(const short8*)&Xs[(16*w + cl)*XSTR + 32*(s/NW) + 8*gr];
    const ushort* wb = Wb + (s&1)*SUB_USH;
#pragma unroll
    for (int j = 0; j < NJ; ++j) {
      short8 bv = *(const short8*)&wb[(16*j + cl)*40 + 8*gr];
      acc[s % NW][j] =
          __builtin_amdgcn_mfma_f32_16x16x32_bf16(af, bv, acc[s % NW][j], 0, 0, 0);
    }
    __syncthreads();
  }
  int rowb = 16*w + 4*gr;            /* + r gives row within block */
  if constexpr (!LN) {
#pragma unroll
    for (int m = 0; m < NW; ++m) {
      bf* Y = (m == 0) ? Y0 : ((m == 1) ? Y1 : Y2);
      const float* bp = (m == 0) ? bi0 : ((m == 1) ? bi1 : bi2);
#pragma unroll
      for (int j = 0; j < NJ; ++j) {
        int d = 16*j + cl;
        if (d < Nd) {
          float bvs = bp[d];
#pragma unroll
          for (int r = 0; r < 4; ++r) {
            float val = acc[m][j][r] + bvs;
            if (RELU) val = fmaxf(val, 0.f);
            Y[(row0 + rowb + r) * Nd + d] = f2bf(val);
          }
        }
      }
    }
  } else {
    /* fused residual + LayerNorm (NW==1) */
#pragma unroll
    for (int j = 0; j < NJ; ++j) {
      int d = 16*j + cl;
      if (d < Nd) {
        float bvs = bi0[d];
#pragma unroll
        for (int r = 0; r < 4; ++r)
          acc[0][j][r] += bvs + bf2f(Res[(row0 + rowb + r) * Nd + d]);
      }
    }
#pragma unroll
    for (int r = 0; r < 4; ++r) {
      float s = 0.f;
#pragma unroll
      for (int j = 0; j < NJ; ++j)
        if (16*j + cl < Nd) s += acc[0][j][r];
      s += __shfl_xor(s, 1, 64); s += __shfl_xor(s, 2, 64);
      s += __shfl_xor(s, 4, 64); s += __shfl_xor(s, 8, 64);
      float mean = s / (float)Nd;
      float s2 = 0.f;
#pragma unroll
      for (int j = 0; j < NJ; ++j)
        if (16*j + cl < Nd) { float dv = acc[0][j][r] - mean; s2 += dv*dv; }
      s2 += __shfl_xor(s2, 1, 64); s2 += __shfl_xor(s2, 2, 64);
      s2 += __shfl_xor(s2, 4, 64); s2 += __shfl_xor(s2, 8, 64);
      float rs = rsqrtf(s2 / (float)Nd + 1e-5f);
#pragma unroll
      for (int j = 0; j < NJ; ++j) {
        int d = 16*j + cl;
        if (d < Nd)
          Y0[(row0 + rowb + r) * Nd + d] =
              f2bf((acc[0][j][r] - mean) * rs * g[d] + bb[d]);
      }
    }
  }
}

/* ------------------------------------------------------------------ */
/* Temporal attention: block per (b,n); S=12; all 4 heads; LDS tiles. */
__global__ __launch_bounds__(256) void k_attn_t(
    const bf* __restrict__ q, const bf* __restrict__ kk,
    const bf* __restrict__ v, bf* __restrict__ a) {
  int s = blockIdx.x; int b = s / N_; int n = s % N_;
  __shared__ float Qs[12][152], Ks[12][152], Vs[12][152];
  __shared__ float Sc[4][12][12];
  int tid = threadIdx.x;
  for (int i = tid; i < 12*152; i += 256) {
    int l = i / 152, d = i % 152;
    long tok = ((long)(b*L_ + l) * N_ + n) * 152 + d;
    Qs[l][d] = bf2f(q[tok]); Ks[l][d] = bf2f(kk[tok]); Vs[l][d] = bf2f(v[tok]);
  }
  __syncthreads();
  for (int e = tid; e < 576; e += 256) {
    int hh = e / 144, r = e % 144, qi = r / 12, kj = r % 12;
    float sc = 0.f;
#pragma unroll
    for (int d = 0; d < HD_; ++d) sc += Qs[qi][hh*HD_ + d] * Ks[kj][hh*HD_ + d];
    Sc[hh][qi][kj] = sc * SCALE_;
  }
  __syncthreads();
  if (tid < 48) {
    int hh = tid / 12, qi = tid % 12;
    float m = Sc[hh][qi][0];
    for (int j = 1; j < 12; ++j) m = fmaxf(m, Sc[hh][qi][j]);
    float sum = 0.f;
    for (int j = 0; j < 12; ++j) {
      float p = __expf(Sc[hh][qi][j] - m);
      Sc[hh][qi][j] = p; sum += p;
    }
    float inv = 1.f / sum;
    for (int j = 0; j < 12; ++j) Sc[hh][qi][j] *= inv;
  }
  __syncthreads();
  for (int e = tid; e < 12*152; e += 256) {
    int qi = e / 152, dd = e % 152, hh = dd / HD_;
    float o = 0.f;
#pragma unroll
    for (int j = 0; j < 12; ++j) o += Sc[hh][qi][j] * Vs[j][dd];
    a[((long)(b*L_ + qi) * N_ + n) * 152 + dd] = f2bf(o);
  }
}

/* ------------------------------------------------------------------ */
/* Spatial attention v5: swapped-operand MFMA flash.
   Block = 512 threads (8 waves), processes 2 consecutive (b,l,h) units
   (same (b,l), paired heads) -> grid 384, all co-resident (no tail).
   S^T = mfma(A=K, B=Q): lane (cl,gr) -> query cl, keys k0+4gr+r (+16).
   Softmax per query = lane-local tree + shfl_xor(16,32): 2 shfls.
   O^T = mfma(A=V^T, B=P^T): P^T B-frag built in-register via 8 shfls
   (no LDS P bounce). Defer-max (THR=8) skips O-rescale on most tiles.
   Ks/Vt staging + fragment addressing identical to proven v4.        */
__global__ __launch_bounds__(512) void k_attn_s5(
    const ushort* __restrict__ qg, const ushort* __restrict__ kg,
    const ushort* __restrict__ vg, bf* __restrict__ a) {
  __shared__ ushort Ks[360][40];      /* 28800 B; rows>=358, cols 38/39 zero */
  __shared__ ushort Vt[38][392];      /* 29792 B; cols 358..383 zero        */
  int tid = threadIdx.x;
  int lane = tid & 63, w = tid >> 6;
  int cl = lane & 15, gr = lane >> 4;
  bool g0 = (gr == 0);
  const short8 z8 = {0,0,0,0,0,0,0,0};

  for (int uu = 0; uu < 2; ++uu) {
    int id = blockIdx.x * 2 + uu;
    int h = id & 3; int s = id >> 2;
    int b = s / L_; int l = s % L_;
    long base = (long)(b*L_ + l) * N_;
    if (uu) __syncthreads();          /* all reads of prev unit done */
    /* stage K row-major, zero-padded (rows 358..359, col pair 38/39) */
    for (int i = tid; i < 360*20; i += 512) {
      int j = i / 20, t2 = i % 20;
      unsigned u = 0u;
      if (j < N_ && t2 < 19)
        u = *(const unsigned*)(kg + (base + j)*D_ + h*HD_ + 2*t2);
      *(unsigned*)&Ks[j][2*t2] = u;
    }
    /* stage V transposed */
    for (int i = tid; i < N_*19; i += 512) {
      int j = i / 19, t2 = i % 19;
      unsigned u = *(const unsigned*)(vg + (base + j)*D_ + h*HD_ + 2*t2);
      Vt[2*t2][j]     = (ushort)(u & 0xffffu);
      Vt[2*t2 + 1][j] = (ushort)(u >> 16);
    }
    for (int i = tid; i < 38*26; i += 512)
      Vt[i / 26][N_ + i % 26] = 0;
    __syncthreads();

    for (int qt = w; qt < 23; qt += 8) {
      const ushort* qp = qg + (base + 16*qt + cl) * D_ + h*HD_;
      short8 qB0 = ld_g8(qp + 8*gr);       /* B-frag: col cl, k=8gr+e     */
      short8 qB1 = ld_g8(qp + 32 + 8*gr);  /* d-tail chunk; A side zeroed */
      float m_ = -1e30f, sum_ = 0.f;
      float4v accO[3];
      accO[0] = (float4v){0,0,0,0};
      accO[1] = (float4v){0,0,0,0};
      accO[2] = (float4v){0,0,0,0};
#pragma unroll 1
      for (int pr = 0; pr < 12; ++pr) {
        int k0 = 32*pr;
        int kr0 = k0 + cl;      if (kr0 > 359) kr0 = 359;
        int kr1 = k0 + 16 + cl; if (kr1 > 359) kr1 = 359;
        float4v s0a = (float4v){0,0,0,0}, s1a = (float4v){0,0,0,0};
        {
          short8 a00 = *(const short8*)&Ks[kr0][8*gr];
          short8 a10 = *(const short8*)&Ks[kr1][8*gr];
          __builtin_amdgcn_s_setprio(1);
          s0a = __builtin_amdgcn_mfma_f32_16x16x32_bf16(a00, qB0, s0a, 0, 0, 0);
          s1a = __builtin_amdgcn_mfma_f32_16x16x32_bf16(a10, qB0, s1a, 0, 0, 0);
          short8 a01 = g0 ? *(const short8*)&Ks[kr0][32] : z8;
          short8 a11 = g0 ? *(const short8*)&Ks[kr1][32] : z8;
          s0a = __builtin_amdgcn_mfma_f32_16x16x32_bf16(a01, qB1, s0a, 0, 0, 0);
          s1a = __builtin_amdgcn_mfma_f32_16x16x32_bf16(a11, qB1, s1a, 0, 0, 0);
          __builtin_amdgcn_s_setprio(0);
        }
        /* s0a[r] = S^T[key k0+4gr+r][q cl]; s1a[r] = key +16 */
        float x0[4], x1[4];
#pragma unroll
        for (int r = 0; r < 4; ++r) {
          x0[r] = (k0 + 4*gr + r      < N_) ? s0a[r]*SCALE_ : -1e30f;
          x1[r] = (k0 + 16 + 4*gr + r < N_) ? s1a[r]*SCALE_ : -1e30f;
        }
        float t01 = fmaxf(fmaxf(x0[0], x0[1]), fmaxf(x0[2], x0[3]));
        float t23 = fmaxf(fmaxf(x1[0], x1[1]), fmaxf(x1[2], x1[3]));
        float t = fmaxf(t01, t23);
        t = fmaxf(t, __shfl_xor(t, 16, 64));
        t = fmaxf(t, __shfl_xor(t, 32, 64));
        if (!__all(t <= m_ + 8.f)) {      /* defer-max: rescale rarely */
          float mn = fmaxf(m_, t);
          float fac = __expf(m_ - mn);
          m_ = mn;
          sum_ *= fac;
#pragma unroll
          for (int dt = 0; dt < 3; ++dt)
#pragma unroll
            for (int r = 0; r < 4; ++r) accO[dt][r] *= fac;
        }
        float p0[4], p1[4];
#pragma unroll
        for (int r = 0; r < 4; ++r) {
          p0[r] = __expf(x0[r] - m_);
          p1[r] = __expf(x1[r] - m_);
        }
        float s8 = (p0[0] + p0[1]) + (p0[2] + p0[3])
                 + (p1[0] + p1[1]) + (p1[2] + p1[3]);
        s8 += __shfl_xor(s8, 16, 64);
        s8 += __shfl_xor(s8, 32, 64);
        sum_ += s8;
        /* build P^T B-frag: lane (cl,gr) needs P[q=cl][keys k0+8gr..+7] */
        unsigned u0 = pk_bf(p0[0], p0[1]);
        unsigned u1 = pk_bf(p0[2], p0[3]);
        unsigned u2 = pk_bf(p1[0], p1[1]);
        unsigned u3 = pk_bf(p1[2], p1[3]);
        int srcA = cl + 16*((2*gr) & 3);
        int srcB = srcA + 16;
        unsigned a0 = __shfl(u0, srcA, 64), b0 = __shfl(u1, srcA, 64);
        unsigned c0 = __shfl(u0, srcB, 64), d0 = __shfl(u1, srcB, 64);
        unsigned a2 = __shfl(u2, srcA, 64), b2 = __shfl(u3, srcA, 64);
        unsigned c2 = __shfl(u2, srcB, 64), d2 = __shfl(u3, srcB, 64);
        bool lo = gr < 2;
        union { unsigned u[4]; short8 v; } pbu;
        pbu.u[0] = lo ? a0 : a2;
        pbu.u[1] = lo ? b0 : b2;
        pbu.u[2] = lo ? c0 : c2;
        pbu.u[3] = lo ? d0 : d2;
        short8 pB = pbu.v;
        __builtin_amdgcn_s_setprio(1);
#pragma unroll
        for (int dt = 0; dt < 3; ++dt) {
          short8 aV = (dt < 2 || cl < 6)
              ? *(const short8*)&Vt[16*dt + cl][k0 + 8*gr] : z8;
          accO[dt] = __builtin_amdgcn_mfma_f32_16x16x32_bf16(aV, pB, accO[dt], 0, 0, 0);
        }
        __builtin_amdgcn_s_setprio(0);
      }
      /* write: accO[dt][r] = O^T[d=16dt+4gr+r][q=cl] */
      int qi = 16*qt + cl;
      if (qi < N_) {
        float inv = 1.f / sum_;
        bf* ap = a + (base + qi)*D_ + h*HD_;
#pragma unroll
        for (int dt = 0; dt < 2; ++dt) {
          *(unsigned*)(ap + 16*dt + 4*gr)     = pk_bf(accO[dt][0]*inv, accO[dt][1]*inv);
          *(unsigned*)(ap + 16*dt + 4*gr + 2) = pk_bf(accO[dt][2]*inv, accO[dt][3]*inv);
        }
        if (gr == 0) {
          *(unsigned*)(ap + 32) = pk_bf(accO[2][0]*inv, accO[2][1]*inv);
          *(unsigned*)(ap + 34) = pk_bf(accO[2][2]*inv, accO[2][3]*inv);
        } else if (gr == 1) {
          *(unsigned*)(ap + 36) = pk_bf(accO[2][0]*inv, accO[2][1]*inv);
        }
      }
    }
  }
}

/* ------------------------------------------------------------------ */
__global__ __launch_bounds__(256) void k_wcomb(
    const float* __restrict__ W_mm, const float* __restrict__ W_ts,
    float* __restrict__ wcomb, float* __restrict__ wevtsum) {
  int i = blockIdx.x * 256 + threadIdx.x;
  if (i < 1824*12) {
    int r = i / 12, p = i % 12, l = r / 152, d = r % 152;
    wcomb[i] = W_mm[(l*408 + 256 + d)*12 + p] + W_ts[i];
  }
  if (i < 256*12) {
    int e = i / 12, p = i % 12;
    float s = 0.f;
    for (int l = 0; l < 12; ++l) s += W_mm[(l*408 + e)*12 + p];
    wevtsum[i] = s;
  }
}

/* ------------------------------------------------------------------ */
__global__ __launch_bounds__(256) void k_evt1(
    const float* __restrict__ marker, const int* __restrict__ doy_idx,
    const float* __restrict__ emb, const float* __restrict__ W_evt,
    const float* __restrict__ b_evt, float* __restrict__ evt_h) {
  int bk = blockIdx.x; int b = bk >> 3; int ks = bk & 7;
  float m3 = marker[((b*L_ + (L_-1))*N_ + 0)*4 + 3];
  int doy = (int)(m3 * 365.f); doy = doy < 0 ? 0 : (doy > 365 ? 365 : doy);
  int idx = doy_idx[doy*8 + ks];
  if (idx < 0 || idx > 4096) idx = 0;
  int d = threadIdx.x;
  float acc = b_evt[d];
  const float* er = emb + (long)idx * 1024;
  for (int e = 0; e < 1024; ++e)
    acc += er[e] * W_evt[e*256 + d];
  evt_h[bk*256 + d] = acc;
}

/* ------------------------------------------------------------------ */
__global__ __launch_bounds__(256) void k_evtpool(
    const float* __restrict__ marker, const void* __restrict__ doy_mask,
    const float* __restrict__ evt_h, float* __restrict__ evtp) {
  __shared__ int hasF32, hasBig;
  if (threadIdx.x == 0) { hasF32 = 0; hasBig = 0; }
  __syncthreads();
  const unsigned* mw = (const unsigned*)doy_mask;
  for (int w = threadIdx.x; w < 732; w += 256) {
    unsigned u = mw[w];
    if (u == 0x3F800000u) hasF32 = 1;
    else if (u > 1u) hasBig = 1;
  }
  __syncthreads();
  int fmt = hasF32 ? 2 : (hasBig ? 1 : 0);
  int b = blockIdx.x;
  float m3 = marker[((b*L_ + (L_-1))*N_ + 0)*4 + 3];
  int doy = (int)(m3 * 365.f); doy = doy < 0 ? 0 : (doy > 365 ? 365 : doy);
  int j = threadIdx.x;
  float mx = -1e30f;
  for (int kx = 0; kx < 8; ++kx) {
    bool mk;
    if (fmt == 2)      mk = ((const float*)doy_mask)[doy*8 + kx] != 0.f;
    else if (fmt == 1) mk = ((const unsigned char*)doy_mask)[doy*8 + kx] != 0;
    else               mk = ((const int*)doy_mask)[doy*8 + kx] != 0;
    if (mk) mx = fmaxf(mx, evt_h[(b*8 + kx)*256 + j]);
  }
  evtp[b*256 + j] = mx;
}

/* ------------------------------------------------------------------ */
__global__ __launch_bounds__(192) void k_final3(
    const bf* __restrict__ x, const float* __restrict__ wcomb,
    const float* __restrict__ wevtsum, const float* __restrict__ evtp,
    const float* __restrict__ b_mm, const float* __restrict__ b_ts,
    float* __restrict__ out) {
  int id = blockIdx.x; int b = id / N_; int n = id % N_;
  __shared__ float xs[1824];
  __shared__ float part[16][12];
  int tid = threadIdx.x;
  for (int e = tid; e < 1824; e += 192) {
    int l = e / 152, d = e % 152;
    xs[e] = bf2f(x[((long)(b*L_ + l) * N_ + n) * 152 + d]);
  }
  __syncthreads();
  int g2 = tid / 12, p = tid % 12;
  float acc = 0.f;
  for (int e = g2; e < 1824; e += 16)
    acc += xs[e] * wcomb[e*12 + p];
  part[g2][p] = acc;
  __syncthreads();
  if (tid < 12) {
    float s = b_mm[tid] + b_ts[tid];
    for (int e = 0; e < 256; ++e) s += evtp[b*256 + e] * wevtsum[e*12 + tid];
    for (int gg = 0; gg < 16; ++gg) s += part[gg][tid];
    out[(b*12 + tid) * N_ + n] = s;
  }
}

/* ------------------------------------------------------------------ */
extern "C" void kernel_launch(void* const* d_in, const int* in_sizes, int n_in,
                              void* d_out, int out_size, void* d_ws, size_t ws_size,
                              hipStream_t stream) {
  static const int expect[32] = {
    68736, 274944, 72, 24, 3456, 168, 343680,
    138624, 912, 138624, 912, 138624, 912, 138624, 912,
    233472, 1536, 233472, 912,
    912, 912, 912, 912,
    4195328, 262144, 256,
    58752, 12, 21888, 12,
    2928, 2928 };
  int nb = (out_size + 255)/256;
  if (n_in != 32) {
    k_beacon<<<nb, 256, 0, stream>>>((float*)d_out, out_size, 998.f);
    return;
  }
  for (int i = 0; i < 32; ++i) {
    if (in_sizes[i] != expect[i]) {
      k_beacon<<<nb, 256, 0, stream>>>((float*)d_out, out_size, 1000.f + i);
      return;
    }
  }
  if (out_size != 68736) {
    k_beacon<<<nb, 256, 0, stream>>>((float*)d_out, out_size, 997.f);
    return;
  }

  const float* var_x  = (const float*)d_in[0];
  const float* marker = (const float*)d_in[1];
  const float* W_in   = (const float*)d_in[2];
  const float* b_in   = (const float*)d_in[3];
  const float* tod    = (const float*)d_in[4];
  const float* dow    = (const float*)d_in[5];
  const float* adap   = (const float*)d_in[6];
  const float* Wq = (const float*)d_in[7];  const float* bq = (const float*)d_in[8];
  const float* Wk = (const float*)d_in[9];  const float* bk = (const float*)d_in[10];
  const float* Wv = (const float*)d_in[11]; const float* bv = (const float*)d_in[12];
  const float* Wo = (const float*)d_in[13]; const float* bo = (const float*)d_in[14];
  const float* W1 = (const float*)d_in[15]; const float* b1 = (const float*)d_in[16];
  const float* W2 = (const float*)d_in[17]; const float* b2 = (const float*)d_in[18];
  const float* g1 = (const float*)d_in[19]; const float* be1 = (const float*)d_in[20];
  const float* g2 = (const float*)d_in[21]; const float* be2 = (const float*)d_in[22];
  const float* emb   = (const float*)d_in[23];
  const float* W_evt = (const float*)d_in[24]; const float* b_evt = (const float*)d_in[25];
  const float* W_mm  = (const float*)d_in[26]; const float* b_mm  = (const float*)d_in[27];
  const float* W_ts  = (const float*)d_in[28]; const float* b_ts  = (const float*)d_in[29];
  const int* doyi = (const int*)d_in[30];
  const void* doym = d_in[31];

  const long TD = (long)TOK_ * D_;
  size_t need = (size_t)TD * 2 * 5
              + (size_t)(32768 + 4096 + 3072 + 21888) * 4
              + 2764800 /* prepped weights: 6 layers x 230400 ushorts */
              + 4096;
  if (ws_size < need) {
    k_beacon<<<nb, 256, 0, stream>>>((float*)d_out, out_size, (float)(ws_size >> 20));
    return;
  }

  bf* x = (bf*)d_ws;
  bf* q = x + TD;
  bf* k = q + TD;
  bf* v = k + TD;
  bf* a = v + TD;
  float* evt_h   = (float*)(a + TD);
  float* evtp    = evt_h + 32768;
  float* wevtsum = evtp + 4096;
  float* wcomb   = wevtsum + 3072;
  ushort* wprep  = (ushort*)(wcomb + 21888);   /* 16B-aligned by construction */

  k_wprep6<<<2700, 256, 0, stream>>>(Wq, Wk, Wv, Wo, W1, W2, (unsigned*)wprep);
  k_embed2<<<(TOK_ + 255)/256, 256, 0, stream>>>(var_x, marker, W_in, b_in,
                                                 tod, dow, adap, x);
  for (int i = 0; i < 6; ++i) {
    const ushort* pl = wprep + (size_t)i * 230400;
    /* fused QKV projection */
    k_gemm6<152,152,3,false,false><<<TOK_/64, 256, 0, stream>>>(
        x, pl, bq + i*152, bk + i*152, bv + i*152,
        nullptr, nullptr, nullptr, q, k, v);
    if (i < 3)
      k_attn_t<<<B_*N_, 256, 0, stream>>>(q, k, v, a);
    else
      k_attn_s5<<<B_*L_*2, 512, 0, stream>>>(
          (const ushort*)q, (const ushort*)k, (const ushort*)v, a);
    /* o-proj + residual(x) + LN1 -> k (h) */
    k_gemm6<152,152,1,false,true><<<TOK_/64, 256, 0, stream>>>(
        a, pl + 96000, bo + i*152, nullptr, nullptr,
        x, g1 + i*152, be1 + i*152, k, nullptr, nullptr);
    /* FF1 (ReLU): k -> v */
    k_gemm6<152,256,1,true,false><<<TOK_/64, 256, 0, stream>>>(
        k, pl + 128000, b1 + i*256, nullptr, nullptr,
        nullptr, nullptr, nullptr, v, nullptr, nullptr);
    /* FF2 + residual(h=k) + LN2 -> x */
    k_gemm6<256,152,1,false,true><<<TOK_/64, 256, 0, stream>>>(
        v, pl + 179200, b2 + i*152, nullptr, nullptr,
        k, g2 + i*152, be2 + i*152, x, nullptr, nullptr);
  }
  k_evt1<<<16*8, 256, 0, stream>>>(marker, doyi, emb, W_evt, b_evt, evt_h);
  k_evtpool<<<16, 256, 0, stream>>>(marker, doym, evt_h, evtp);
  k_wcomb<<<(1824*12 + 255)/256, 256, 0, stream>>>(W_mm, W_ts, wcomb, wevtsum);
  k_final3<<<B_*N_, 192, 0, stream>>>(x, wcomb, wevtsum, evtp, b_mm, b_ts,
                                      (float*)d_out);
}

// Round 4
// 1288.661 us; speedup vs baseline: 3.8768x; 1.1257x over previous
//
#include <hip/hip_runtime.h>
#include <hip/hip_bf16.h>

using bf = __hip_bfloat16;

#define B_   16
#define L_   12
#define N_   358
#define D_   152
#define TOK_ (B_*L_*N_)   /* 68736 */
#define FF_  256
#define HD_  38
#define SCALE_ 0.16222142113076254f  /* 38^-0.5 */

__device__ __forceinline__ float bf2f(bf x) { return __bfloat162float(x); }
__device__ __forceinline__ bf f2bf(float f) { return __float2bfloat16(f); }
__device__ __forceinline__ float lo_bf(unsigned u) { return __uint_as_float(u << 16); }
__device__ __forceinline__ float hi_bf(unsigned u) { return __uint_as_float(u & 0xffff0000u); }
__device__ __forceinline__ unsigned pk_bf(float a, float b) {
  union { bf h; unsigned short u; } A, Bu;
  A.h = f2bf(a); Bu.h = f2bf(b);
  return ((unsigned)Bu.u << 16) | A.u;
}

using short8  = __attribute__((ext_vector_type(8))) short;
using float4v = __attribute__((ext_vector_type(4))) float;

/* async global->LDS, 16B per lane; dst is wave-uniform base (HW adds lane*16) */
__device__ __forceinline__ void gl_lds16(const void* g, void* l) {
  __builtin_amdgcn_global_load_lds(
      (const __attribute__((address_space(1))) void*)g,
      (__attribute__((address_space(3))) void*)l, 16, 0, 0);
}

/* copy SUBCB bytes global->LDS; 8 waves interleave 1024B blocks */
template<int SUBCB>
__device__ __forceinline__ void issue_w8(const char* gsrc, ushort* lds, int w, int lane) {
  constexpr int TB = SUBCB >> 10;
  constexpr int TAIL = SUBCB & 1023;   /* 0 or 512 */
#pragma unroll
  for (int blk0 = 0; blk0 < TB; blk0 += 8) {
    int blk = blk0 + w;
    if (blk < TB)
      gl_lds16(gsrc + blk*1024 + (size_t)lane*16, (char*)lds + blk*1024);
  }
  if (TAIL) {
    if (w == (TB & 7) && lane < TAIL/16)
      gl_lds16(gsrc + TB*1024 + (size_t)lane*16, (char*)lds + TB*1024);
  }
}

/* 16B logical load from a 4B-aligned (not necessarily 16B-aligned) address */
__device__ __forceinline__ short8 ld_g8(const ushort* p) {
  union { unsigned u[4]; short8 v; } t;
  t.u[0] = *(const unsigned*)(p);
  t.u[1] = *(const unsigned*)(p + 2);
  t.u[2] = *(const unsigned*)(p + 4);
  t.u[3] = *(const unsigned*)(p + 6);
  return t.v;
}

/* ------------------------------------------------------------------ */
__global__ void k_beacon(float* out, int n, float val) {
  int i = blockIdx.x * 256 + threadIdx.x;
  if (i < n) out[i] = val;
}

/* ------------------------------------------------------------------ */
/* Embed: x[b,l,n,:] = [x_in@W_in+b_in | tod_emb | dow_emb | adaptive] */
__global__ __launch_bounds__(256) void k_embed2(
    const float* __restrict__ var_x, const float* __restrict__ marker,
    const float* __restrict__ W_in, const float* __restrict__ b_in,
    const float* __restrict__ tod_emb, const float* __restrict__ dow_emb,
    const float* __restrict__ adap, bf* __restrict__ x) {
  int t = blockIdx.x * 256 + threadIdx.x;
  if (t >= TOK_) return;
  int n = t % N_;
  int l = (t / N_) % L_;
  float var = var_x[t];
  float m0 = marker[t*4 + 0];
  float m1 = marker[t*4 + 1];
  int tod = (int)(m0 * 144.f); tod = tod < 0 ? 0 : (tod > 143 ? 143 : tod);
  int dw  = (int)(m1 * 7.f);   dw  = dw  < 0 ? 0 : (dw  > 6   ? 6   : dw);
  bf* xp = x + (long)t * D_;
  for (int d = 0; d < 24; ++d)
    xp[d] = f2bf(var * W_in[d] + m0 * W_in[24 + d] + m1 * W_in[48 + d] + b_in[d]);
  for (int d = 0; d < 24; ++d) xp[24 + d] = f2bf(tod_emb[tod*24 + d]);
  for (int d = 0; d < 24; ++d) xp[48 + d] = f2bf(dow_emb[dw*24 + d]);
  for (int d = 0; d < 80; ++d) xp[72 + d] = f2bf(adap[(l*N_ + n)*80 + d]);
}

/* ------------------------------------------------------------------ */
/* Weight prep: convert all layer weights (f32, k-major) to the exact
   LDS chunk image: bf16 pairs, [chunk][matrix][NdP rows][40 ushorts].
   Per-layer uint map (115200 uints):
     [0,48000)      QKV: [c<5][m<3][d<160][20]
     [48000,64000)  Wo : [c<5][d<160][20]
     [64000,89600)  W1 : [c<5][d<256][20]
     [89600,115200) W2 : [c<8][d<160][20]
   k>=K and d>=Nd entries are ZERO (relied on by gemm7 garbage-tail).  */
__global__ __launch_bounds__(256) void k_wprep6(
    const float* __restrict__ Wq, const float* __restrict__ Wk,
    const float* __restrict__ Wv, const float* __restrict__ Wo,
    const float* __restrict__ W1, const float* __restrict__ W2,
    unsigned* __restrict__ out) {
  int i = blockIdx.x * 256 + threadIdx.x;
  if (i >= 6*115200) return;
  int layer = i / 115200, r = i % 115200;
  const float* src; int K, Nd, d, up, c;
  if (r < 48000) {
    c = r / 9600; int rr = r % 9600; int m = rr / 3200; int r2 = rr % 3200;
    d = r2 / 20; up = r2 % 20;
    src = (m == 0 ? Wq : (m == 1 ? Wk : Wv)) + layer*23104; K = 152; Nd = 152;
  } else if (r < 64000) {
    int rr = r - 48000; c = rr / 3200; int r2 = rr % 3200;
    d = r2 / 20; up = r2 % 20;
    src = Wo + layer*23104; K = 152; Nd = 152;
  } else if (r < 89600) {
    int rr = r - 64000; c = rr / 5120; int r2 = rr % 5120;
    d = r2 / 20; up = r2 % 20;
    src = W1 + layer*38912; K = 152; Nd = 256;
  } else {
    int rr = r - 89600; c = rr / 3200; int r2 = rr % 3200;
    d = r2 / 20; up = r2 % 20;
    src = W2 + layer*38912; K = 256; Nd = 152;
  }
  float v0 = 0.f, v1 = 0.f;
  int k0 = 32*c + 2*up;
  if (up < 16 && d < Nd) {
    if (k0 < K)     v0 = src[(long)k0*Nd + d];
    if (k0 + 1 < K) v1 = src[(long)(k0+1)*Nd + d];
  }
  out[i] = pk_bf(v0, v1);
}

/* ------------------------------------------------------------------ */
/* GEMM v7: 512 threads / 8 waves; wave grid 4 row-stripes x 2 col-halves.
   X staged via linear global_load_lds (no pad; K-tail garbage is safe
   because the W image zero-pads k>=K, d>=Nd). W image streamed flat,
   double-buffered, CSPLIT sub-steps for wide Nd (FF1).
   A-frag: lane l -> row (l&15), k = kc + 8*(l>>4)+e
   B-frag: lane l -> col (l&15), same k
   C/D:    lane l -> col (l&15), row = 4*(l>>4)+reg   (m89-verified)  */
template<int K, int Nd, int NW, int TOKB, int CSPLIT, bool RELU, bool LN>
__global__ __launch_bounds__(512) void k_gemm7(
    const bf* __restrict__ X, const ushort* __restrict__ Wg,
    const float* __restrict__ bi0, const float* __restrict__ bi1,
    const float* __restrict__ bi2, const bf* __restrict__ Res,
    const float* __restrict__ g, const float* __restrict__ bb,
    bf* __restrict__ Y0, bf* __restrict__ Y1, bf* __restrict__ Y2) {
  constexpr int NJ   = (Nd + 15) / 16;
  constexpr int NdP  = NJ * 16;
  constexpr int KC   = (K + 31) / 32;
  constexpr int G    = NW * CSPLIT;          /* acc groups */
  constexpr int S    = KC * G;               /* steps */
  constexpr int IR   = NdP / CSPLIT;         /* image rows per step */
  constexpr int SUB_USH = IR * 40;
  constexpr int SUBCB   = SUB_USH * 2;
  constexpr int NJW  = IR / 32;              /* col tiles per wave per step */
  constexpr int MR   = TOKB / 64;            /* 16-row tiles per wave */
  constexpr bool GLX = (K == 152);
  constexpr int XSTR = GLX ? K : (K + 8);
  __shared__ __align__(16) ushort Xs[TOKB * XSTR + 8];
  __shared__ __align__(16) ushort Wb[2 * SUB_USH];
  long row0 = (long)blockIdx.x * TOKB;
  int tid = threadIdx.x;
  int lane = tid & 63, w = tid >> 6;
  int cl = lane & 15, gr = lane >> 4;
  int wr = w >> 1, wc = w & 1;
  /* stage X */
  if constexpr (GLX) {
    constexpr int TBX = TOKB * K * 2 / 1024;  /* 19 or 38 */
    const char* Xgc = (const char*)(X + row0 * K);
#pragma unroll
    for (int b0 = 0; b0 < TBX; b0 += 8) {
      int blk = b0 + w;
      if (blk < TBX)
        gl_lds16(Xgc + blk*1024 + (size_t)lane*16, (char*)Xs + blk*1024);
    }
  } else {
    const char* Xgc = (const char*)(X + row0 * K);
    for (int i = tid; i < TOKB*(K/8); i += 512) {
      int r = i / (K/8), c = i % (K/8);
      *(short8*)&Xs[r*XSTR + 8*c] = *(const short8*)(Xgc + r*(K*2) + c*16);
    }
  }
  const char* gW = (const char*)Wg;
  issue_w8<SUBCB>(gW, Wb, w, lane);
  __syncthreads();
  float4v acc[G][MR][NJW];
#pragma unroll
  for (int gi = 0; gi < G; ++gi)
#pragma unroll
    for (int mi = 0; mi < MR; ++mi)
#pragma unroll
      for (int j = 0; j < NJW; ++j) acc[gi][mi][j] = (float4v){0.f,0.f,0.f,0.f};
#pragma unroll
  for (int s = 0; s < S; ++s) {
    if (s + 1 < S)
      issue_w8<SUBCB>(gW + (size_t)(s+1)*SUBCB, Wb + ((s+1)&1)*SUB_USH, w, lane);
    constexpr int dummy = 0; (void)dummy;
    int kc = (s / G) * 32;
    const ushort* wb = Wb + (s&1)*SUB_USH;
    short8 af[MR];
#pragma unroll
    for (int mi = 0; mi < MR; ++mi)
      af[mi] = *(const short8*)&Xs[((TOKB/4)*wr + 16*mi + cl)*XSTR + kc + 8*gr];
#pragma unroll
    for (int j = 0; j < NJW; ++j) {
      short8 bv = *(const short8*)&wb[((IR/2)*wc + 16*j + cl)*40 + 8*gr];
#pragma unroll
      for (int mi = 0; mi < MR; ++mi)
        acc[s % G][mi][j] =
            __builtin_amdgcn_mfma_f32_16x16x32_bf16(af[mi], bv, acc[s % G][mi][j], 0, 0, 0);
    }
    __syncthreads();
  }
  if constexpr (!LN) {
#pragma unroll
    for (int gi = 0; gi < G; ++gi) {
      bf* Y = (NW > 1) ? (gi == 0 ? Y0 : (gi == 1 ? Y1 : Y2)) : Y0;
      const float* bp = (NW > 1) ? (gi == 0 ? bi0 : (gi == 1 ? bi1 : bi2)) : bi0;
      int colb = (CSPLIT > 1 ? IR*gi : 0) + (IR/2)*wc;
#pragma unroll
      for (int j = 0; j < NJW; ++j) {
        int col = colb + 16*j + cl;
        if (col < Nd) {
          float bvs = bp[col];
#pragma unroll
          for (int mi = 0; mi < MR; ++mi) {
            long rw = row0 + (TOKB/4)*wr + 16*mi + 4*gr;
#pragma unroll
            for (int r = 0; r < 4; ++r) {
              float val = acc[gi][mi][j][r] + bvs;
              if (RELU) val = fmaxf(val, 0.f);
              Y[(rw + r) * Nd + col] = f2bf(val);
            }
          }
        }
      }
    }
  } else {
    /* fused residual + LayerNorm; cols split across wc halves ->
       cross-wave-pair reduction through (dead) Wb buffer. */
    float* LNb = (float*)Wb;
    int colb = (IR/2)*wc;
#pragma unroll
    for (int j = 0; j < NJW; ++j) {
      int col = colb + 16*j + cl;
      if (col < Nd) {
        float bvs = bi0[col];
#pragma unroll
        for (int mi = 0; mi < MR; ++mi) {
          long rw = row0 + (TOKB/4)*wr + 16*mi + 4*gr;
#pragma unroll
          for (int r = 0; r < 4; ++r)
            acc[0][mi][j][r] += bvs + bf2f(Res[(rw + r) * Nd + col]);
        }
      }
    }
    float mean[MR][4], rs[MR][4];
#pragma unroll
    for (int mi = 0; mi < MR; ++mi)
#pragma unroll
      for (int r = 0; r < 4; ++r) {
        float s = 0.f;
#pragma unroll
        for (int j = 0; j < NJW; ++j) s += acc[0][mi][j][r];
        s += __shfl_xor(s, 1, 64); s += __shfl_xor(s, 2, 64);
        s += __shfl_xor(s, 4, 64); s += __shfl_xor(s, 8, 64);
        if (cl == 0) LNb[((wr*MR + mi)*2 + wc)*16 + 4*gr + r] = s;
      }
    __syncthreads();
#pragma unroll
    for (int mi = 0; mi < MR; ++mi)
#pragma unroll
      for (int r = 0; r < 4; ++r) {
        float tot = LNb[((wr*MR + mi)*2 + 0)*16 + 4*gr + r]
                  + LNb[((wr*MR + mi)*2 + 1)*16 + 4*gr + r];
        mean[mi][r] = tot * (1.f / (float)Nd);
      }
#pragma unroll
    for (int mi = 0; mi < MR; ++mi)
#pragma unroll
      for (int r = 0; r < 4; ++r) {
        float s2 = 0.f;
#pragma unroll
        for (int j = 0; j < NJW; ++j) {
          int col = colb + 16*j + cl;
          if (col < Nd) {
            float dv = acc[0][mi][j][r] - mean[mi][r];
            s2 += dv*dv;
          }
        }
        s2 += __shfl_xor(s2, 1, 64); s2 += __shfl_xor(s2, 2, 64);
        s2 += __shfl_xor(s2, 4, 64); s2 += __shfl_xor(s2, 8, 64);
        if (cl == 0) LNb[256 + ((wr*MR + mi)*2 + wc)*16 + 4*gr + r] = s2;
      }
    __syncthreads();
#pragma unroll
    for (int mi = 0; mi < MR; ++mi)
#pragma unroll
      for (int r = 0; r < 4; ++r) {
        float tot2 = LNb[256 + ((wr*MR + mi)*2 + 0)*16 + 4*gr + r]
                   + LNb[256 + ((wr*MR + mi)*2 + 1)*16 + 4*gr + r];
        rs[mi][r] = rsqrtf(tot2 * (1.f / (float)Nd) + 1e-5f);
      }
#pragma unroll
    for (int j = 0; j < NJW; ++j) {
      int col = colb + 16*j + cl;
      if (col < Nd) {
        float gv = g[col], bv2 = bb[col];
#pragma unroll
        for (int mi = 0; mi < MR; ++mi) {
          long rw = row0 + (TOKB/4)*wr + 16*mi + 4*gr;
#pragma unroll
          for (int r = 0; r < 4; ++r)
            Y0[(rw + r) * Nd + col] =
                f2bf((acc[0][mi][j][r] - mean[mi][r]) * rs[mi][r] * gv + bv2);
        }
      }
    }
  }
}

/* ------------------------------------------------------------------ */
/* Temporal attention: block per (b,n); S=12; all 4 heads; LDS tiles. */
__global__ __launch_bounds__(256) void k_attn_t(
    const bf* __restrict__ q, const bf* __restrict__ kk,
    const bf* __restrict__ v, bf* __restrict__ a) {
  int s = blockIdx.x; int b = s / N_; int n = s % N_;
  __shared__ float Qs[12][152], Ks[12][152], Vs[12][152];
  __shared__ float Sc[4][12][12];
  int tid = threadIdx.x;
  for (int i = tid; i < 12*152; i += 256) {
    int l = i / 152, d = i % 152;
    long tok = ((long)(b*L_ + l) * N_ + n) * 152 + d;
    Qs[l][d] = bf2f(q[tok]); Ks[l][d] = bf2f(kk[tok]); Vs[l][d] = bf2f(v[tok]);
  }
  __syncthreads();
  for (int e = tid; e < 576; e += 256) {
    int hh = e / 144, r = e % 144, qi = r / 12, kj = r % 12;
    float sc = 0.f;
#pragma unroll
    for (int d = 0; d < HD_; ++d) sc += Qs[qi][hh*HD_ + d] * Ks[kj][hh*HD_ + d];
    Sc[hh][qi][kj] = sc * SCALE_;
  }
  __syncthreads();
  if (tid < 48) {
    int hh = tid / 12, qi = tid % 12;
    float m = Sc[hh][qi][0];
    for (int j = 1; j < 12; ++j) m = fmaxf(m, Sc[hh][qi][j]);
    float sum = 0.f;
    for (int j = 0; j < 12; ++j) {
      float p = __expf(Sc[hh][qi][j] - m);
      Sc[hh][qi][j] = p; sum += p;
    }
    float inv = 1.f / sum;
    for (int j = 0; j < 12; ++j) Sc[hh][qi][j] *= inv;
  }
  __syncthreads();
  for (int e = tid; e < 12*152; e += 256) {
    int qi = e / 152, dd = e % 152, hh = dd / HD_;
    float o = 0.f;
#pragma unroll
    for (int j = 0; j < 12; ++j) o += Sc[hh][qi][j] * Vs[j][dd];
    a[((long)(b*L_ + qi) * N_ + n) * 152 + dd] = f2bf(o);
  }
}

/* ------------------------------------------------------------------ */
/* Spatial attention v5: swapped-operand MFMA flash (round-3 proven). */
__global__ __launch_bounds__(512) void k_attn_s5(
    const ushort* __restrict__ qg, const ushort* __restrict__ kg,
    const ushort* __restrict__ vg, bf* __restrict__ a) {
  __shared__ ushort Ks[360][40];      /* 28800 B; rows>=358, cols 38/39 zero */
  __shared__ ushort Vt[38][392];      /* 29792 B; cols 358..383 zero        */
  int tid = threadIdx.x;
  int lane = tid & 63, w = tid >> 6;
  int cl = lane & 15, gr = lane >> 4;
  bool g0 = (gr == 0);
  const short8 z8 = {0,0,0,0,0,0,0,0};

  for (int uu = 0; uu < 2; ++uu) {
    int id = blockIdx.x * 2 + uu;
    int h = id & 3; int s = id >> 2;
    int b = s / L_; int l = s % L_;
    long base = (long)(b*L_ + l) * N_;
    if (uu) __syncthreads();          /* all reads of prev unit done */
    for (int i = tid; i < 360*20; i += 512) {
      int j = i / 20, t2 = i % 20;
      unsigned u = 0u;
      if (j < N_ && t2 < 19)
        u = *(const unsigned*)(kg + (base + j)*D_ + h*HD_ + 2*t2);
      *(unsigned*)&Ks[j][2*t2] = u;
    }
    for (int i = tid; i < N_*19; i += 512) {
      int j = i / 19, t2 = i % 19;
      unsigned u = *(const unsigned*)(vg + (base + j)*D_ + h*HD_ + 2*t2);
      Vt[2*t2][j]     = (ushort)(u & 0xffffu);
      Vt[2*t2 + 1][j] = (ushort)(u >> 16);
    }
    for (int i = tid; i < 38*26; i += 512)
      Vt[i / 26][N_ + i % 26] = 0;
    __syncthreads();

    for (int qt = w; qt < 23; qt += 8) {
      const ushort* qp = qg + (base + 16*qt + cl) * D_ + h*HD_;
      short8 qB0 = ld_g8(qp + 8*gr);
      short8 qB1 = ld_g8(qp + 32 + 8*gr);
      float m_ = -1e30f, sum_ = 0.f;
      float4v accO[3];
      accO[0] = (float4v){0,0,0,0};
      accO[1] = (float4v){0,0,0,0};
      accO[2] = (float4v){0,0,0,0};
#pragma unroll 1
      for (int pr = 0; pr < 12; ++pr) {
        int k0 = 32*pr;
        int kr0 = k0 + cl;      if (kr0 > 359) kr0 = 359;
        int kr1 = k0 + 16 + cl; if (kr1 > 359) kr1 = 359;
        float4v s0a = (float4v){0,0,0,0}, s1a = (float4v){0,0,0,0};
        {
          short8 a00 = *(const short8*)&Ks[kr0][8*gr];
          short8 a10 = *(const short8*)&Ks[kr1][8*gr];
          __builtin_amdgcn_s_setprio(1);
          s0a = __builtin_amdgcn_mfma_f32_16x16x32_bf16(a00, qB0, s0a, 0, 0, 0);
          s1a = __builtin_amdgcn_mfma_f32_16x16x32_bf16(a10, qB0, s1a, 0, 0, 0);
          short8 a01 = g0 ? *(const short8*)&Ks[kr0][32] : z8;
          short8 a11 = g0 ? *(const short8*)&Ks[kr1][32] : z8;
          s0a = __builtin_amdgcn_mfma_f32_16x16x32_bf16(a01, qB1, s0a, 0, 0, 0);
          s1a = __builtin_amdgcn_mfma_f32_16x16x32_bf16(a11, qB1, s1a, 0, 0, 0);
          __builtin_amdgcn_s_setprio(0);
        }
        float x0[4], x1[4];
#pragma unroll
        for (int r = 0; r < 4; ++r) {
          x0[r] = (k0 + 4*gr + r      < N_) ? s0a[r]*SCALE_ : -1e30f;
          x1[r] = (k0 + 16 + 4*gr + r < N_) ? s1a[r]*SCALE_ : -1e30f;
        }
        float t01 = fmaxf(fmaxf(x0[0], x0[1]), fmaxf(x0[2], x0[3]));
        float t23 = fmaxf(fmaxf(x1[0], x1[1]), fmaxf(x1[2], x1[3]));
        float t = fmaxf(t01, t23);
        t = fmaxf(t, __shfl_xor(t, 16, 64));
        t = fmaxf(t, __shfl_xor(t, 32, 64));
        if (!__all(t <= m_ + 8.f)) {
          float mn = fmaxf(m_, t);
          float fac = __expf(m_ - mn);
          m_ = mn;
          sum_ *= fac;
#pragma unroll
          for (int dt = 0; dt < 3; ++dt)
#pragma unroll
            for (int r = 0; r < 4; ++r) accO[dt][r] *= fac;
        }
        float p0[4], p1[4];
#pragma unroll
        for (int r = 0; r < 4; ++r) {
          p0[r] = __expf(x0[r] - m_);
          p1[r] = __expf(x1[r] - m_);
        }
        float s8 = (p0[0] + p0[1]) + (p0[2] + p0[3])
                 + (p1[0] + p1[1]) + (p1[2] + p1[3]);
        s8 += __shfl_xor(s8, 16, 64);
        s8 += __shfl_xor(s8, 32, 64);
        sum_ += s8;
        unsigned u0 = pk_bf(p0[0], p0[1]);
        unsigned u1 = pk_bf(p0[2], p0[3]);
        unsigned u2 = pk_bf(p1[0], p1[1]);
        unsigned u3 = pk_bf(p1[2], p1[3]);
        int srcA = cl + 16*((2*gr) & 3);
        int srcB = srcA + 16;
        unsigned a0 = __shfl(u0, srcA, 64), b0 = __shfl(u1, srcA, 64);
        unsigned c0 = __shfl(u0, srcB, 64), d0 = __shfl(u1, srcB, 64);
        unsigned a2 = __shfl(u2, srcA, 64), b2 = __shfl(u3, srcA, 64);
        unsigned c2 = __shfl(u2, srcB, 64), d2 = __shfl(u3, srcB, 64);
        bool lo = gr < 2;
        union { unsigned u[4]; short8 v; } pbu;
        pbu.u[0] = lo ? a0 : a2;
        pbu.u[1] = lo ? b0 : b2;
        pbu.u[2] = lo ? c0 : c2;
        pbu.u[3] = lo ? d0 : d2;
        short8 pB = pbu.v;
        __builtin_amdgcn_s_setprio(1);
#pragma unroll
        for (int dt = 0; dt < 3; ++dt) {
          short8 aV = (dt < 2 || cl < 6)
              ? *(const short8*)&Vt[16*dt + cl][k0 + 8*gr] : z8;
          accO[dt] = __builtin_amdgcn_mfma_f32_16x16x32_bf16(aV, pB, accO[dt], 0, 0, 0);
        }
        __builtin_amdgcn_s_setprio(0);
      }
      int qi = 16*qt + cl;
      if (qi < N_) {
        float inv = 1.f / sum_;
        bf* ap = a + (base + qi)*D_ + h*HD_;
#pragma unroll
        for (int dt = 0; dt < 2; ++dt) {
          *(unsigned*)(ap + 16*dt + 4*gr)     = pk_bf(accO[dt][0]*inv, accO[dt][1]*inv);
          *(unsigned*)(ap + 16*dt + 4*gr + 2) = pk_bf(accO[dt][2]*inv, accO[dt][3]*inv);
        }
        if (gr == 0) {
          *(unsigned*)(ap + 32) = pk_bf(accO[2][0]*inv, accO[2][1]*inv);
          *(unsigned*)(ap + 34) = pk_bf(accO[2][2]*inv, accO[2][3]*inv);
        } else if (gr == 1) {
          *(unsigned*)(ap + 36) = pk_bf(accO[2][0]*inv, accO[2][1]*inv);
        }
      }
    }
  }
}

/* ------------------------------------------------------------------ */
__global__ __launch_bounds__(256) void k_wcomb(
    const float* __restrict__ W_mm, const float* __restrict__ W_ts,
    float* __restrict__ wcomb, float* __restrict__ wevtsum) {
  int i = blockIdx.x * 256 + threadIdx.x;
  if (i < 1824*12) {
    int r = i / 12, p = i % 12, l = r / 152, d = r % 152;
    wcomb[i] = W_mm[(l*408 + 256 + d)*12 + p] + W_ts[i];
  }
  if (i < 256*12) {
    int e = i / 12, p = i % 12;
    float s = 0.f;
    for (int l = 0; l < 12; ++l) s += W_mm[(l*408 + e)*12 + p];
    wevtsum[i] = s;
  }
}

/* ------------------------------------------------------------------ */
__global__ __launch_bounds__(256) void k_evt1(
    const float* __restrict__ marker, const int* __restrict__ doy_idx,
    const float* __restrict__ emb, const float* __restrict__ W_evt,
    const float* __restrict__ b_evt, float* __restrict__ evt_h) {
  int bk = blockIdx.x; int b = bk >> 3; int ks = bk & 7;
  float m3 = marker[((b*L_ + (L_-1))*N_ + 0)*4 + 3];
  int doy = (int)(m3 * 365.f); doy = doy < 0 ? 0 : (doy > 365 ? 365 : doy);
  int idx = doy_idx[doy*8 + ks];
  if (idx < 0 || idx > 4096) idx = 0;
  int d = threadIdx.x;
  float acc = b_evt[d];
  const float* er = emb + (long)idx * 1024;
  for (int e = 0; e < 1024; ++e)
    acc += er[e] * W_evt[e*256 + d];
  evt_h[bk*256 + d] = acc;
}

/* ------------------------------------------------------------------ */
__global__ __launch_bounds__(256) void k_evtpool(
    const float* __restrict__ marker, const void* __restrict__ doy_mask,
    const float* __restrict__ evt_h, float* __restrict__ evtp) {
  __shared__ int hasF32, hasBig;
  if (threadIdx.x == 0) { hasF32 = 0; hasBig = 0; }
  __syncthreads();
  const unsigned* mw = (const unsigned*)doy_mask;
  for (int w = threadIdx.x; w < 732; w += 256) {
    unsigned u = mw[w];
    if (u == 0x3F800000u) hasF32 = 1;
    else if (u > 1u) hasBig = 1;
  }
  __syncthreads();
  int fmt = hasF32 ? 2 : (hasBig ? 1 : 0);
  int b = blockIdx.x;
  float m3 = marker[((b*L_ + (L_-1))*N_ + 0)*4 + 3];
  int doy = (int)(m3 * 365.f); doy = doy < 0 ? 0 : (doy > 365 ? 365 : doy);
  int j = threadIdx.x;
  float mx = -1e30f;
  for (int kx = 0; kx < 8; ++kx) {
    bool mk;
    if (fmt == 2)      mk = ((const float*)doy_mask)[doy*8 + kx] != 0.f;
    else if (fmt == 1) mk = ((const unsigned char*)doy_mask)[doy*8 + kx] != 0;
    else               mk = ((const int*)doy_mask)[doy*8 + kx] != 0;
    if (mk) mx = fmaxf(mx, evt_h[(b*8 + kx)*256 + j]);
  }
  evtp[b*256 + j] = mx;
}

/* ------------------------------------------------------------------ */
__global__ __launch_bounds__(192) void k_final3(
    const bf* __restrict__ x, const float* __restrict__ wcomb,
    const float* __restrict__ wevtsum, const float* __restrict__ evtp,
    const float* __restrict__ b_mm, const float* __restrict__ b_ts,
    float* __restrict__ out) {
  int id = blockIdx.x; int b = id / N_; int n = id % N_;
  __shared__ float xs[1824];
  __shared__ float part[16][12];
  int tid = threadIdx.x;
  for (int e = tid; e < 1824; e += 192) {
    int l = e / 152, d = e % 152;
    xs[e] = bf2f(x[((long)(b*L_ + l) * N_ + n) * 152 + d]);
  }
  __syncthreads();
  int g2 = tid / 12, p = tid % 12;
  float acc = 0.f;
  for (int e = g2; e < 1824; e += 16)
    acc += xs[e] * wcomb[e*12 + p];
  part[g2][p] = acc;
  __syncthreads();
  if (tid < 12) {
    float s = b_mm[tid] + b_ts[tid];
    for (int e = 0; e < 256; ++e) s += evtp[b*256 + e] * wevtsum[e*12 + tid];
    for (int gg = 0; gg < 16; ++gg) s += part[gg][tid];
    out[(b*12 + tid) * N_ + n] = s;
  }
}

/* ------------------------------------------------------------------ */
extern "C" void kernel_launch(void* const* d_in, const int* in_sizes, int n_in,
                              void* d_out, int out_size, void* d_ws, size_t ws_size,
                              hipStream_t stream) {
  static const int expect[32] = {
    68736, 274944, 72, 24, 3456, 168, 343680,
    138624, 912, 138624, 912, 138624, 912, 138624, 912,
    233472, 1536, 233472, 912,
    912, 912, 912, 912,
    4195328, 262144, 256,
    58752, 12, 21888, 12,
    2928, 2928 };
  int nb = (out_size + 255)/256;
  if (n_in != 32) {
    k_beacon<<<nb, 256, 0, stream>>>((float*)d_out, out_size, 998.f);
    return;
  }
  for (int i = 0; i < 32; ++i) {
    if (in_sizes[i] != expect[i]) {
      k_beacon<<<nb, 256, 0, stream>>>((float*)d_out, out_size, 1000.f + i);
      return;
    }
  }
  if (out_size != 68736) {
    k_beacon<<<nb, 256, 0, stream>>>((float*)d_out, out_size, 997.f);
    return;
  }

  const float* var_x  = (const float*)d_in[0];
  const float* marker = (const float*)d_in[1];
  const float* W_in   = (const float*)d_in[2];
  const float* b_in   = (const float*)d_in[3];
  const float* tod    = (const float*)d_in[4];
  const float* dow    = (const float*)d_in[5];
  const float* adap   = (const float*)d_in[6];
  const float* Wq = (const float*)d_in[7];  const float* bq = (const float*)d_in[8];
  const float* Wk = (const float*)d_in[9];  const float* bk = (const float*)d_in[10];
  const float* Wv = (const float*)d_in[11]; const float* bv = (const float*)d_in[12];
  const float* Wo = (const float*)d_in[13]; const float* bo = (const float*)d_in[14];
  const float* W1 = (const float*)d_in[15]; const float* b1 = (const float*)d_in[16];
  const float* W2 = (const float*)d_in[17]; const float* b2 = (const float*)d_in[18];
  const float* g1 = (const float*)d_in[19]; const float* be1 = (const float*)d_in[20];
  const float* g2 = (const float*)d_in[21]; const float* be2 = (const float*)d_in[22];
  const float* emb   = (const float*)d_in[23];
  const float* W_evt = (const float*)d_in[24]; const float* b_evt = (const float*)d_in[25];
  const float* W_mm  = (const float*)d_in[26]; const float* b_mm  = (const float*)d_in[27];
  const float* W_ts  = (const float*)d_in[28]; const float* b_ts  = (const float*)d_in[29];
  const int* doyi = (const int*)d_in[30];
  const void* doym = d_in[31];

  const long TD = (long)TOK_ * D_;
  size_t need = (size_t)TD * 2 * 5
              + (size_t)(32768 + 4096 + 3072 + 21888) * 4
              + 2764800 /* prepped weights: 6 layers x 230400 ushorts */
              + 4096;
  if (ws_size < need) {
    k_beacon<<<nb, 256, 0, stream>>>((float*)d_out, out_size, (float)(ws_size >> 20));
    return;
  }

  bf* x = (bf*)d_ws;
  bf* q = x + TD;
  bf* k = q + TD;
  bf* v = k + TD;
  bf* a = v + TD;
  float* evt_h   = (float*)(a + TD);
  float* evtp    = evt_h + 32768;
  float* wevtsum = evtp + 4096;
  float* wcomb   = wevtsum + 3072;
  ushort* wprep  = (ushort*)(wcomb + 21888);   /* 16B-aligned by construction */

  k_wprep6<<<2700, 256, 0, stream>>>(Wq, Wk, Wv, Wo, W1, W2, (unsigned*)wprep);
  k_embed2<<<(TOK_ + 255)/256, 256, 0, stream>>>(var_x, marker, W_in, b_in,
                                                 tod, dow, adap, x);
  for (int i = 0; i < 6; ++i) {
    const ushort* pl = wprep + (size_t)i * 230400;
    /* fused QKV projection (64-tok blocks) */
    k_gemm7<152,152,3,64,1,false,false><<<TOK_/64, 512, 0, stream>>>(
        x, pl, bq + i*152, bk + i*152, bv + i*152,
        nullptr, nullptr, nullptr, q, k, v);
    if (i < 3)
      k_attn_t<<<B_*N_, 256, 0, stream>>>(q, k, v, a);
    else
      k_attn_s5<<<B_*L_*2, 512, 0, stream>>>(
          (const ushort*)q, (const ushort*)k, (const ushort*)v, a);
    /* o-proj + residual(x) + LN1 -> k (h)  (128-tok blocks) */
    k_gemm7<152,152,1,128,1,false,true><<<TOK_/128, 512, 0, stream>>>(
        a, pl + 96000, bo + i*152, nullptr, nullptr,
        x, g1 + i*152, be1 + i*152, k, nullptr, nullptr);
    /* FF1 (ReLU): k -> v  (128-tok blocks, col-split steps) */
    k_gemm7<152,256,1,128,2,true,false><<<TOK_/128, 512, 0, stream>>>(
        k, pl + 128000, b1 + i*256, nullptr, nullptr,
        nullptr, nullptr, nullptr, v, nullptr, nullptr);
    /* FF2 + residual(h=k) + LN2 -> x  (64-tok blocks, K=256) */
    k_gemm7<256,152,1,64,1,false,true><<<TOK_/64, 512, 0, stream>>>(
        v, pl + 179200, b2 + i*152, nullptr, nullptr,
        k, g2 + i*152, be2 + i*152, x, nullptr, nullptr);
  }
  k_evt1<<<16*8, 256, 0, stream>>>(marker, doyi, emb, W_evt, b_evt, evt_h);
  k_evtpool<<<16, 256, 0, stream>>>(marker, doym, evt_h, evtp);
  k_wcomb<<<(1824*12 + 255)/256, 256, 0, stream>>>(W_mm, W_ts, wcomb, wevtsum);
  k_final3<<<B_*N_, 192, 0, stream>>>(x, wcomb, wevtsum, evtp, b_mm, b_ts,
                                      (float*)d_out);
}

// Round 5
// 1188.347 us; speedup vs baseline: 4.2040x; 1.0844x over previous
//
#include <hip/hip_runtime.h>
#include <hip/hip_bf16.h>

using bf = __hip_bfloat16;

#define B_   16
#define L_   12
#define N_   358
#define D_   152
#define TOK_ (B_*L_*N_)   /* 68736 */
#define FF_  256
#define HD_  38
#define SCALE_ 0.16222142113076254f  /* 38^-0.5 */
#define C2_   0.23403921469340696f   /* SCALE_ * log2(e) */

__device__ __forceinline__ float bf2f(bf x) { return __bfloat162float(x); }
__device__ __forceinline__ bf f2bf(float f) { return __float2bfloat16(f); }
__device__ __forceinline__ float lo_bf(unsigned u) { return __uint_as_float(u << 16); }
__device__ __forceinline__ float hi_bf(unsigned u) { return __uint_as_float(u & 0xffff0000u); }
__device__ __forceinline__ unsigned pk_bf(float a, float b) {
  union { bf h; unsigned short u; } A, Bu;
  A.h = f2bf(a); Bu.h = f2bf(b);
  return ((unsigned)Bu.u << 16) | A.u;
}

using short8  = __attribute__((ext_vector_type(8))) short;
using float4v = __attribute__((ext_vector_type(4))) float;

/* async global->LDS, 16B per lane; dst is wave-uniform base (HW adds lane*16) */
__device__ __forceinline__ void gl_lds16(const void* g, void* l) {
  __builtin_amdgcn_global_load_lds(
      (const __attribute__((address_space(1))) void*)g,
      (__attribute__((address_space(3))) void*)l, 16, 0, 0);
}

/* copy SUBCB bytes global->LDS; 8 waves interleave 1024B blocks */
template<int SUBCB>
__device__ __forceinline__ void issue_w8(const char* gsrc, ushort* lds, int w, int lane) {
  constexpr int TB = SUBCB >> 10;
  constexpr int TAIL = SUBCB & 1023;
#pragma unroll
  for (int blk0 = 0; blk0 < TB; blk0 += 8) {
    int blk = blk0 + w;
    if (blk < TB)
      gl_lds16(gsrc + blk*1024 + (size_t)lane*16, (char*)lds + blk*1024);
  }
  if (TAIL) {
    if (w == (TB & 7) && lane < TAIL/16)
      gl_lds16(gsrc + TB*1024 + (size_t)lane*16, (char*)lds + TB*1024);
  }
}

/* 16B logical load from a 4B-aligned (not necessarily 16B-aligned) address */
__device__ __forceinline__ short8 ld_g8(const ushort* p) {
  union { unsigned u[4]; short8 v; } t;
  t.u[0] = *(const unsigned*)(p);
  t.u[1] = *(const unsigned*)(p + 2);
  t.u[2] = *(const unsigned*)(p + 4);
  t.u[3] = *(const unsigned*)(p + 6);
  return t.v;
}

/* ------------------------------------------------------------------ */
__global__ void k_beacon(float* out, int n, float val) {
  int i = blockIdx.x * 256 + threadIdx.x;
  if (i < n) out[i] = val;
}

/* ------------------------------------------------------------------ */
/* Embed: x[b,l,n,:] = [x_in@W_in+b_in | tod_emb | dow_emb | adaptive] */
__global__ __launch_bounds__(256) void k_embed2(
    const float* __restrict__ var_x, const float* __restrict__ marker,
    const float* __restrict__ W_in, const float* __restrict__ b_in,
    const float* __restrict__ tod_emb, const float* __restrict__ dow_emb,
    const float* __restrict__ adap, bf* __restrict__ x) {
  int t = blockIdx.x * 256 + threadIdx.x;
  if (t >= TOK_) return;
  int n = t % N_;
  int l = (t / N_) % L_;
  float var = var_x[t];
  float m0 = marker[t*4 + 0];
  float m1 = marker[t*4 + 1];
  int tod = (int)(m0 * 144.f); tod = tod < 0 ? 0 : (tod > 143 ? 143 : tod);
  int dw  = (int)(m1 * 7.f);   dw  = dw  < 0 ? 0 : (dw  > 6   ? 6   : dw);
  bf* xp = x + (long)t * D_;
  for (int d = 0; d < 24; ++d)
    xp[d] = f2bf(var * W_in[d] + m0 * W_in[24 + d] + m1 * W_in[48 + d] + b_in[d]);
  for (int d = 0; d < 24; ++d) xp[24 + d] = f2bf(tod_emb[tod*24 + d]);
  for (int d = 0; d < 24; ++d) xp[48 + d] = f2bf(dow_emb[dw*24 + d]);
  for (int d = 0; d < 80; ++d) xp[72 + d] = f2bf(adap[(l*N_ + n)*80 + d]);
}

/* ------------------------------------------------------------------ */
/* Weight prep: [chunk][matrix][NdP rows][40 ushorts], zero-padded.   */
__global__ __launch_bounds__(256) void k_wprep6(
    const float* __restrict__ Wq, const float* __restrict__ Wk,
    const float* __restrict__ Wv, const float* __restrict__ Wo,
    const float* __restrict__ W1, const float* __restrict__ W2,
    unsigned* __restrict__ out) {
  int i = blockIdx.x * 256 + threadIdx.x;
  if (i >= 6*115200) return;
  int layer = i / 115200, r = i % 115200;
  const float* src; int K, Nd, d, up, c;
  if (r < 48000) {
    c = r / 9600; int rr = r % 9600; int m = rr / 3200; int r2 = rr % 3200;
    d = r2 / 20; up = r2 % 20;
    src = (m == 0 ? Wq : (m == 1 ? Wk : Wv)) + layer*23104; K = 152; Nd = 152;
  } else if (r < 64000) {
    int rr = r - 48000; c = rr / 3200; int r2 = rr % 3200;
    d = r2 / 20; up = r2 % 20;
    src = Wo + layer*23104; K = 152; Nd = 152;
  } else if (r < 89600) {
    int rr = r - 64000; c = rr / 5120; int r2 = rr % 5120;
    d = r2 / 20; up = r2 % 20;
    src = W1 + layer*38912; K = 152; Nd = 256;
  } else {
    int rr = r - 89600; c = rr / 3200; int r2 = rr % 3200;
    d = r2 / 20; up = r2 % 20;
    src = W2 + layer*38912; K = 256; Nd = 152;
  }
  float v0 = 0.f, v1 = 0.f;
  int k0 = 32*c + 2*up;
  if (up < 16 && d < Nd) {
    if (k0 < K)     v0 = src[(long)k0*Nd + d];
    if (k0 + 1 < K) v1 = src[(long)(k0+1)*Nd + d];
  }
  out[i] = pk_bf(v0, v1);
}

/* ------------------------------------------------------------------ */
/* GEMM v7 (round-4 proven): 512 threads / 8 waves; 4 row x 2 col.    */
template<int K, int Nd, int NW, int TOKB, int CSPLIT, bool RELU, bool LN>
__global__ __launch_bounds__(512) void k_gemm7(
    const bf* __restrict__ X, const ushort* __restrict__ Wg,
    const float* __restrict__ bi0, const float* __restrict__ bi1,
    const float* __restrict__ bi2, const bf* __restrict__ Res,
    const float* __restrict__ g, const float* __restrict__ bb,
    bf* __restrict__ Y0, bf* __restrict__ Y1, bf* __restrict__ Y2) {
  constexpr int NJ   = (Nd + 15) / 16;
  constexpr int NdP  = NJ * 16;
  constexpr int KC   = (K + 31) / 32;
  constexpr int G    = NW * CSPLIT;
  constexpr int S    = KC * G;
  constexpr int IR   = NdP / CSPLIT;
  constexpr int SUB_USH = IR * 40;
  constexpr int SUBCB   = SUB_USH * 2;
  constexpr int NJW  = IR / 32;
  constexpr int MR   = TOKB / 64;
  constexpr bool GLX = (K == 152);
  constexpr int XSTR = GLX ? K : (K + 8);
  __shared__ __align__(16) ushort Xs[TOKB * XSTR + 8];
  __shared__ __align__(16) ushort Wb[2 * SUB_USH];
  long row0 = (long)blockIdx.x * TOKB;
  int tid = threadIdx.x;
  int lane = tid & 63, w = tid >> 6;
  int cl = lane & 15, gr = lane >> 4;
  int wr = w >> 1, wc = w & 1;
  if constexpr (GLX) {
    constexpr int TBX = TOKB * K * 2 / 1024;
    const char* Xgc = (const char*)(X + row0 * K);
#pragma unroll
    for (int b0 = 0; b0 < TBX; b0 += 8) {
      int blk = b0 + w;
      if (blk < TBX)
        gl_lds16(Xgc + blk*1024 + (size_t)lane*16, (char*)Xs + blk*1024);
    }
  } else {
    const char* Xgc = (const char*)(X + row0 * K);
    for (int i = tid; i < TOKB*(K/8); i += 512) {
      int r = i / (K/8), c = i % (K/8);
      *(short8*)&Xs[r*XSTR + 8*c] = *(const short8*)(Xgc + r*(K*2) + c*16);
    }
  }
  const char* gW = (const char*)Wg;
  issue_w8<SUBCB>(gW, Wb, w, lane);
  __syncthreads();
  float4v acc[G][MR][NJW];
#pragma unroll
  for (int gi = 0; gi < G; ++gi)
#pragma unroll
    for (int mi = 0; mi < MR; ++mi)
#pragma unroll
      for (int j = 0; j < NJW; ++j) acc[gi][mi][j] = (float4v){0.f,0.f,0.f,0.f};
#pragma unroll
  for (int s = 0; s < S; ++s) {
    if (s + 1 < S)
      issue_w8<SUBCB>(gW + (size_t)(s+1)*SUBCB, Wb + ((s+1)&1)*SUB_USH, w, lane);
    int kc = (s / G) * 32;
    const ushort* wb = Wb + (s&1)*SUB_USH;
    short8 af[MR];
#pragma unroll
    for (int mi = 0; mi < MR; ++mi)
      af[mi] = *(const short8*)&Xs[((TOKB/4)*wr + 16*mi + cl)*XSTR + kc + 8*gr];
#pragma unroll
    for (int j = 0; j < NJW; ++j) {
      short8 bv = *(const short8*)&wb[((IR/2)*wc + 16*j + cl)*40 + 8*gr];
#pragma unroll
      for (int mi = 0; mi < MR; ++mi)
        acc[s % G][mi][j] =
            __builtin_amdgcn_mfma_f32_16x16x32_bf16(af[mi], bv, acc[s % G][mi][j], 0, 0, 0);
    }
    __syncthreads();
  }
  if constexpr (!LN) {
#pragma unroll
    for (int gi = 0; gi < G; ++gi) {
      bf* Y = (NW > 1) ? (gi == 0 ? Y0 : (gi == 1 ? Y1 : Y2)) : Y0;
      const float* bp = (NW > 1) ? (gi == 0 ? bi0 : (gi == 1 ? bi1 : bi2)) : bi0;
      int colb = (CSPLIT > 1 ? IR*gi : 0) + (IR/2)*wc;
#pragma unroll
      for (int j = 0; j < NJW; ++j) {
        int col = colb + 16*j + cl;
        if (col < Nd) {
          float bvs = bp[col];
#pragma unroll
          for (int mi = 0; mi < MR; ++mi) {
            long rw = row0 + (TOKB/4)*wr + 16*mi + 4*gr;
#pragma unroll
            for (int r = 0; r < 4; ++r) {
              float val = acc[gi][mi][j][r] + bvs;
              if (RELU) val = fmaxf(val, 0.f);
              Y[(rw + r) * Nd + col] = f2bf(val);
            }
          }
        }
      }
    }
  } else {
    float* LNb = (float*)Wb;
    int colb = (IR/2)*wc;
#pragma unroll
    for (int j = 0; j < NJW; ++j) {
      int col = colb + 16*j + cl;
      if (col < Nd) {
        float bvs = bi0[col];
#pragma unroll
        for (int mi = 0; mi < MR; ++mi) {
          long rw = row0 + (TOKB/4)*wr + 16*mi + 4*gr;
#pragma unroll
          for (int r = 0; r < 4; ++r)
            acc[0][mi][j][r] += bvs + bf2f(Res[(rw + r) * Nd + col]);
        }
      }
    }
    float mean[MR][4], rs[MR][4];
#pragma unroll
    for (int mi = 0; mi < MR; ++mi)
#pragma unroll
      for (int r = 0; r < 4; ++r) {
        float s = 0.f;
#pragma unroll
        for (int j = 0; j < NJW; ++j) s += acc[0][mi][j][r];
        s += __shfl_xor(s, 1, 64); s += __shfl_xor(s, 2, 64);
        s += __shfl_xor(s, 4, 64); s += __shfl_xor(s, 8, 64);
        if (cl == 0) LNb[((wr*MR + mi)*2 + wc)*16 + 4*gr + r] = s;
      }
    __syncthreads();
#pragma unroll
    for (int mi = 0; mi < MR; ++mi)
#pragma unroll
      for (int r = 0; r < 4; ++r) {
        float tot = LNb[((wr*MR + mi)*2 + 0)*16 + 4*gr + r]
                  + LNb[((wr*MR + mi)*2 + 1)*16 + 4*gr + r];
        mean[mi][r] = tot * (1.f / (float)Nd);
      }
#pragma unroll
    for (int mi = 0; mi < MR; ++mi)
#pragma unroll
      for (int r = 0; r < 4; ++r) {
        float s2 = 0.f;
#pragma unroll
        for (int j = 0; j < NJW; ++j) {
          int col = colb + 16*j + cl;
          if (col < Nd) {
            float dv = acc[0][mi][j][r] - mean[mi][r];
            s2 += dv*dv;
          }
        }
        s2 += __shfl_xor(s2, 1, 64); s2 += __shfl_xor(s2, 2, 64);
        s2 += __shfl_xor(s2, 4, 64); s2 += __shfl_xor(s2, 8, 64);
        if (cl == 0) LNb[256 + ((wr*MR + mi)*2 + wc)*16 + 4*gr + r] = s2;
      }
    __syncthreads();
#pragma unroll
    for (int mi = 0; mi < MR; ++mi)
#pragma unroll
      for (int r = 0; r < 4; ++r) {
        float tot2 = LNb[256 + ((wr*MR + mi)*2 + 0)*16 + 4*gr + r]
                   + LNb[256 + ((wr*MR + mi)*2 + 1)*16 + 4*gr + r];
        rs[mi][r] = rsqrtf(tot2 * (1.f / (float)Nd) + 1e-5f);
      }
#pragma unroll
    for (int j = 0; j < NJW; ++j) {
      int col = colb + 16*j + cl;
      if (col < Nd) {
        float gv = g[col], bv2 = bb[col];
#pragma unroll
        for (int mi = 0; mi < MR; ++mi) {
          long rw = row0 + (TOKB/4)*wr + 16*mi + 4*gr;
#pragma unroll
          for (int r = 0; r < 4; ++r)
            Y0[(rw + r) * Nd + col] =
                f2bf((acc[0][mi][j][r] - mean[mi][r]) * rs[mi][r] * gv + bv2);
        }
      }
    }
  }
}

/* ------------------------------------------------------------------ */
/* Temporal attention v2: MFMA, swapped-operand (same algebra as s5).
   Block per (b,n), 4 waves = 4 heads. K/Q/V staged bf16, zero-padded:
     Ksh/Qsh [4][16][40] (keys/queries pad 12->16, hd pad 38->40)
     Vth     [4][40][16] (V^T: d pad->40, keys pad->16)
   S^T = mfma(K,Q): lane (cl,gr) -> q cl, keys 4gr+r. No-max softmax
   (scores tiny; clamp 80). P^T B-frag via 4 bpermutes. O^T = mfma(V^T,P^T). */
__global__ __launch_bounds__(256) void k_attn_t2(
    const ushort* __restrict__ qg, const ushort* __restrict__ kg,
    const ushort* __restrict__ vg, bf* __restrict__ a) {
  int id = blockIdx.x; int b = id / N_; int n = id % N_;
  __shared__ ushort Ksh[4][16][40];
  __shared__ ushort Qsh[4][16][40];
  __shared__ ushort Vth[4][40][16];
  int tid = threadIdx.x;
  for (int i = tid; i < 1280; i += 256) {
    ((unsigned*)Ksh)[i] = 0u; ((unsigned*)Qsh)[i] = 0u; ((unsigned*)Vth)[i] = 0u;
  }
  __syncthreads();
  /* stage K,Q (valid cols 0..37 as uint pairs) */
  for (int i = tid; i < 4*12*19; i += 256) {
    int h = i / 228, r = i % 228, l = r / 19, t2 = r % 19;
    long off = ((long)(b*L_ + l) * N_ + n) * D_ + h*HD_ + 2*t2;
    *(unsigned*)&Ksh[h][l][2*t2] = *(const unsigned*)(kg + off);
    *(unsigned*)&Qsh[h][l][2*t2] = *(const unsigned*)(qg + off);
  }
  /* stage V transposed */
  for (int i = tid; i < 4*12*19; i += 256) {
    int h = i / 228, r = i % 228, l = r / 19, t2 = r % 19;
    long off = ((long)(b*L_ + l) * N_ + n) * D_ + h*HD_ + 2*t2;
    unsigned u = *(const unsigned*)(vg + off);
    Vth[h][2*t2][l]     = (ushort)(u & 0xffffu);
    Vth[h][2*t2 + 1][l] = (ushort)(u >> 16);
  }
  __syncthreads();
  int lane = tid & 63, w = tid >> 6;      /* w = head */
  int cl = lane & 15, gr = lane >> 4;
  const short8 z8 = {0,0,0,0,0,0,0,0};
  short8 a00 = *(const short8*)&Ksh[w][cl][8*gr];
  short8 qB0 = *(const short8*)&Qsh[w][cl][8*gr];
  short8 a01 = (gr == 0) ? *(const short8*)&Ksh[w][cl][32] : z8;
  short8 qB1 = (gr == 0) ? *(const short8*)&Qsh[w][cl][32] : z8;
  float4v sa = (float4v){0,0,0,0};
  sa = __builtin_amdgcn_mfma_f32_16x16x32_bf16(a00, qB0, sa, 0, 0, 0);
  sa = __builtin_amdgcn_mfma_f32_16x16x32_bf16(a01, qB1, sa, 0, 0, 0);
  float p[4];
#pragma unroll
  for (int r = 0; r < 4; ++r) {
    float xv = (4*gr + r < 12) ? sa[r]*C2_ : -1e30f;
    p[r] = __builtin_exp2f(fminf(xv, 80.f));
  }
  float sum_ = (p[0] + p[1]) + (p[2] + p[3]);
  sum_ += __shfl_xor(sum_, 16, 64);
  sum_ += __shfl_xor(sum_, 32, 64);
  unsigned u0 = pk_bf(p[0], p[1]);
  unsigned u1 = pk_bf(p[2], p[3]);
  int srcA = cl + 32*(gr & 1);
  int srcB = srcA + 16;
  unsigned w0 = __shfl(u0, srcA, 64), w1 = __shfl(u1, srcA, 64);
  unsigned w2 = __shfl(u0, srcB, 64), w3 = __shfl(u1, srcB, 64);
  union { unsigned u[4]; short8 v; } pbu;
  bool gv = gr < 2;
  pbu.u[0] = gv ? w0 : 0u; pbu.u[1] = gv ? w1 : 0u;
  pbu.u[2] = gv ? w2 : 0u; pbu.u[3] = gv ? w3 : 0u;
  short8 pB = pbu.v;
  float4v accO[3];
#pragma unroll
  for (int dt = 0; dt < 3; ++dt) {
    short8 aV = (gv && (dt < 2 || cl < 8))
        ? *(const short8*)&Vth[w][16*dt + cl][8*gr] : z8;
    accO[dt] = (float4v){0,0,0,0};
    accO[dt] = __builtin_amdgcn_mfma_f32_16x16x32_bf16(aV, pB, accO[dt], 0, 0, 0);
  }
  if (cl < 12) {
    float inv = 1.f / sum_;
    bf* ap = a + ((long)(b*L_ + cl) * N_ + n) * D_ + w*HD_;
#pragma unroll
    for (int dt = 0; dt < 2; ++dt) {
      *(unsigned*)(ap + 16*dt + 4*gr)     = pk_bf(accO[dt][0]*inv, accO[dt][1]*inv);
      *(unsigned*)(ap + 16*dt + 4*gr + 2) = pk_bf(accO[dt][2]*inv, accO[dt][3]*inv);
    }
    if (gr == 0) {
      *(unsigned*)(ap + 32) = pk_bf(accO[2][0]*inv, accO[2][1]*inv);
      *(unsigned*)(ap + 34) = pk_bf(accO[2][2]*inv, accO[2][3]*inv);
    } else if (gr == 1) {
      *(unsigned*)(ap + 36) = pk_bf(accO[2][0]*inv, accO[2][1]*inv);
    }
  }
}

/* ------------------------------------------------------------------ */
/* Spatial attention v6: v5 minus online-max (scores tiny: LN'd inputs
   x 0.02-std weights; exp2 with clamp 80 for worst-case safety), with
   lane-local deferred sum (2 shfls/query total) and a cheap 6-key tail. */
__global__ __launch_bounds__(512) void k_attn_s6(
    const ushort* __restrict__ qg, const ushort* __restrict__ kg,
    const ushort* __restrict__ vg, bf* __restrict__ a) {
  __shared__ ushort Ks[360][40];      /* rows>=358, cols 38/39 zero */
  __shared__ ushort Vt[38][392];      /* cols 358..383 zero         */
  int tid = threadIdx.x;
  int lane = tid & 63, w = tid >> 6;
  int cl = lane & 15, gr = lane >> 4;
  bool g0 = (gr == 0);
  const short8 z8 = {0,0,0,0,0,0,0,0};

  for (int uu = 0; uu < 2; ++uu) {
    int id = blockIdx.x * 2 + uu;
    int h = id & 3; int s = id >> 2;
    int b = s / L_; int l = s % L_;
    long base = (long)(b*L_ + l) * N_;
    if (uu) __syncthreads();
    for (int i = tid; i < 360*20; i += 512) {
      int j = i / 20, t2 = i % 20;
      unsigned u = 0u;
      if (j < N_ && t2 < 19)
        u = *(const unsigned*)(kg + (base + j)*D_ + h*HD_ + 2*t2);
      *(unsigned*)&Ks[j][2*t2] = u;
    }
    for (int i = tid; i < N_*19; i += 512) {
      int j = i / 19, t2 = i % 19;
      unsigned u = *(const unsigned*)(vg + (base + j)*D_ + h*HD_ + 2*t2);
      Vt[2*t2][j]     = (ushort)(u & 0xffffu);
      Vt[2*t2 + 1][j] = (ushort)(u >> 16);
    }
    for (int i = tid; i < 38*26; i += 512)
      Vt[i / 26][N_ + i % 26] = 0;
    __syncthreads();

    for (int qt = w; qt < 23; qt += 8) {
      const ushort* qp = qg + (base + 16*qt + cl) * D_ + h*HD_;
      short8 qB0 = ld_g8(qp + 8*gr);
      short8 qB1 = ld_g8(qp + 32 + 8*gr);
      float sum_ = 0.f;
      float4v accO[3];
      accO[0] = (float4v){0,0,0,0};
      accO[1] = (float4v){0,0,0,0};
      accO[2] = (float4v){0,0,0,0};
#pragma unroll 1
      for (int pr = 0; pr < 11; ++pr) {    /* full tiles: keys 0..351 */
        int k0 = 32*pr;
        int kr0 = k0 + cl;
        int kr1 = k0 + 16 + cl;
        float4v s0a = (float4v){0,0,0,0}, s1a = (float4v){0,0,0,0};
        {
          short8 a00 = *(const short8*)&Ks[kr0][8*gr];
          short8 a10 = *(const short8*)&Ks[kr1][8*gr];
          __builtin_amdgcn_s_setprio(1);
          s0a = __builtin_amdgcn_mfma_f32_16x16x32_bf16(a00, qB0, s0a, 0, 0, 0);
          s1a = __builtin_amdgcn_mfma_f32_16x16x32_bf16(a10, qB0, s1a, 0, 0, 0);
          short8 a01 = g0 ? *(const short8*)&Ks[kr0][32] : z8;
          short8 a11 = g0 ? *(const short8*)&Ks[kr1][32] : z8;
          s0a = __builtin_amdgcn_mfma_f32_16x16x32_bf16(a01, qB1, s0a, 0, 0, 0);
          s1a = __builtin_amdgcn_mfma_f32_16x16x32_bf16(a11, qB1, s1a, 0, 0, 0);
          __builtin_amdgcn_s_setprio(0);
        }
        float p0[4], p1[4];
#pragma unroll
        for (int r = 0; r < 4; ++r) {
          p0[r] = __builtin_exp2f(fminf(s0a[r]*C2_, 80.f));
          p1[r] = __builtin_exp2f(fminf(s1a[r]*C2_, 80.f));
        }
        sum_ += (p0[0] + p0[1]) + (p0[2] + p0[3])
              + (p1[0] + p1[1]) + (p1[2] + p1[3]);
        unsigned u0 = pk_bf(p0[0], p0[1]);
        unsigned u1 = pk_bf(p0[2], p0[3]);
        unsigned u2 = pk_bf(p1[0], p1[1]);
        unsigned u3 = pk_bf(p1[2], p1[3]);
        int srcA = cl + 16*((2*gr) & 3);
        int srcB = srcA + 16;
        unsigned a0 = __shfl(u0, srcA, 64), b0 = __shfl(u1, srcA, 64);
        unsigned c0 = __shfl(u0, srcB, 64), d0 = __shfl(u1, srcB, 64);
        unsigned a2 = __shfl(u2, srcA, 64), b2 = __shfl(u3, srcA, 64);
        unsigned c2 = __shfl(u2, srcB, 64), d2 = __shfl(u3, srcB, 64);
        bool lo = gr < 2;
        union { unsigned u[4]; short8 v; } pbu;
        pbu.u[0] = lo ? a0 : a2;
        pbu.u[1] = lo ? b0 : b2;
        pbu.u[2] = lo ? c0 : c2;
        pbu.u[3] = lo ? d0 : d2;
        short8 pB = pbu.v;
        __builtin_amdgcn_s_setprio(1);
#pragma unroll
        for (int dt = 0; dt < 3; ++dt) {
          short8 aV = (dt < 2 || cl < 6)
              ? *(const short8*)&Vt[16*dt + cl][k0 + 8*gr] : z8;
          accO[dt] = __builtin_amdgcn_mfma_f32_16x16x32_bf16(aV, pB, accO[dt], 0, 0, 0);
        }
        __builtin_amdgcn_s_setprio(0);
      }
      { /* tail tile: keys 352..357 (6 valid) */
        int k0 = 352;
        int kr0 = k0 + cl; if (kr0 > 359) kr0 = 359;
        float4v s0a = (float4v){0,0,0,0};
        {
          short8 a00 = *(const short8*)&Ks[kr0][8*gr];
          s0a = __builtin_amdgcn_mfma_f32_16x16x32_bf16(a00, qB0, s0a, 0, 0, 0);
          short8 a01 = g0 ? *(const short8*)&Ks[kr0][32] : z8;
          s0a = __builtin_amdgcn_mfma_f32_16x16x32_bf16(a01, qB1, s0a, 0, 0, 0);
        }
        float p0[4];
#pragma unroll
        for (int r = 0; r < 4; ++r) {
          float xv = (4*gr + r < 6) ? s0a[r]*C2_ : -1e30f;
          p0[r] = __builtin_exp2f(fminf(xv, 80.f));
        }
        sum_ += (p0[0] + p0[1]) + (p0[2] + p0[3]);
        unsigned u0 = pk_bf(p0[0], p0[1]);
        unsigned u1 = pk_bf(p0[2], p0[3]);
        int srcA = cl + 16*((2*gr) & 3);
        int srcB = srcA + 16;
        unsigned a0 = __shfl(u0, srcA, 64), b0 = __shfl(u1, srcA, 64);
        unsigned c0 = __shfl(u0, srcB, 64), d0 = __shfl(u1, srcB, 64);
        bool lo = gr < 2;
        union { unsigned u[4]; short8 v; } pbu;
        pbu.u[0] = lo ? a0 : 0u;
        pbu.u[1] = lo ? b0 : 0u;
        pbu.u[2] = lo ? c0 : 0u;
        pbu.u[3] = lo ? d0 : 0u;
        short8 pB = pbu.v;
#pragma unroll
        for (int dt = 0; dt < 3; ++dt) {
          short8 aV = (dt < 2 || cl < 6)
              ? *(const short8*)&Vt[16*dt + cl][k0 + 8*gr] : z8;
          accO[dt] = __builtin_amdgcn_mfma_f32_16x16x32_bf16(aV, pB, accO[dt], 0, 0, 0);
        }
      }
      sum_ += __shfl_xor(sum_, 16, 64);
      sum_ += __shfl_xor(sum_, 32, 64);
      int qi = 16*qt + cl;
      if (qi < N_) {
        float inv = 1.f / sum_;
        bf* ap = a + (base + qi)*D_ + h*HD_;
#pragma unroll
        for (int dt = 0; dt < 2; ++dt) {
          *(unsigned*)(ap + 16*dt + 4*gr)     = pk_bf(accO[dt][0]*inv, accO[dt][1]*inv);
          *(unsigned*)(ap + 16*dt + 4*gr + 2) = pk_bf(accO[dt][2]*inv, accO[dt][3]*inv);
        }
        if (gr == 0) {
          *(unsigned*)(ap + 32) = pk_bf(accO[2][0]*inv, accO[2][1]*inv);
          *(unsigned*)(ap + 34) = pk_bf(accO[2][2]*inv, accO[2][3]*inv);
        } else if (gr == 1) {
          *(unsigned*)(ap + 36) = pk_bf(accO[2][0]*inv, accO[2][1]*inv);
        }
      }
    }
  }
}

/* ------------------------------------------------------------------ */
__global__ __launch_bounds__(256) void k_wcomb(
    const float* __restrict__ W_mm, const float* __restrict__ W_ts,
    float* __restrict__ wcomb, float* __restrict__ wevtsum) {
  int i = blockIdx.x * 256 + threadIdx.x;
  if (i < 1824*12) {
    int r = i / 12, p = i % 12, l = r / 152, d = r % 152;
    wcomb[i] = W_mm[(l*408 + 256 + d)*12 + p] + W_ts[i];
  }
  if (i < 256*12) {
    int e = i / 12, p = i % 12;
    float s = 0.f;
    for (int l = 0; l < 12; ++l) s += W_mm[(l*408 + e)*12 + p];
    wevtsum[i] = s;
  }
}

/* ------------------------------------------------------------------ */
__global__ __launch_bounds__(256) void k_evt1(
    const float* __restrict__ marker, const int* __restrict__ doy_idx,
    const float* __restrict__ emb, const float* __restrict__ W_evt,
    const float* __restrict__ b_evt, float* __restrict__ evt_h) {
  int bk = blockIdx.x; int b = bk >> 3; int ks = bk & 7;
  float m3 = marker[((b*L_ + (L_-1))*N_ + 0)*4 + 3];
  int doy = (int)(m3 * 365.f); doy = doy < 0 ? 0 : (doy > 365 ? 365 : doy);
  int idx = doy_idx[doy*8 + ks];
  if (idx < 0 || idx > 4096) idx = 0;
  int d = threadIdx.x;
  float acc = b_evt[d];
  const float* er = emb + (long)idx * 1024;
  for (int e = 0; e < 1024; ++e)
    acc += er[e] * W_evt[e*256 + d];
  evt_h[bk*256 + d] = acc;
}

/* ------------------------------------------------------------------ */
__global__ __launch_bounds__(256) void k_evtpool(
    const float* __restrict__ marker, const void* __restrict__ doy_mask,
    const float* __restrict__ evt_h, float* __restrict__ evtp) {
  __shared__ int hasF32, hasBig;
  if (threadIdx.x == 0) { hasF32 = 0; hasBig = 0; }
  __syncthreads();
  const unsigned* mw = (const unsigned*)doy_mask;
  for (int w = threadIdx.x; w < 732; w += 256) {
    unsigned u = mw[w];
    if (u == 0x3F800000u) hasF32 = 1;
    else if (u > 1u) hasBig = 1;
  }
  __syncthreads();
  int fmt = hasF32 ? 2 : (hasBig ? 1 : 0);
  int b = blockIdx.x;
  float m3 = marker[((b*L_ + (L_-1))*N_ + 0)*4 + 3];
  int doy = (int)(m3 * 365.f); doy = doy < 0 ? 0 : (doy > 365 ? 365 : doy);
  int j = threadIdx.x;
  float mx = -1e30f;
  for (int kx = 0; kx < 8; ++kx) {
    bool mk;
    if (fmt == 2)      mk = ((const float*)doy_mask)[doy*8 + kx] != 0.f;
    else if (fmt == 1) mk = ((const unsigned char*)doy_mask)[doy*8 + kx] != 0;
    else               mk = ((const int*)doy_mask)[doy*8 + kx] != 0;
    if (mk) mx = fmaxf(mx, evt_h[(b*8 + kx)*256 + j]);
  }
  evtp[b*256 + j] = mx;
}

/* ------------------------------------------------------------------ */
__global__ __launch_bounds__(192) void k_final3(
    const bf* __restrict__ x, const float* __restrict__ wcomb,
    const float* __restrict__ wevtsum, const float* __restrict__ evtp,
    const float* __restrict__ b_mm, const float* __restrict__ b_ts,
    float* __restrict__ out) {
  int id = blockIdx.x; int b = id / N_; int n = id % N_;
  __shared__ float xs[1824];
  __shared__ float part[16][12];
  int tid = threadIdx.x;
  for (int e = tid; e < 1824; e += 192) {
    int l = e / 152, d = e % 152;
    xs[e] = bf2f(x[((long)(b*L_ + l) * N_ + n) * 152 + d]);
  }
  __syncthreads();
  int g2 = tid / 12, p = tid % 12;
  float acc = 0.f;
  for (int e = g2; e < 1824; e += 16)
    acc += xs[e] * wcomb[e*12 + p];
  part[g2][p] = acc;
  __syncthreads();
  if (tid < 12) {
    float s = b_mm[tid] + b_ts[tid];
    for (int e = 0; e < 256; ++e) s += evtp[b*256 + e] * wevtsum[e*12 + tid];
    for (int gg = 0; gg < 16; ++gg) s += part[gg][tid];
    out[(b*12 + tid) * N_ + n] = s;
  }
}

/* ------------------------------------------------------------------ */
extern "C" void kernel_launch(void* const* d_in, const int* in_sizes, int n_in,
                              void* d_out, int out_size, void* d_ws, size_t ws_size,
                              hipStream_t stream) {
  static const int expect[32] = {
    68736, 274944, 72, 24, 3456, 168, 343680,
    138624, 912, 138624, 912, 138624, 912, 138624, 912,
    233472, 1536, 233472, 912,
    912, 912, 912, 912,
    4195328, 262144, 256,
    58752, 12, 21888, 12,
    2928, 2928 };
  int nb = (out_size + 255)/256;
  if (n_in != 32) {
    k_beacon<<<nb, 256, 0, stream>>>((float*)d_out, out_size, 998.f);
    return;
  }
  for (int i = 0; i < 32; ++i) {
    if (in_sizes[i] != expect[i]) {
      k_beacon<<<nb, 256, 0, stream>>>((float*)d_out, out_size, 1000.f + i);
      return;
    }
  }
  if (out_size != 68736) {
    k_beacon<<<nb, 256, 0, stream>>>((float*)d_out, out_size, 997.f);
    return;
  }

  const float* var_x  = (const float*)d_in[0];
  const float* marker = (const float*)d_in[1];
  const float* W_in   = (const float*)d_in[2];
  const float* b_in   = (const float*)d_in[3];
  const float* tod    = (const float*)d_in[4];
  const float* dow    = (const float*)d_in[5];
  const float* adap   = (const float*)d_in[6];
  const float* Wq = (const float*)d_in[7];  const float* bq = (const float*)d_in[8];
  const float* Wk = (const float*)d_in[9];  const float* bk = (const float*)d_in[10];
  const float* Wv = (const float*)d_in[11]; const float* bv = (const float*)d_in[12];
  const float* Wo = (const float*)d_in[13]; const float* bo = (const float*)d_in[14];
  const float* W1 = (const float*)d_in[15]; const float* b1 = (const float*)d_in[16];
  const float* W2 = (const float*)d_in[17]; const float* b2 = (const float*)d_in[18];
  const float* g1 = (const float*)d_in[19]; const float* be1 = (const float*)d_in[20];
  const float* g2 = (const float*)d_in[21]; const float* be2 = (const float*)d_in[22];
  const float* emb   = (const float*)d_in[23];
  const float* W_evt = (const float*)d_in[24]; const float* b_evt = (const float*)d_in[25];
  const float* W_mm  = (const float*)d_in[26]; const float* b_mm  = (const float*)d_in[27];
  const float* W_ts  = (const float*)d_in[28]; const float* b_ts  = (const float*)d_in[29];
  const int* doyi = (const int*)d_in[30];
  const void* doym = d_in[31];

  const long TD = (long)TOK_ * D_;
  size_t need = (size_t)TD * 2 * 5
              + (size_t)(32768 + 4096 + 3072 + 21888) * 4
              + 2764800
              + 4096;
  if (ws_size < need) {
    k_beacon<<<nb, 256, 0, stream>>>((float*)d_out, out_size, (float)(ws_size >> 20));
    return;
  }

  bf* x = (bf*)d_ws;
  bf* q = x + TD;
  bf* k = q + TD;
  bf* v = k + TD;
  bf* a = v + TD;
  float* evt_h   = (float*)(a + TD);
  float* evtp    = evt_h + 32768;
  float* wevtsum = evtp + 4096;
  float* wcomb   = wevtsum + 3072;
  ushort* wprep  = (ushort*)(wcomb + 21888);

  k_wprep6<<<2700, 256, 0, stream>>>(Wq, Wk, Wv, Wo, W1, W2, (unsigned*)wprep);
  k_embed2<<<(TOK_ + 255)/256, 256, 0, stream>>>(var_x, marker, W_in, b_in,
                                                 tod, dow, adap, x);
  for (int i = 0; i < 6; ++i) {
    const ushort* pl = wprep + (size_t)i * 230400;
    /* fused QKV projection (64-tok blocks) */
    k_gemm7<152,152,3,64,1,false,false><<<TOK_/64, 512, 0, stream>>>(
        x, pl, bq + i*152, bk + i*152, bv + i*152,
        nullptr, nullptr, nullptr, q, k, v);
    if (i < 3)
      k_attn_t2<<<B_*N_, 256, 0, stream>>>(
          (const ushort*)q, (const ushort*)k, (const ushort*)v, a);
    else
      k_attn_s6<<<B_*L_*2, 512, 0, stream>>>(
          (const ushort*)q, (const ushort*)k, (const ushort*)v, a);
    /* o-proj + residual(x) + LN1 -> k (h)  (128-tok blocks) */
    k_gemm7<152,152,1,128,1,false,true><<<TOK_/128, 512, 0, stream>>>(
        a, pl + 96000, bo + i*152, nullptr, nullptr,
        x, g1 + i*152, be1 + i*152, k, nullptr, nullptr);
    /* FF1 (ReLU): k -> v  (128-tok blocks, col-split steps) */
    k_gemm7<152,256,1,128,2,true,false><<<TOK_/128, 512, 0, stream>>>(
        k, pl + 128000, b1 + i*256, nullptr, nullptr,
        nullptr, nullptr, nullptr, v, nullptr, nullptr);
    /* FF2 + residual(h=k) + LN2 -> x  (64-tok blocks, K=256) */
    k_gemm7<256,152,1,64,1,false,true><<<TOK_/64, 512, 0, stream>>>(
        v, pl + 179200, b2 + i*152, nullptr, nullptr,
        k, g2 + i*152, be2 + i*152, x, nullptr, nullptr);
  }
  k_evt1<<<16*8, 256, 0, stream>>>(marker, doyi, emb, W_evt, b_evt, evt_h);
  k_evtpool<<<16, 256, 0, stream>>>(marker, doym, evt_h, evtp);
  k_wcomb<<<(1824*12 + 255)/256, 256, 0, stream>>>(W_mm, W_ts, wcomb, wevtsum);
  k_final3<<<B_*N_, 192, 0, stream>>>(x, wcomb, wevtsum, evtp, b_mm, b_ts,
                                      (float*)d_out);
}

// Round 6
// 1121.677 us; speedup vs baseline: 4.4539x; 1.0594x over previous
//
#include <hip/hip_runtime.h>
#include <hip/hip_bf16.h>

using bf = __hip_bfloat16;

#define B_   16
#define L_   12
#define N_   358
#define D_   152
#define TOK_ (B_*L_*N_)   /* 68736 */
#define FF_  256
#define HD_  38
#define SCALE_ 0.16222142113076254f  /* 38^-0.5 */
#define C2_   0.23403921469340696f   /* SCALE_ * log2(e) */

__device__ __forceinline__ float bf2f(bf x) { return __bfloat162float(x); }
__device__ __forceinline__ bf f2bf(float f) { return __float2bfloat16(f); }
__device__ __forceinline__ float lo_bf(unsigned u) { return __uint_as_float(u << 16); }
__device__ __forceinline__ float hi_bf(unsigned u) { return __uint_as_float(u & 0xffff0000u); }
__device__ __forceinline__ unsigned pk_bf(float a, float b) {
  union { bf h; unsigned short u; } A, Bu;
  A.h = f2bf(a); Bu.h = f2bf(b);
  return ((unsigned)Bu.u << 16) | A.u;
}
__device__ __forceinline__ ushort f2bf_u(float f) {
  union { bf h; ushort u; } t; t.h = f2bf(f); return t.u;
}

using short8  = __attribute__((ext_vector_type(8))) short;
using float4v = __attribute__((ext_vector_type(4))) float;

/* async global->LDS, 16B per lane; dst is wave-uniform base (HW adds lane*16) */
__device__ __forceinline__ void gl_lds16(const void* g, void* l) {
  __builtin_amdgcn_global_load_lds(
      (const __attribute__((address_space(1))) void*)g,
      (__attribute__((address_space(3))) void*)l, 16, 0, 0);
}

/* copy SUBCB bytes global->LDS; 8 waves interleave 1024B blocks */
template<int SUBCB>
__device__ __forceinline__ void issue_w8(const char* gsrc, ushort* lds, int w, int lane) {
  constexpr int TB = SUBCB >> 10;
  constexpr int TAIL = SUBCB & 1023;
#pragma unroll
  for (int blk0 = 0; blk0 < TB; blk0 += 8) {
    int blk = blk0 + w;
    if (blk < TB)
      gl_lds16(gsrc + blk*1024 + (size_t)lane*16, (char*)lds + blk*1024);
  }
  if (TAIL) {
    if (w == (TB & 7) && lane < TAIL/16)
      gl_lds16(gsrc + TB*1024 + (size_t)lane*16, (char*)lds + TB*1024);
  }
}

/* 16B logical load from a 4B-aligned (not necessarily 16B-aligned) address */
__device__ __forceinline__ short8 ld_g8(const ushort* p) {
  union { unsigned u[4]; short8 v; } t;
  t.u[0] = *(const unsigned*)(p);
  t.u[1] = *(const unsigned*)(p + 2);
  t.u[2] = *(const unsigned*)(p + 4);
  t.u[3] = *(const unsigned*)(p + 6);
  return t.v;
}

/* ------------------------------------------------------------------ */
__global__ void k_beacon(float* out, int n, float val) {
  int i = blockIdx.x * 256 + threadIdx.x;
  if (i < n) out[i] = val;
}

/* ================= fused prep: wprep | embed | evt1 | wcomb ======= */
#define WPREP_B 2700
#define EMB_B   269
#define EVT_B   128
#define WC_B    86
#define PREP_B  (WPREP_B + EMB_B + EVT_B + WC_B)   /* 3183 */

__device__ void d_wprep(int bid, int tid,
    const float* __restrict__ Wq, const float* __restrict__ Wk,
    const float* __restrict__ Wv, const float* __restrict__ Wo,
    const float* __restrict__ W1, const float* __restrict__ W2,
    unsigned* __restrict__ out) {
  int i = bid * 256 + tid;
  if (i >= 6*115200) return;
  int layer = i / 115200, r = i % 115200;
  const float* src; int K, Nd, d, up, c;
  if (r < 48000) {
    c = r / 9600; int rr = r % 9600; int m = rr / 3200; int r2 = rr % 3200;
    d = r2 / 20; up = r2 % 20;
    src = (m == 0 ? Wq : (m == 1 ? Wk : Wv)) + layer*23104; K = 152; Nd = 152;
  } else if (r < 64000) {
    int rr = r - 48000; c = rr / 3200; int r2 = rr % 3200;
    d = r2 / 20; up = r2 % 20;
    src = Wo + layer*23104; K = 152; Nd = 152;
  } else if (r < 89600) {
    int rr = r - 64000; c = rr / 5120; int r2 = rr % 5120;
    d = r2 / 20; up = r2 % 20;
    src = W1 + layer*38912; K = 152; Nd = 256;
  } else {
    int rr = r - 89600; c = rr / 3200; int r2 = rr % 3200;
    d = r2 / 20; up = r2 % 20;
    src = W2 + layer*38912; K = 256; Nd = 152;
  }
  float v0 = 0.f, v1 = 0.f;
  int k0 = 32*c + 2*up;
  if (up < 16 && d < Nd) {
    if (k0 < K)     v0 = src[(long)k0*Nd + d];
    if (k0 + 1 < K) v1 = src[(long)(k0+1)*Nd + d];
  }
  out[i] = pk_bf(v0, v1);
}

__device__ void d_embed(int bid, int tid,
    const float* __restrict__ var_x, const float* __restrict__ marker,
    const float* __restrict__ W_in, const float* __restrict__ b_in,
    const float* __restrict__ tod_emb, const float* __restrict__ dow_emb,
    const float* __restrict__ adap, bf* __restrict__ x) {
  int t = bid * 256 + tid;
  if (t >= TOK_) return;
  int n = t % N_;
  int l = (t / N_) % L_;
  float var = var_x[t];
  float m0 = marker[t*4 + 0];
  float m1 = marker[t*4 + 1];
  int tod = (int)(m0 * 144.f); tod = tod < 0 ? 0 : (tod > 143 ? 143 : tod);
  int dw  = (int)(m1 * 7.f);   dw  = dw  < 0 ? 0 : (dw  > 6   ? 6   : dw);
  bf* xp = x + (long)t * D_;
  for (int d = 0; d < 24; ++d)
    xp[d] = f2bf(var * W_in[d] + m0 * W_in[24 + d] + m1 * W_in[48 + d] + b_in[d]);
  for (int d = 0; d < 24; ++d) xp[24 + d] = f2bf(tod_emb[tod*24 + d]);
  for (int d = 0; d < 24; ++d) xp[48 + d] = f2bf(dow_emb[dw*24 + d]);
  for (int d = 0; d < 80; ++d) xp[72 + d] = f2bf(adap[(l*N_ + n)*80 + d]);
}

__device__ void d_evt1(int bk, int tid,
    const float* __restrict__ marker, const int* __restrict__ doy_idx,
    const float* __restrict__ emb, const float* __restrict__ W_evt,
    const float* __restrict__ b_evt, float* __restrict__ evt_h) {
  int b = bk >> 3; int ks = bk & 7;
  float m3 = marker[((b*L_ + (L_-1))*N_ + 0)*4 + 3];
  int doy = (int)(m3 * 365.f); doy = doy < 0 ? 0 : (doy > 365 ? 365 : doy);
  int idx = doy_idx[doy*8 + ks];
  if (idx < 0 || idx > 4096) idx = 0;
  int d = tid;
  float acc = b_evt[d];
  const float* er = emb + (long)idx * 1024;
  for (int e = 0; e < 1024; ++e)
    acc += er[e] * W_evt[e*256 + d];
  evt_h[bk*256 + d] = acc;
}

__device__ void d_wcomb(int bid, int tid,
    const float* __restrict__ W_mm, const float* __restrict__ W_ts,
    float* __restrict__ wcomb, float* __restrict__ wevtsum) {
  int i = bid * 256 + tid;
  if (i < 1824*12) {
    int r = i / 12, p = i % 12, l = r / 152, d = r % 152;
    wcomb[i] = W_mm[(l*408 + 256 + d)*12 + p] + W_ts[i];
  }
  if (i < 256*12) {
    int e = i / 12, p = i % 12;
    float s = 0.f;
    for (int l = 0; l < 12; ++l) s += W_mm[(l*408 + e)*12 + p];
    wevtsum[i] = s;
  }
}

__global__ __launch_bounds__(256) void k_prep(
    const float* Wq, const float* Wk, const float* Wv, const float* Wo,
    const float* W1, const float* W2, unsigned* wout,
    const float* var_x, const float* marker, const float* W_in,
    const float* b_in, const float* tod_emb, const float* dow_emb,
    const float* adap, bf* x,
    const int* doyi, const float* emb, const float* W_evt,
    const float* b_evt, float* evt_h,
    const float* W_mm, const float* W_ts, float* wcomb, float* wevtsum) {
  int bid = blockIdx.x, tid = threadIdx.x;
  if (bid < WPREP_B)
    d_wprep(bid, tid, Wq, Wk, Wv, Wo, W1, W2, wout);
  else if (bid < WPREP_B + EMB_B)
    d_embed(bid - WPREP_B, tid, var_x, marker, W_in, b_in, tod_emb, dow_emb, adap, x);
  else if (bid < WPREP_B + EMB_B + EVT_B)
    d_evt1(bid - WPREP_B - EMB_B, tid, marker, doyi, emb, W_evt, b_evt, evt_h);
  else
    d_wcomb(bid - WPREP_B - EMB_B - EVT_B, tid, W_mm, W_ts, wcomb, wevtsum);
}

/* ------------------------------------------------------------------ */
/* GEMM v7 (round-4 proven): 512 threads / 8 waves; 4 row x 2 col.    */
template<int K, int Nd, int NW, int TOKB, int CSPLIT, bool RELU, bool LN>
__global__ __launch_bounds__(512) void k_gemm7(
    const bf* __restrict__ X, const ushort* __restrict__ Wg,
    const float* __restrict__ bi0, const float* __restrict__ bi1,
    const float* __restrict__ bi2, const bf* __restrict__ Res,
    const float* __restrict__ g, const float* __restrict__ bb,
    bf* __restrict__ Y0, bf* __restrict__ Y1, bf* __restrict__ Y2) {
  constexpr int NJ   = (Nd + 15) / 16;
  constexpr int NdP  = NJ * 16;
  constexpr int KC   = (K + 31) / 32;
  constexpr int G    = NW * CSPLIT;
  constexpr int S    = KC * G;
  constexpr int IR   = NdP / CSPLIT;
  constexpr int SUB_USH = IR * 40;
  constexpr int SUBCB   = SUB_USH * 2;
  constexpr int NJW  = IR / 32;
  constexpr int MR   = TOKB / 64;
  constexpr bool GLX = (K == 152);
  constexpr int XSTR = GLX ? K : (K + 8);
  __shared__ __align__(16) ushort Xs[TOKB * XSTR + 8];
  __shared__ __align__(16) ushort Wb[2 * SUB_USH];
  long row0 = (long)blockIdx.x * TOKB;
  int tid = threadIdx.x;
  int lane = tid & 63, w = tid >> 6;
  int cl = lane & 15, gr = lane >> 4;
  int wr = w >> 1, wc = w & 1;
  if constexpr (GLX) {
    constexpr int TBX = TOKB * K * 2 / 1024;
    const char* Xgc = (const char*)(X + row0 * K);
#pragma unroll
    for (int b0 = 0; b0 < TBX; b0 += 8) {
      int blk = b0 + w;
      if (blk < TBX)
        gl_lds16(Xgc + blk*1024 + (size_t)lane*16, (char*)Xs + blk*1024);
    }
  } else {
    const char* Xgc = (const char*)(X + row0 * K);
    for (int i = tid; i < TOKB*(K/8); i += 512) {
      int r = i / (K/8), c = i % (K/8);
      *(short8*)&Xs[r*XSTR + 8*c] = *(const short8*)(Xgc + r*(K*2) + c*16);
    }
  }
  const char* gW = (const char*)Wg;
  issue_w8<SUBCB>(gW, Wb, w, lane);
  __syncthreads();
  float4v acc[G][MR][NJW];
#pragma unroll
  for (int gi = 0; gi < G; ++gi)
#pragma unroll
    for (int mi = 0; mi < MR; ++mi)
#pragma unroll
      for (int j = 0; j < NJW; ++j) acc[gi][mi][j] = (float4v){0.f,0.f,0.f,0.f};
#pragma unroll
  for (int s = 0; s < S; ++s) {
    if (s + 1 < S)
      issue_w8<SUBCB>(gW + (size_t)(s+1)*SUBCB, Wb + ((s+1)&1)*SUB_USH, w, lane);
    int kc = (s / G) * 32;
    const ushort* wb = Wb + (s&1)*SUB_USH;
    short8 af[MR];
#pragma unroll
    for (int mi = 0; mi < MR; ++mi)
      af[mi] = *(const short8*)&Xs[((TOKB/4)*wr + 16*mi + cl)*XSTR + kc + 8*gr];
#pragma unroll
    for (int j = 0; j < NJW; ++j) {
      short8 bv = *(const short8*)&wb[((IR/2)*wc + 16*j + cl)*40 + 8*gr];
#pragma unroll
      for (int mi = 0; mi < MR; ++mi)
        acc[s % G][mi][j] =
            __builtin_amdgcn_mfma_f32_16x16x32_bf16(af[mi], bv, acc[s % G][mi][j], 0, 0, 0);
    }
    __syncthreads();
  }
  if constexpr (!LN) {
#pragma unroll
    for (int gi = 0; gi < G; ++gi) {
      bf* Y = (NW > 1) ? (gi == 0 ? Y0 : (gi == 1 ? Y1 : Y2)) : Y0;
      const float* bp = (NW > 1) ? (gi == 0 ? bi0 : (gi == 1 ? bi1 : bi2)) : bi0;
      int colb = (CSPLIT > 1 ? IR*gi : 0) + (IR/2)*wc;
#pragma unroll
      for (int j = 0; j < NJW; ++j) {
        int col = colb + 16*j + cl;
        if (col < Nd) {
          float bvs = bp[col];
#pragma unroll
          for (int mi = 0; mi < MR; ++mi) {
            long rw = row0 + (TOKB/4)*wr + 16*mi + 4*gr;
#pragma unroll
            for (int r = 0; r < 4; ++r) {
              float val = acc[gi][mi][j][r] + bvs;
              if (RELU) val = fmaxf(val, 0.f);
              Y[(rw + r) * Nd + col] = f2bf(val);
            }
          }
        }
      }
    }
  } else {
    float* LNb = (float*)Wb;
    int colb = (IR/2)*wc;
#pragma unroll
    for (int j = 0; j < NJW; ++j) {
      int col = colb + 16*j + cl;
      if (col < Nd) {
        float bvs = bi0[col];
#pragma unroll
        for (int mi = 0; mi < MR; ++mi) {
          long rw = row0 + (TOKB/4)*wr + 16*mi + 4*gr;
#pragma unroll
          for (int r = 0; r < 4; ++r)
            acc[0][mi][j][r] += bvs + bf2f(Res[(rw + r) * Nd + col]);
        }
      }
    }
    float mean[MR][4], rs[MR][4];
#pragma unroll
    for (int mi = 0; mi < MR; ++mi)
#pragma unroll
      for (int r = 0; r < 4; ++r) {
        float s = 0.f;
#pragma unroll
        for (int j = 0; j < NJW; ++j) s += acc[0][mi][j][r];
        s += __shfl_xor(s, 1, 64); s += __shfl_xor(s, 2, 64);
        s += __shfl_xor(s, 4, 64); s += __shfl_xor(s, 8, 64);
        if (cl == 0) LNb[((wr*MR + mi)*2 + wc)*16 + 4*gr + r] = s;
      }
    __syncthreads();
#pragma unroll
    for (int mi = 0; mi < MR; ++mi)
#pragma unroll
      for (int r = 0; r < 4; ++r) {
        float tot = LNb[((wr*MR + mi)*2 + 0)*16 + 4*gr + r]
                  + LNb[((wr*MR + mi)*2 + 1)*16 + 4*gr + r];
        mean[mi][r] = tot * (1.f / (float)Nd);
      }
#pragma unroll
    for (int mi = 0; mi < MR; ++mi)
#pragma unroll
      for (int r = 0; r < 4; ++r) {
        float s2 = 0.f;
#pragma unroll
        for (int j = 0; j < NJW; ++j) {
          int col = colb + 16*j + cl;
          if (col < Nd) {
            float dv = acc[0][mi][j][r] - mean[mi][r];
            s2 += dv*dv;
          }
        }
        s2 += __shfl_xor(s2, 1, 64); s2 += __shfl_xor(s2, 2, 64);
        s2 += __shfl_xor(s2, 4, 64); s2 += __shfl_xor(s2, 8, 64);
        if (cl == 0) LNb[256 + ((wr*MR + mi)*2 + wc)*16 + 4*gr + r] = s2;
      }
    __syncthreads();
#pragma unroll
    for (int mi = 0; mi < MR; ++mi)
#pragma unroll
      for (int r = 0; r < 4; ++r) {
        float tot2 = LNb[256 + ((wr*MR + mi)*2 + 0)*16 + 4*gr + r]
                   + LNb[256 + ((wr*MR + mi)*2 + 1)*16 + 4*gr + r];
        rs[mi][r] = rsqrtf(tot2 * (1.f / (float)Nd) + 1e-5f);
      }
#pragma unroll
    for (int j = 0; j < NJW; ++j) {
      int col = colb + 16*j + cl;
      if (col < Nd) {
        float gv = g[col], bv2 = bb[col];
#pragma unroll
        for (int mi = 0; mi < MR; ++mi) {
          long rw = row0 + (TOKB/4)*wr + 16*mi + 4*gr;
#pragma unroll
          for (int r = 0; r < 4; ++r)
            Y0[(rw + r) * Nd + col] =
                f2bf((acc[0][mi][j][r] - mean[mi][r]) * rs[mi][r] * gv + bv2);
        }
      }
    }
  }
}

/* ------------------------------------------------------------------ */
/* Fused FFN: y = LN( relu(X@W1+b1)@W2 + b2 + Res ).  64 tok/block.
   FF1 (K=152->256, col-split steps) accumulates in regs; h = bias+relu
   written bf16 to LDS Hs[64][260] (stride 520B: bank(2r) distinct ->
   conflict-free A-frag reads). FF2 (K=256->152) streams W2, A from Hs.
   LDS arena time-multiplexed: {Xs[0,9728) W1b[9728,19968)} then
   {Hs[0,16640) W2b[16640,29440)} - switch after FF1's last barrier.  */
__global__ __launch_bounds__(512) void k_ffn(
    const bf* __restrict__ X, const ushort* __restrict__ W1g,
    const ushort* __restrict__ W2g,
    const float* __restrict__ b1, const float* __restrict__ b2,
    const bf* __restrict__ Res, const float* __restrict__ g,
    const float* __restrict__ bb, bf* __restrict__ Y) {
  constexpr int S1 = 10, SUB1 = 5120;   /* 5 chunks x 2 col-halves */
  constexpr int S2 = 8,  SUB2 = 6400;
  constexpr int HSTR = 260;
  __shared__ __align__(16) ushort S_[29440];   /* 58880 B */
  ushort* Xs  = S_;
  ushort* W1b = S_ + 9728;
  ushort* Hs  = S_;
  ushort* W2b = S_ + 16640;
  long row0 = (long)blockIdx.x * 64;
  int tid = threadIdx.x, lane = tid & 63, w = tid >> 6;
  int cl = lane & 15, gr = lane >> 4;
  int wr = w >> 1, wc = w & 1;
  {  /* stage X: 64x152x2 = 19456 B = 19 blocks */
    const char* Xgc = (const char*)(X + row0 * 152);
#pragma unroll
    for (int b0 = 0; b0 < 19; b0 += 8) {
      int blk = b0 + w;
      if (blk < 19)
        gl_lds16(Xgc + blk*1024 + (size_t)lane*16, (char*)Xs + blk*1024);
    }
  }
  issue_w8<SUB1*2>((const char*)W1g, W1b, w, lane);
  __syncthreads();
  float4v acc1[2][4];
#pragma unroll
  for (int g2 = 0; g2 < 2; ++g2)
#pragma unroll
    for (int j = 0; j < 4; ++j) acc1[g2][j] = (float4v){0.f,0.f,0.f,0.f};
#pragma unroll
  for (int s = 0; s < S1; ++s) {
    if (s + 1 < S1)
      issue_w8<SUB1*2>((const char*)W1g + (size_t)(s+1)*SUB1*2,
                       W1b + ((s+1)&1)*SUB1, w, lane);
    int kc = (s / 2) * 32;
    const ushort* wb = W1b + (s&1)*SUB1;
    short8 af = *(const short8*)&Xs[(16*wr + cl)*152 + kc + 8*gr];
#pragma unroll
    for (int j = 0; j < 4; ++j) {
      short8 bv = *(const short8*)&wb[(64*wc + 16*j + cl)*40 + 8*gr];
      acc1[s&1][j] =
          __builtin_amdgcn_mfma_f32_16x16x32_bf16(af, bv, acc1[s&1][j], 0, 0, 0);
    }
    __syncthreads();            /* last iter: all Xs/W1b reads done */
  }
  /* h = relu(acc+b1) -> Hs (overwrites Xs/W1b region: dead) */
#pragma unroll
  for (int g2 = 0; g2 < 2; ++g2)
#pragma unroll
    for (int j = 0; j < 4; ++j) {
      int col = g2*128 + 64*wc + 16*j + cl;
      float bvs = b1[col];
#pragma unroll
      for (int r = 0; r < 4; ++r) {
        int row = 16*wr + 4*gr + r;
        Hs[row*HSTR + col] = f2bf_u(fmaxf(acc1[g2][j][r] + bvs, 0.f));
      }
    }
  issue_w8<SUB2*2>((const char*)W2g, W2b, w, lane);
  __syncthreads();              /* h visible + W2 chunk0 drained */
  float4v acc2[5];
#pragma unroll
  for (int j = 0; j < 5; ++j) acc2[j] = (float4v){0.f,0.f,0.f,0.f};
#pragma unroll
  for (int s = 0; s < S2; ++s) {
    if (s + 1 < S2)
      issue_w8<SUB2*2>((const char*)W2g + (size_t)(s+1)*SUB2*2,
                       W2b + ((s+1)&1)*SUB2, w, lane);
    int kc = s * 32;
    const ushort* wb = W2b + (s&1)*SUB2;
    short8 af = *(const short8*)&Hs[(16*wr + cl)*HSTR + kc + 8*gr];
#pragma unroll
    for (int j = 0; j < 5; ++j) {
      short8 bv = *(const short8*)&wb[(80*wc + 16*j + cl)*40 + 8*gr];
      acc2[j] =
          __builtin_amdgcn_mfma_f32_16x16x32_bf16(af, bv, acc2[j], 0, 0, 0);
    }
    __syncthreads();
  }
  /* residual + LayerNorm epilogue (gemm7 LN path, MR=1, NJW=5) */
  float* LNb = (float*)W2b;
  int colb = 80*wc;
#pragma unroll
  for (int j = 0; j < 5; ++j) {
    int col = colb + 16*j + cl;
    if (col < D_) {
      float bvs = b2[col];
#pragma unroll
      for (int r = 0; r < 4; ++r)
        acc2[j][r] += bvs + bf2f(Res[(row0 + 16*wr + 4*gr + r) * D_ + col]);
    }
  }
  float mean[4], rsv[4];
#pragma unroll
  for (int r = 0; r < 4; ++r) {
    float s = 0.f;
#pragma unroll
    for (int j = 0; j < 5; ++j)
      if (colb + 16*j + cl < D_) s += acc2[j][r];
    s += __shfl_xor(s, 1, 64); s += __shfl_xor(s, 2, 64);
    s += __shfl_xor(s, 4, 64); s += __shfl_xor(s, 8, 64);
    if (cl == 0) LNb[(wr*2 + wc)*16 + 4*gr + r] = s;
  }
  __syncthreads();
#pragma unroll
  for (int r = 0; r < 4; ++r) {
    float tot = LNb[(wr*2 + 0)*16 + 4*gr + r] + LNb[(wr*2 + 1)*16 + 4*gr + r];
    mean[r] = tot * (1.f / (float)D_);
  }
#pragma unroll
  for (int r = 0; r < 4; ++r) {
    float s2 = 0.f;
#pragma unroll
    for (int j = 0; j < 5; ++j) {
      int col = colb + 16*j + cl;
      if (col < D_) { float dv = acc2[j][r] - mean[r]; s2 += dv*dv; }
    }
    s2 += __shfl_xor(s2, 1, 64); s2 += __shfl_xor(s2, 2, 64);
    s2 += __shfl_xor(s2, 4, 64); s2 += __shfl_xor(s2, 8, 64);
    if (cl == 0) LNb[128 + (wr*2 + wc)*16 + 4*gr + r] = s2;
  }
  __syncthreads();
#pragma unroll
  for (int r = 0; r < 4; ++r) {
    float tot2 = LNb[128 + (wr*2 + 0)*16 + 4*gr + r]
               + LNb[128 + (wr*2 + 1)*16 + 4*gr + r];
    rsv[r] = rsqrtf(tot2 * (1.f / (float)D_) + 1e-5f);
  }
#pragma unroll
  for (int j = 0; j < 5; ++j) {
    int col = colb + 16*j + cl;
    if (col < D_) {
      float gv = g[col], bv2 = bb[col];
#pragma unroll
      for (int r = 0; r < 4; ++r)
        Y[(row0 + 16*wr + 4*gr + r) * D_ + col] =
            f2bf((acc2[j][r] - mean[r]) * rsv[r] * gv + bv2);
    }
  }
}

/* ------------------------------------------------------------------ */
/* Temporal attention v2 (round-5 proven): MFMA swapped-operand.      */
__global__ __launch_bounds__(256) void k_attn_t2(
    const ushort* __restrict__ qg, const ushort* __restrict__ kg,
    const ushort* __restrict__ vg, bf* __restrict__ a) {
  int id = blockIdx.x; int b = id / N_; int n = id % N_;
  __shared__ ushort Ksh[4][16][40];
  __shared__ ushort Qsh[4][16][40];
  __shared__ ushort Vth[4][40][16];
  int tid = threadIdx.x;
  for (int i = tid; i < 1280; i += 256) {
    ((unsigned*)Ksh)[i] = 0u; ((unsigned*)Qsh)[i] = 0u; ((unsigned*)Vth)[i] = 0u;
  }
  __syncthreads();
  for (int i = tid; i < 4*12*19; i += 256) {
    int h = i / 228, r = i % 228, l = r / 19, t2 = r % 19;
    long off = ((long)(b*L_ + l) * N_ + n) * D_ + h*HD_ + 2*t2;
    *(unsigned*)&Ksh[h][l][2*t2] = *(const unsigned*)(kg + off);
    *(unsigned*)&Qsh[h][l][2*t2] = *(const unsigned*)(qg + off);
  }
  for (int i = tid; i < 4*12*19; i += 256) {
    int h = i / 228, r = i % 228, l = r / 19, t2 = r % 19;
    long off = ((long)(b*L_ + l) * N_ + n) * D_ + h*HD_ + 2*t2;
    unsigned u = *(const unsigned*)(vg + off);
    Vth[h][2*t2][l]     = (ushort)(u & 0xffffu);
    Vth[h][2*t2 + 1][l] = (ushort)(u >> 16);
  }
  __syncthreads();
  int lane = tid & 63, w = tid >> 6;
  int cl = lane & 15, gr = lane >> 4;
  const short8 z8 = {0,0,0,0,0,0,0,0};
  short8 a00 = *(const short8*)&Ksh[w][cl][8*gr];
  short8 qB0 = *(const short8*)&Qsh[w][cl][8*gr];
  short8 a01 = (gr == 0) ? *(const short8*)&Ksh[w][cl][32] : z8;
  short8 qB1 = (gr == 0) ? *(const short8*)&Qsh[w][cl][32] : z8;
  float4v sa = (float4v){0,0,0,0};
  sa = __builtin_amdgcn_mfma_f32_16x16x32_bf16(a00, qB0, sa, 0, 0, 0);
  sa = __builtin_amdgcn_mfma_f32_16x16x32_bf16(a01, qB1, sa, 0, 0, 0);
  float p[4];
#pragma unroll
  for (int r = 0; r < 4; ++r) {
    float xv = (4*gr + r < 12) ? sa[r]*C2_ : -1e30f;
    p[r] = __builtin_exp2f(fminf(xv, 80.f));
  }
  float sum_ = (p[0] + p[1]) + (p[2] + p[3]);
  sum_ += __shfl_xor(sum_, 16, 64);
  sum_ += __shfl_xor(sum_, 32, 64);
  unsigned u0 = pk_bf(p[0], p[1]);
  unsigned u1 = pk_bf(p[2], p[3]);
  int srcA = cl + 32*(gr & 1);
  int srcB = srcA + 16;
  unsigned w0 = __shfl(u0, srcA, 64), w1 = __shfl(u1, srcA, 64);
  unsigned w2 = __shfl(u0, srcB, 64), w3 = __shfl(u1, srcB, 64);
  union { unsigned u[4]; short8 v; } pbu;
  bool gv = gr < 2;
  pbu.u[0] = gv ? w0 : 0u; pbu.u[1] = gv ? w1 : 0u;
  pbu.u[2] = gv ? w2 : 0u; pbu.u[3] = gv ? w3 : 0u;
  short8 pB = pbu.v;
  float4v accO[3];
#pragma unroll
  for (int dt = 0; dt < 3; ++dt) {
    short8 aV = (gv && (dt < 2 || cl < 8))
        ? *(const short8*)&Vth[w][16*dt + cl][8*gr] : z8;
    accO[dt] = (float4v){0,0,0,0};
    accO[dt] = __builtin_amdgcn_mfma_f32_16x16x32_bf16(aV, pB, accO[dt], 0, 0, 0);
  }
  if (cl < 12) {
    float inv = 1.f / sum_;
    bf* ap = a + ((long)(b*L_ + cl) * N_ + n) * D_ + w*HD_;
#pragma unroll
    for (int dt = 0; dt < 2; ++dt) {
      *(unsigned*)(ap + 16*dt + 4*gr)     = pk_bf(accO[dt][0]*inv, accO[dt][1]*inv);
      *(unsigned*)(ap + 16*dt + 4*gr + 2) = pk_bf(accO[dt][2]*inv, accO[dt][3]*inv);
    }
    if (gr == 0) {
      *(unsigned*)(ap + 32) = pk_bf(accO[2][0]*inv, accO[2][1]*inv);
      *(unsigned*)(ap + 34) = pk_bf(accO[2][2]*inv, accO[2][3]*inv);
    } else if (gr == 1) {
      *(unsigned*)(ap + 36) = pk_bf(accO[2][0]*inv, accO[2][1]*inv);
    }
  }
}

/* ------------------------------------------------------------------ */
/* Spatial attention v6 (round-5 proven).                             */
__global__ __launch_bounds__(512) void k_attn_s6(
    const ushort* __restrict__ qg, const ushort* __restrict__ kg,
    const ushort* __restrict__ vg, bf* __restrict__ a) {
  __shared__ ushort Ks[360][40];
  __shared__ ushort Vt[38][392];
  int tid = threadIdx.x;
  int lane = tid & 63, w = tid >> 6;
  int cl = lane & 15, gr = lane >> 4;
  bool g0 = (gr == 0);
  const short8 z8 = {0,0,0,0,0,0,0,0};

  for (int uu = 0; uu < 2; ++uu) {
    int id = blockIdx.x * 2 + uu;
    int h = id & 3; int s = id >> 2;
    int b = s / L_; int l = s % L_;
    long base = (long)(b*L_ + l) * N_;
    if (uu) __syncthreads();
    for (int i = tid; i < 360*20; i += 512) {
      int j = i / 20, t2 = i % 20;
      unsigned u = 0u;
      if (j < N_ && t2 < 19)
        u = *(const unsigned*)(kg + (base + j)*D_ + h*HD_ + 2*t2);
      *(unsigned*)&Ks[j][2*t2] = u;
    }
    for (int i = tid; i < N_*19; i += 512) {
      int j = i / 19, t2 = i % 19;
      unsigned u = *(const unsigned*)(vg + (base + j)*D_ + h*HD_ + 2*t2);
      Vt[2*t2][j]     = (ushort)(u & 0xffffu);
      Vt[2*t2 + 1][j] = (ushort)(u >> 16);
    }
    for (int i = tid; i < 38*26; i += 512)
      Vt[i / 26][N_ + i % 26] = 0;
    __syncthreads();

    for (int qt = w; qt < 23; qt += 8) {
      const ushort* qp = qg + (base + 16*qt + cl) * D_ + h*HD_;
      short8 qB0 = ld_g8(qp + 8*gr);
      short8 qB1 = ld_g8(qp + 32 + 8*gr);
      float sum_ = 0.f;
      float4v accO[3];
      accO[0] = (float4v){0,0,0,0};
      accO[1] = (float4v){0,0,0,0};
      accO[2] = (float4v){0,0,0,0};
#pragma unroll 1
      for (int pr = 0; pr < 11; ++pr) {
        int k0 = 32*pr;
        int kr0 = k0 + cl;
        int kr1 = k0 + 16 + cl;
        float4v s0a = (float4v){0,0,0,0}, s1a = (float4v){0,0,0,0};
        {
          short8 a00 = *(const short8*)&Ks[kr0][8*gr];
          short8 a10 = *(const short8*)&Ks[kr1][8*gr];
          __builtin_amdgcn_s_setprio(1);
          s0a = __builtin_amdgcn_mfma_f32_16x16x32_bf16(a00, qB0, s0a, 0, 0, 0);
          s1a = __builtin_amdgcn_mfma_f32_16x16x32_bf16(a10, qB0, s1a, 0, 0, 0);
          short8 a01 = g0 ? *(const short8*)&Ks[kr0][32] : z8;
          short8 a11 = g0 ? *(const short8*)&Ks[kr1][32] : z8;
          s0a = __builtin_amdgcn_mfma_f32_16x16x32_bf16(a01, qB1, s0a, 0, 0, 0);
          s1a = __builtin_amdgcn_mfma_f32_16x16x32_bf16(a11, qB1, s1a, 0, 0, 0);
          __builtin_amdgcn_s_setprio(0);
        }
        float p0[4], p1[4];
#pragma unroll
        for (int r = 0; r < 4; ++r) {
          p0[r] = __builtin_exp2f(fminf(s0a[r]*C2_, 80.f));
          p1[r] = __builtin_exp2f(fminf(s1a[r]*C2_, 80.f));
        }
        sum_ += (p0[0] + p0[1]) + (p0[2] + p0[3])
              + (p1[0] + p1[1]) + (p1[2] + p1[3]);
        unsigned u0 = pk_bf(p0[0], p0[1]);
        unsigned u1 = pk_bf(p0[2], p0[3]);
        unsigned u2 = pk_bf(p1[0], p1[1]);
        unsigned u3 = pk_bf(p1[2], p1[3]);
        int srcA = cl + 16*((2*gr) & 3);
        int srcB = srcA + 16;
        unsigned a0 = __shfl(u0, srcA, 64), b0 = __shfl(u1, srcA, 64);
        unsigned c0 = __shfl(u0, srcB, 64), d0 = __shfl(u1, srcB, 64);
        unsigned a2 = __shfl(u2, srcA, 64), b2 = __shfl(u3, srcA, 64);
        unsigned c2 = __shfl(u2, srcB, 64), d2 = __shfl(u3, srcB, 64);
        bool lo = gr < 2;
        union { unsigned u[4]; short8 v; } pbu;
        pbu.u[0] = lo ? a0 : a2;
        pbu.u[1] = lo ? b0 : b2;
        pbu.u[2] = lo ? c0 : c2;
        pbu.u[3] = lo ? d0 : d2;
        short8 pB = pbu.v;
        __builtin_amdgcn_s_setprio(1);
#pragma unroll
        for (int dt = 0; dt < 3; ++dt) {
          short8 aV = (dt < 2 || cl < 6)
              ? *(const short8*)&Vt[16*dt + cl][k0 + 8*gr] : z8;
          accO[dt] = __builtin_amdgcn_mfma_f32_16x16x32_bf16(aV, pB, accO[dt], 0, 0, 0);
        }
        __builtin_amdgcn_s_setprio(0);
      }
      { /* tail tile: keys 352..357 */
        int k0 = 352;
        int kr0 = k0 + cl; if (kr0 > 359) kr0 = 359;
        float4v s0a = (float4v){0,0,0,0};
        {
          short8 a00 = *(const short8*)&Ks[kr0][8*gr];
          s0a = __builtin_amdgcn_mfma_f32_16x16x32_bf16(a00, qB0, s0a, 0, 0, 0);
          short8 a01 = g0 ? *(const short8*)&Ks[kr0][32] : z8;
          s0a = __builtin_amdgcn_mfma_f32_16x16x32_bf16(a01, qB1, s0a, 0, 0, 0);
        }
        float p0[4];
#pragma unroll
        for (int r = 0; r < 4; ++r) {
          float xv = (4*gr + r < 6) ? s0a[r]*C2_ : -1e30f;
          p0[r] = __builtin_exp2f(fminf(xv, 80.f));
        }
        sum_ += (p0[0] + p0[1]) + (p0[2] + p0[3]);
        unsigned u0 = pk_bf(p0[0], p0[1]);
        unsigned u1 = pk_bf(p0[2], p0[3]);
        int srcA = cl + 16*((2*gr) & 3);
        int srcB = srcA + 16;
        unsigned a0 = __shfl(u0, srcA, 64), b0 = __shfl(u1, srcA, 64);
        unsigned c0 = __shfl(u0, srcB, 64), d0 = __shfl(u1, srcB, 64);
        bool lo = gr < 2;
        union { unsigned u[4]; short8 v; } pbu;
        pbu.u[0] = lo ? a0 : 0u;
        pbu.u[1] = lo ? b0 : 0u;
        pbu.u[2] = lo ? c0 : 0u;
        pbu.u[3] = lo ? d0 : 0u;
        short8 pB = pbu.v;
#pragma unroll
        for (int dt = 0; dt < 3; ++dt) {
          short8 aV = (dt < 2 || cl < 6)
              ? *(const short8*)&Vt[16*dt + cl][k0 + 8*gr] : z8;
          accO[dt] = __builtin_amdgcn_mfma_f32_16x16x32_bf16(aV, pB, accO[dt], 0, 0, 0);
        }
      }
      sum_ += __shfl_xor(sum_, 16, 64);
      sum_ += __shfl_xor(sum_, 32, 64);
      int qi = 16*qt + cl;
      if (qi < N_) {
        float inv = 1.f / sum_;
        bf* ap = a + (base + qi)*D_ + h*HD_;
#pragma unroll
        for (int dt = 0; dt < 2; ++dt) {
          *(unsigned*)(ap + 16*dt + 4*gr)     = pk_bf(accO[dt][0]*inv, accO[dt][1]*inv);
          *(unsigned*)(ap + 16*dt + 4*gr + 2) = pk_bf(accO[dt][2]*inv, accO[dt][3]*inv);
        }
        if (gr == 0) {
          *(unsigned*)(ap + 32) = pk_bf(accO[2][0]*inv, accO[2][1]*inv);
          *(unsigned*)(ap + 34) = pk_bf(accO[2][2]*inv, accO[2][3]*inv);
        } else if (gr == 1) {
          *(unsigned*)(ap + 36) = pk_bf(accO[2][0]*inv, accO[2][1]*inv);
        }
      }
    }
  }
}

/* ------------------------------------------------------------------ */
__global__ __launch_bounds__(256) void k_evtpool(
    const float* __restrict__ marker, const void* __restrict__ doy_mask,
    const float* __restrict__ evt_h, float* __restrict__ evtp) {
  __shared__ int hasF32, hasBig;
  if (threadIdx.x == 0) { hasF32 = 0; hasBig = 0; }
  __syncthreads();
  const unsigned* mw = (const unsigned*)doy_mask;
  for (int w = threadIdx.x; w < 732; w += 256) {
    unsigned u = mw[w];
    if (u == 0x3F800000u) hasF32 = 1;
    else if (u > 1u) hasBig = 1;
  }
  __syncthreads();
  int fmt = hasF32 ? 2 : (hasBig ? 1 : 0);
  int b = blockIdx.x;
  float m3 = marker[((b*L_ + (L_-1))*N_ + 0)*4 + 3];
  int doy = (int)(m3 * 365.f); doy = doy < 0 ? 0 : (doy > 365 ? 365 : doy);
  int j = threadIdx.x;
  float mx = -1e30f;
  for (int kx = 0; kx < 8; ++kx) {
    bool mk;
    if (fmt == 2)      mk = ((const float*)doy_mask)[doy*8 + kx] != 0.f;
    else if (fmt == 1) mk = ((const unsigned char*)doy_mask)[doy*8 + kx] != 0;
    else               mk = ((const int*)doy_mask)[doy*8 + kx] != 0;
    if (mk) mx = fmaxf(mx, evt_h[(b*8 + kx)*256 + j]);
  }
  evtp[b*256 + j] = mx;
}

/* ------------------------------------------------------------------ */
__global__ __launch_bounds__(192) void k_final3(
    const bf* __restrict__ x, const float* __restrict__ wcomb,
    const float* __restrict__ wevtsum, const float* __restrict__ evtp,
    const float* __restrict__ b_mm, const float* __restrict__ b_ts,
    float* __restrict__ out) {
  int id = blockIdx.x; int b = id / N_; int n = id % N_;
  __shared__ float xs[1824];
  __shared__ float part[16][12];
  int tid = threadIdx.x;
  for (int e = tid; e < 912; e += 192) {
    int l = e / 76, du = e % 76;
    unsigned u = *(const unsigned*)((const ushort*)x +
        (((long)(b*L_ + l) * N_ + n) * 152 + 2*du));
    xs[l*152 + 2*du]     = lo_bf(u);
    xs[l*152 + 2*du + 1] = hi_bf(u);
  }
  __syncthreads();
  int g2 = tid / 12, p = tid % 12;
  float acc = 0.f;
  for (int e = g2; e < 1824; e += 16)
    acc += xs[e] * wcomb[e*12 + p];
  part[g2][p] = acc;
  __syncthreads();
  if (tid < 12) {
    float s = b_mm[tid] + b_ts[tid];
    for (int e = 0; e < 256; ++e) s += evtp[b*256 + e] * wevtsum[e*12 + tid];
    for (int gg = 0; gg < 16; ++gg) s += part[gg][tid];
    out[(b*12 + tid) * N_ + n] = s;
  }
}

/* ------------------------------------------------------------------ */
extern "C" void kernel_launch(void* const* d_in, const int* in_sizes, int n_in,
                              void* d_out, int out_size, void* d_ws, size_t ws_size,
                              hipStream_t stream) {
  static const int expect[32] = {
    68736, 274944, 72, 24, 3456, 168, 343680,
    138624, 912, 138624, 912, 138624, 912, 138624, 912,
    233472, 1536, 233472, 912,
    912, 912, 912, 912,
    4195328, 262144, 256,
    58752, 12, 21888, 12,
    2928, 2928 };
  int nb = (out_size + 255)/256;
  if (n_in != 32) {
    k_beacon<<<nb, 256, 0, stream>>>((float*)d_out, out_size, 998.f);
    return;
  }
  for (int i = 0; i < 32; ++i) {
    if (in_sizes[i] != expect[i]) {
      k_beacon<<<nb, 256, 0, stream>>>((float*)d_out, out_size, 1000.f + i);
      return;
    }
  }
  if (out_size != 68736) {
    k_beacon<<<nb, 256, 0, stream>>>((float*)d_out, out_size, 997.f);
    return;
  }

  const float* var_x  = (const float*)d_in[0];
  const float* marker = (const float*)d_in[1];
  const float* W_in   = (const float*)d_in[2];
  const float* b_in   = (const float*)d_in[3];
  const float* tod    = (const float*)d_in[4];
  const float* dow    = (const float*)d_in[5];
  const float* adap   = (const float*)d_in[6];
  const float* Wq = (const float*)d_in[7];  const float* bq = (const float*)d_in[8];
  const float* Wk = (const float*)d_in[9];  const float* bk = (const float*)d_in[10];
  const float* Wv = (const float*)d_in[11]; const float* bv = (const float*)d_in[12];
  const float* Wo = (const float*)d_in[13]; const float* bo = (const float*)d_in[14];
  const float* W1 = (const float*)d_in[15]; const float* b1 = (const float*)d_in[16];
  const float* W2 = (const float*)d_in[17]; const float* b2 = (const float*)d_in[18];
  const float* g1 = (const float*)d_in[19]; const float* be1 = (const float*)d_in[20];
  const float* g2 = (const float*)d_in[21]; const float* be2 = (const float*)d_in[22];
  const float* emb   = (const float*)d_in[23];
  const float* W_evt = (const float*)d_in[24]; const float* b_evt = (const float*)d_in[25];
  const float* W_mm  = (const float*)d_in[26]; const float* b_mm  = (const float*)d_in[27];
  const float* W_ts  = (const float*)d_in[28]; const float* b_ts  = (const float*)d_in[29];
  const int* doyi = (const int*)d_in[30];
  const void* doym = d_in[31];

  const long TD = (long)TOK_ * D_;
  size_t need = (size_t)TD * 2 * 5
              + (size_t)(32768 + 4096 + 3072 + 21888) * 4
              + 2764800
              + 4096;
  if (ws_size < need) {
    k_beacon<<<nb, 256, 0, stream>>>((float*)d_out, out_size, (float)(ws_size >> 20));
    return;
  }

  bf* x = (bf*)d_ws;
  bf* q = x + TD;
  bf* k = q + TD;
  bf* v = k + TD;
  bf* a = v + TD;
  float* evt_h   = (float*)(a + TD);
  float* evtp    = evt_h + 32768;
  float* wevtsum = evtp + 4096;
  float* wcomb   = wevtsum + 3072;
  ushort* wprep  = (ushort*)(wcomb + 21888);

  k_prep<<<PREP_B, 256, 0, stream>>>(
      Wq, Wk, Wv, Wo, W1, W2, (unsigned*)wprep,
      var_x, marker, W_in, b_in, tod, dow, adap, x,
      doyi, emb, W_evt, b_evt, evt_h,
      W_mm, W_ts, wcomb, wevtsum);
  k_evtpool<<<16, 256, 0, stream>>>(marker, doym, evt_h, evtp);
  for (int i = 0; i < 6; ++i) {
    const ushort* pl = wprep + (size_t)i * 230400;
    /* fused QKV projection (64-tok blocks) */
    k_gemm7<152,152,3,64,1,false,false><<<TOK_/64, 512, 0, stream>>>(
        x, pl, bq + i*152, bk + i*152, bv + i*152,
        nullptr, nullptr, nullptr, q, k, v);
    if (i < 3)
      k_attn_t2<<<B_*N_, 256, 0, stream>>>(
          (const ushort*)q, (const ushort*)k, (const ushort*)v, a);
    else
      k_attn_s6<<<B_*L_*2, 512, 0, stream>>>(
          (const ushort*)q, (const ushort*)k, (const ushort*)v, a);
    /* o-proj + residual(x) + LN1 -> k (h)  (128-tok blocks) */
    k_gemm7<152,152,1,128,1,false,true><<<TOK_/128, 512, 0, stream>>>(
        a, pl + 96000, bo + i*152, nullptr, nullptr,
        x, g1 + i*152, be1 + i*152, k, nullptr, nullptr);
    /* fused FFN: x = LN2( relu(k@W1+b1)@W2 + b2 + k ) */
    k_ffn<<<TOK_/64, 512, 0, stream>>>(
        k, pl + 128000, pl + 179200, b1 + i*256, b2 + i*152,
        k, g2 + i*152, be2 + i*152, x);
  }
  k_final3<<<B_*N_, 192, 0, stream>>>(x, wcomb, wevtsum, evtp, b_mm, b_ts,
                                      (float*)d_out);
}

// Round 7
// 1119.493 us; speedup vs baseline: 4.4626x; 1.0020x over previous
//
#include <hip/hip_runtime.h>
#include <hip/hip_bf16.h>

using bf = __hip_bfloat16;

#define B_   16
#define L_   12
#define N_   358
#define D_   152
#define TOK_ (B_*L_*N_)   /* 68736 */
#define FF_  256
#define HD_  38
#define SCALE_ 0.16222142113076254f  /* 38^-0.5 */
#define C2_   0.23403921469340696f   /* SCALE_ * log2(e) */

__device__ __forceinline__ float bf2f(bf x) { return __bfloat162float(x); }
__device__ __forceinline__ bf f2bf(float f) { return __float2bfloat16(f); }
__device__ __forceinline__ float lo_bf(unsigned u) { return __uint_as_float(u << 16); }
__device__ __forceinline__ float hi_bf(unsigned u) { return __uint_as_float(u & 0xffff0000u); }
__device__ __forceinline__ unsigned pk_bf(float a, float b) {
  union { bf h; unsigned short u; } A, Bu;
  A.h = f2bf(a); Bu.h = f2bf(b);
  return ((unsigned)Bu.u << 16) | A.u;
}
__device__ __forceinline__ ushort f2bf_u(float f) {
  union { bf h; ushort u; } t; t.h = f2bf(f); return t.u;
}

using short8  = __attribute__((ext_vector_type(8))) short;
using float4v = __attribute__((ext_vector_type(4))) float;

/* async global->LDS, 16B per lane; dst is wave-uniform base (HW adds lane*16) */
__device__ __forceinline__ void gl_lds16(const void* g, void* l) {
  __builtin_amdgcn_global_load_lds(
      (const __attribute__((address_space(1))) void*)g,
      (__attribute__((address_space(3))) void*)l, 16, 0, 0);
}

/* copy SUBCB bytes global->LDS; 8 waves interleave 1024B blocks */
template<int SUBCB>
__device__ __forceinline__ void issue_w8(const char* gsrc, ushort* lds, int w, int lane) {
  constexpr int TB = SUBCB >> 10;
  constexpr int TAIL = SUBCB & 1023;
#pragma unroll
  for (int blk0 = 0; blk0 < TB; blk0 += 8) {
    int blk = blk0 + w;
    if (blk < TB)
      gl_lds16(gsrc + blk*1024 + (size_t)lane*16, (char*)lds + blk*1024);
  }
  if (TAIL) {
    if (w == (TB & 7) && lane < TAIL/16)
      gl_lds16(gsrc + TB*1024 + (size_t)lane*16, (char*)lds + TB*1024);
  }
}

/* per-wave count of gl_lds16 issues done by issue_w8<SUBCB> (wave-uniform) */
template<int SUBCB>
__device__ __forceinline__ int issue_cnt(int w) {
  constexpr int TB = SUBCB >> 10;
  constexpr int TAIL = SUBCB & 1023;
  int n = (TB > 8 && w < TB - 8) ? 2 : 1;
  if (TAIL && w == (TB & 7)) n += 1;
  return n;
}

/* counted-vmcnt wait: keep newest n loads in flight (n in {1,2,3}) */
__device__ __forceinline__ void vm_wait(int n) {
  if (n == 1)      asm volatile("s_waitcnt vmcnt(1)" ::: "memory");
  else if (n == 2) asm volatile("s_waitcnt vmcnt(2)" ::: "memory");
  else             asm volatile("s_waitcnt vmcnt(3)" ::: "memory");
}

/* 16B logical load from a 4B-aligned (not necessarily 16B-aligned) address */
__device__ __forceinline__ short8 ld_g8(const ushort* p) {
  union { unsigned u[4]; short8 v; } t;
  t.u[0] = *(const unsigned*)(p);
  t.u[1] = *(const unsigned*)(p + 2);
  t.u[2] = *(const unsigned*)(p + 4);
  t.u[3] = *(const unsigned*)(p + 6);
  return t.v;
}

/* ------------------------------------------------------------------ */
__global__ void k_beacon(float* out, int n, float val) {
  int i = blockIdx.x * 256 + threadIdx.x;
  if (i < n) out[i] = val;
}

/* ================= fused prep: wprep | embed | evt1 | wcomb ======= */
#define WPREP_B 2700
#define EMB_B   269
#define EVT_B   128
#define WC_B    86
#define PREP_B  (WPREP_B + EMB_B + EVT_B + WC_B)   /* 3183 */

__device__ void d_wprep(int bid, int tid,
    const float* __restrict__ Wq, const float* __restrict__ Wk,
    const float* __restrict__ Wv, const float* __restrict__ Wo,
    const float* __restrict__ W1, const float* __restrict__ W2,
    unsigned* __restrict__ out) {
  int i = bid * 256 + tid;
  if (i >= 6*115200) return;
  int layer = i / 115200, r = i % 115200;
  const float* src; int K, Nd, d, up, c;
  if (r < 48000) {
    c = r / 9600; int rr = r % 9600; int m = rr / 3200; int r2 = rr % 3200;
    d = r2 / 20; up = r2 % 20;
    src = (m == 0 ? Wq : (m == 1 ? Wk : Wv)) + layer*23104; K = 152; Nd = 152;
  } else if (r < 64000) {
    int rr = r - 48000; c = rr / 3200; int r2 = rr % 3200;
    d = r2 / 20; up = r2 % 20;
    src = Wo + layer*23104; K = 152; Nd = 152;
  } else if (r < 89600) {
    int rr = r - 64000; c = rr / 5120; int r2 = rr % 5120;
    d = r2 / 20; up = r2 % 20;
    src = W1 + layer*38912; K = 152; Nd = 256;
  } else {
    int rr = r - 89600; c = rr / 3200; int r2 = rr % 3200;
    d = r2 / 20; up = r2 % 20;
    src = W2 + layer*38912; K = 256; Nd = 152;
  }
  float v0 = 0.f, v1 = 0.f;
  int k0 = 32*c + 2*up;
  if (up < 16 && d < Nd) {
    if (k0 < K)     v0 = src[(long)k0*Nd + d];
    if (k0 + 1 < K) v1 = src[(long)(k0+1)*Nd + d];
  }
  out[i] = pk_bf(v0, v1);
}

__device__ void d_embed(int bid, int tid,
    const float* __restrict__ var_x, const float* __restrict__ marker,
    const float* __restrict__ W_in, const float* __restrict__ b_in,
    const float* __restrict__ tod_emb, const float* __restrict__ dow_emb,
    const float* __restrict__ adap, bf* __restrict__ x) {
  int t = bid * 256 + tid;
  if (t >= TOK_) return;
  int n = t % N_;
  int l = (t / N_) % L_;
  float var = var_x[t];
  float m0 = marker[t*4 + 0];
  float m1 = marker[t*4 + 1];
  int tod = (int)(m0 * 144.f); tod = tod < 0 ? 0 : (tod > 143 ? 143 : tod);
  int dw  = (int)(m1 * 7.f);   dw  = dw  < 0 ? 0 : (dw  > 6   ? 6   : dw);
  bf* xp = x + (long)t * D_;
  for (int d = 0; d < 24; ++d)
    xp[d] = f2bf(var * W_in[d] + m0 * W_in[24 + d] + m1 * W_in[48 + d] + b_in[d]);
  for (int d = 0; d < 24; ++d) xp[24 + d] = f2bf(tod_emb[tod*24 + d]);
  for (int d = 0; d < 24; ++d) xp[48 + d] = f2bf(dow_emb[dw*24 + d]);
  for (int d = 0; d < 80; ++d) xp[72 + d] = f2bf(adap[(l*N_ + n)*80 + d]);
}

__device__ void d_evt1(int bk, int tid,
    const float* __restrict__ marker, const int* __restrict__ doy_idx,
    const float* __restrict__ emb, const float* __restrict__ W_evt,
    const float* __restrict__ b_evt, float* __restrict__ evt_h) {
  int b = bk >> 3; int ks = bk & 7;
  float m3 = marker[((b*L_ + (L_-1))*N_ + 0)*4 + 3];
  int doy = (int)(m3 * 365.f); doy = doy < 0 ? 0 : (doy > 365 ? 365 : doy);
  int idx = doy_idx[doy*8 + ks];
  if (idx < 0 || idx > 4096) idx = 0;
  int d = tid;
  float acc = b_evt[d];
  const float* er = emb + (long)idx * 1024;
  for (int e = 0; e < 1024; ++e)
    acc += er[e] * W_evt[e*256 + d];
  evt_h[bk*256 + d] = acc;
}

__device__ void d_wcomb(int bid, int tid,
    const float* __restrict__ W_mm, const float* __restrict__ W_ts,
    float* __restrict__ wcomb, float* __restrict__ wevtsum) {
  int i = bid * 256 + tid;
  if (i < 1824*12) {
    int r = i / 12, p = i % 12, l = r / 152, d = r % 152;
    wcomb[i] = W_mm[(l*408 + 256 + d)*12 + p] + W_ts[i];
  }
  if (i < 256*12) {
    int e = i / 12, p = i % 12;
    float s = 0.f;
    for (int l = 0; l < 12; ++l) s += W_mm[(l*408 + e)*12 + p];
    wevtsum[i] = s;
  }
}

__global__ __launch_bounds__(256) void k_prep(
    const float* Wq, const float* Wk, const float* Wv, const float* Wo,
    const float* W1, const float* W2, unsigned* wout,
    const float* var_x, const float* marker, const float* W_in,
    const float* b_in, const float* tod_emb, const float* dow_emb,
    const float* adap, bf* x,
    const int* doyi, const float* emb, const float* W_evt,
    const float* b_evt, float* evt_h,
    const float* W_mm, const float* W_ts, float* wcomb, float* wevtsum) {
  int bid = blockIdx.x, tid = threadIdx.x;
  if (bid < WPREP_B)
    d_wprep(bid, tid, Wq, Wk, Wv, Wo, W1, W2, wout);
  else if (bid < WPREP_B + EMB_B)
    d_embed(bid - WPREP_B, tid, var_x, marker, W_in, b_in, tod_emb, dow_emb, adap, x);
  else if (bid < WPREP_B + EMB_B + EVT_B)
    d_evt1(bid - WPREP_B - EMB_B, tid, marker, doyi, emb, W_evt, b_evt, evt_h);
  else
    d_wcomb(bid - WPREP_B - EMB_B - EVT_B, tid, W_mm, W_ts, wcomb, wevtsum);
}

/* ------------------------------------------------------------------ */
/* GEMM v8: gemm7 + counted-vmcnt two-barrier K-loop (m201 T3/T4).
   Per step: issue(s+1) -> vmcnt(n_w) [my step-s loads done, s+1 batch
   stays in flight] -> s_barrier [everyone's step-s loads done] ->
   ds_read+MFMA -> lgkmcnt(0) -> s_barrier [buffer safe to overwrite]. */
template<int K, int Nd, int NW, int TOKB, int CSPLIT, bool RELU, bool LN>
__global__ __launch_bounds__(512) void k_gemm7(
    const bf* __restrict__ X, const ushort* __restrict__ Wg,
    const float* __restrict__ bi0, const float* __restrict__ bi1,
    const float* __restrict__ bi2, const bf* __restrict__ Res,
    const float* __restrict__ g, const float* __restrict__ bb,
    bf* __restrict__ Y0, bf* __restrict__ Y1, bf* __restrict__ Y2) {
  constexpr int NJ   = (Nd + 15) / 16;
  constexpr int NdP  = NJ * 16;
  constexpr int KC   = (K + 31) / 32;
  constexpr int G    = NW * CSPLIT;
  constexpr int S    = KC * G;
  constexpr int IR   = NdP / CSPLIT;
  constexpr int SUB_USH = IR * 40;
  constexpr int SUBCB   = SUB_USH * 2;
  constexpr int NJW  = IR / 32;
  constexpr int MR   = TOKB / 64;
  constexpr bool GLX = (K == 152);
  constexpr int XSTR = GLX ? K : (K + 8);
  __shared__ __align__(16) ushort Xs[TOKB * XSTR + 8];
  __shared__ __align__(16) ushort Wb[2 * SUB_USH];
  long row0 = (long)blockIdx.x * TOKB;
  int tid = threadIdx.x;
  int lane = tid & 63, w = tid >> 6;
  int cl = lane & 15, gr = lane >> 4;
  int wr = w >> 1, wc = w & 1;
  if constexpr (GLX) {
    constexpr int TBX = TOKB * K * 2 / 1024;
    const char* Xgc = (const char*)(X + row0 * K);
#pragma unroll
    for (int b0 = 0; b0 < TBX; b0 += 8) {
      int blk = b0 + w;
      if (blk < TBX)
        gl_lds16(Xgc + blk*1024 + (size_t)lane*16, (char*)Xs + blk*1024);
    }
  } else {
    const char* Xgc = (const char*)(X + row0 * K);
    for (int i = tid; i < TOKB*(K/8); i += 512) {
      int r = i / (K/8), c = i % (K/8);
      *(short8*)&Xs[r*XSTR + 8*c] = *(const short8*)(Xgc + r*(K*2) + c*16);
    }
    __syncthreads();   /* ds-write staging path: full drain (unused for K=152) */
  }
  const char* gW = (const char*)Wg;
  issue_w8<SUBCB>(gW, Wb, w, lane);
  const int nw = issue_cnt<SUBCB>(w);
  float4v acc[G][MR][NJW];
#pragma unroll
  for (int gi = 0; gi < G; ++gi)
#pragma unroll
    for (int mi = 0; mi < MR; ++mi)
#pragma unroll
      for (int j = 0; j < NJW; ++j) acc[gi][mi][j] = (float4v){0.f,0.f,0.f,0.f};
#pragma unroll
  for (int s = 0; s < S; ++s) {
    if (s + 1 < S) {
      issue_w8<SUBCB>(gW + (size_t)(s+1)*SUBCB, Wb + ((s+1)&1)*SUB_USH, w, lane);
      vm_wait(nw);
    } else {
      asm volatile("s_waitcnt vmcnt(0)" ::: "memory");
    }
    __builtin_amdgcn_s_barrier();
    int kc = (s / G) * 32;
    const ushort* wb = Wb + (s&1)*SUB_USH;
    short8 af[MR];
#pragma unroll
    for (int mi = 0; mi < MR; ++mi)
      af[mi] = *(const short8*)&Xs[((TOKB/4)*wr + 16*mi + cl)*XSTR + kc + 8*gr];
#pragma unroll
    for (int j = 0; j < NJW; ++j) {
      short8 bv = *(const short8*)&wb[((IR/2)*wc + 16*j + cl)*40 + 8*gr];
#pragma unroll
      for (int mi = 0; mi < MR; ++mi)
        acc[s % G][mi][j] =
            __builtin_amdgcn_mfma_f32_16x16x32_bf16(af[mi], bv, acc[s % G][mi][j], 0, 0, 0);
    }
    asm volatile("s_waitcnt lgkmcnt(0)" ::: "memory");
    __builtin_amdgcn_s_barrier();
  }
  if constexpr (!LN) {
#pragma unroll
    for (int gi = 0; gi < G; ++gi) {
      bf* Y = (NW > 1) ? (gi == 0 ? Y0 : (gi == 1 ? Y1 : Y2)) : Y0;
      const float* bp = (NW > 1) ? (gi == 0 ? bi0 : (gi == 1 ? bi1 : bi2)) : bi0;
      int colb = (CSPLIT > 1 ? IR*gi : 0) + (IR/2)*wc;
#pragma unroll
      for (int j = 0; j < NJW; ++j) {
        int col = colb + 16*j + cl;
        if (col < Nd) {
          float bvs = bp[col];
#pragma unroll
          for (int mi = 0; mi < MR; ++mi) {
            long rw = row0 + (TOKB/4)*wr + 16*mi + 4*gr;
#pragma unroll
            for (int r = 0; r < 4; ++r) {
              float val = acc[gi][mi][j][r] + bvs;
              if (RELU) val = fmaxf(val, 0.f);
              Y[(rw + r) * Nd + col] = f2bf(val);
            }
          }
        }
      }
    }
  } else {
    float* LNb = (float*)Wb;
    int colb = (IR/2)*wc;
#pragma unroll
    for (int j = 0; j < NJW; ++j) {
      int col = colb + 16*j + cl;
      if (col < Nd) {
        float bvs = bi0[col];
#pragma unroll
        for (int mi = 0; mi < MR; ++mi) {
          long rw = row0 + (TOKB/4)*wr + 16*mi + 4*gr;
#pragma unroll
          for (int r = 0; r < 4; ++r)
            acc[0][mi][j][r] += bvs + bf2f(Res[(rw + r) * Nd + col]);
        }
      }
    }
    float mean[MR][4], rs[MR][4];
#pragma unroll
    for (int mi = 0; mi < MR; ++mi)
#pragma unroll
      for (int r = 0; r < 4; ++r) {
        float s = 0.f;
#pragma unroll
        for (int j = 0; j < NJW; ++j) s += acc[0][mi][j][r];
        s += __shfl_xor(s, 1, 64); s += __shfl_xor(s, 2, 64);
        s += __shfl_xor(s, 4, 64); s += __shfl_xor(s, 8, 64);
        if (cl == 0) LNb[((wr*MR + mi)*2 + wc)*16 + 4*gr + r] = s;
      }
    __syncthreads();
#pragma unroll
    for (int mi = 0; mi < MR; ++mi)
#pragma unroll
      for (int r = 0; r < 4; ++r) {
        float tot = LNb[((wr*MR + mi)*2 + 0)*16 + 4*gr + r]
                  + LNb[((wr*MR + mi)*2 + 1)*16 + 4*gr + r];
        mean[mi][r] = tot * (1.f / (float)Nd);
      }
#pragma unroll
    for (int mi = 0; mi < MR; ++mi)
#pragma unroll
      for (int r = 0; r < 4; ++r) {
        float s2 = 0.f;
#pragma unroll
        for (int j = 0; j < NJW; ++j) {
          int col = colb + 16*j + cl;
          if (col < Nd) {
            float dv = acc[0][mi][j][r] - mean[mi][r];
            s2 += dv*dv;
          }
        }
        s2 += __shfl_xor(s2, 1, 64); s2 += __shfl_xor(s2, 2, 64);
        s2 += __shfl_xor(s2, 4, 64); s2 += __shfl_xor(s2, 8, 64);
        if (cl == 0) LNb[256 + ((wr*MR + mi)*2 + wc)*16 + 4*gr + r] = s2;
      }
    __syncthreads();
#pragma unroll
    for (int mi = 0; mi < MR; ++mi)
#pragma unroll
      for (int r = 0; r < 4; ++r) {
        float tot2 = LNb[256 + ((wr*MR + mi)*2 + 0)*16 + 4*gr + r]
                   + LNb[256 + ((wr*MR + mi)*2 + 1)*16 + 4*gr + r];
        rs[mi][r] = rsqrtf(tot2 * (1.f / (float)Nd) + 1e-5f);
      }
#pragma unroll
    for (int j = 0; j < NJW; ++j) {
      int col = colb + 16*j + cl;
      if (col < Nd) {
        float gv = g[col], bv2 = bb[col];
#pragma unroll
        for (int mi = 0; mi < MR; ++mi) {
          long rw = row0 + (TOKB/4)*wr + 16*mi + 4*gr;
#pragma unroll
          for (int r = 0; r < 4; ++r)
            Y0[(rw + r) * Nd + col] =
                f2bf((acc[0][mi][j][r] - mean[mi][r]) * rs[mi][r] * gv + bv2);
        }
      }
    }
  }
}

/* ------------------------------------------------------------------ */
/* Fused FFN v2: counted-vmcnt two-barrier loops (same scheme).       */
__global__ __launch_bounds__(512) void k_ffn(
    const bf* __restrict__ X, const ushort* __restrict__ W1g,
    const ushort* __restrict__ W2g,
    const float* __restrict__ b1, const float* __restrict__ b2,
    const bf* __restrict__ Res, const float* __restrict__ g,
    const float* __restrict__ bb, bf* __restrict__ Y) {
  constexpr int S1 = 10, SUB1 = 5120;   /* 5 chunks x 2 col-halves */
  constexpr int S2 = 8,  SUB2 = 6400;
  constexpr int HSTR = 260;
  __shared__ __align__(16) ushort S_[29440];   /* 58880 B */
  ushort* Xs  = S_;
  ushort* W1b = S_ + 9728;
  ushort* Hs  = S_;
  ushort* W2b = S_ + 16640;
  long row0 = (long)blockIdx.x * 64;
  int tid = threadIdx.x, lane = tid & 63, w = tid >> 6;
  int cl = lane & 15, gr = lane >> 4;
  int wr = w >> 1, wc = w & 1;
  {  /* stage X: 64x152x2 = 19456 B = 19 blocks */
    const char* Xgc = (const char*)(X + row0 * 152);
#pragma unroll
    for (int b0 = 0; b0 < 19; b0 += 8) {
      int blk = b0 + w;
      if (blk < 19)
        gl_lds16(Xgc + blk*1024 + (size_t)lane*16, (char*)Xs + blk*1024);
    }
  }
  issue_w8<SUB1*2>((const char*)W1g, W1b, w, lane);
  const int nw1 = issue_cnt<SUB1*2>(w);
  const int nw2 = issue_cnt<SUB2*2>(w);
  float4v acc1[2][4];
#pragma unroll
  for (int g2 = 0; g2 < 2; ++g2)
#pragma unroll
    for (int j = 0; j < 4; ++j) acc1[g2][j] = (float4v){0.f,0.f,0.f,0.f};
#pragma unroll
  for (int s = 0; s < S1; ++s) {
    if (s + 1 < S1) {
      issue_w8<SUB1*2>((const char*)W1g + (size_t)(s+1)*SUB1*2,
                       W1b + ((s+1)&1)*SUB1, w, lane);
      vm_wait(nw1);
    } else {
      asm volatile("s_waitcnt vmcnt(0)" ::: "memory");
    }
    __builtin_amdgcn_s_barrier();
    int kc = (s / 2) * 32;
    const ushort* wb = W1b + (s&1)*SUB1;
    short8 af = *(const short8*)&Xs[(16*wr + cl)*152 + kc + 8*gr];
#pragma unroll
    for (int j = 0; j < 4; ++j) {
      short8 bv = *(const short8*)&wb[(64*wc + 16*j + cl)*40 + 8*gr];
      acc1[s&1][j] =
          __builtin_amdgcn_mfma_f32_16x16x32_bf16(af, bv, acc1[s&1][j], 0, 0, 0);
    }
    asm volatile("s_waitcnt lgkmcnt(0)" ::: "memory");
    __builtin_amdgcn_s_barrier();        /* last iter: Xs/W1b reads done */
  }
  /* h = relu(acc+b1) -> Hs (overwrites Xs/W1b region: dead) */
#pragma unroll
  for (int g2 = 0; g2 < 2; ++g2)
#pragma unroll
    for (int j = 0; j < 4; ++j) {
      int col = g2*128 + 64*wc + 16*j + cl;
      float bvs = b1[col];
#pragma unroll
      for (int r = 0; r < 4; ++r) {
        int row = 16*wr + 4*gr + r;
        Hs[row*HSTR + col] = f2bf_u(fmaxf(acc1[g2][j][r] + bvs, 0.f));
      }
    }
  issue_w8<SUB2*2>((const char*)W2g, W2b, w, lane);
  asm volatile("s_waitcnt lgkmcnt(0)" ::: "memory");   /* Hs writes visible */
  __builtin_amdgcn_s_barrier();
  float4v acc2[5];
#pragma unroll
  for (int j = 0; j < 5; ++j) acc2[j] = (float4v){0.f,0.f,0.f,0.f};
#pragma unroll
  for (int s = 0; s < S2; ++s) {
    if (s + 1 < S2) {
      issue_w8<SUB2*2>((const char*)W2g + (size_t)(s+1)*SUB2*2,
                       W2b + ((s+1)&1)*SUB2, w, lane);
      vm_wait(nw2);
    } else {
      asm volatile("s_waitcnt vmcnt(0)" ::: "memory");
    }
    __builtin_amdgcn_s_barrier();
    int kc = s * 32;
    const ushort* wb = W2b + (s&1)*SUB2;
    short8 af = *(const short8*)&Hs[(16*wr + cl)*HSTR + kc + 8*gr];
#pragma unroll
    for (int j = 0; j < 5; ++j) {
      short8 bv = *(const short8*)&wb[(80*wc + 16*j + cl)*40 + 8*gr];
      acc2[j] =
          __builtin_amdgcn_mfma_f32_16x16x32_bf16(af, bv, acc2[j], 0, 0, 0);
    }
    asm volatile("s_waitcnt lgkmcnt(0)" ::: "memory");
    __builtin_amdgcn_s_barrier();
  }
  /* residual + LayerNorm epilogue */
  float* LNb = (float*)W2b;
  int colb = 80*wc;
#pragma unroll
  for (int j = 0; j < 5; ++j) {
    int col = colb + 16*j + cl;
    if (col < D_) {
      float bvs = b2[col];
#pragma unroll
      for (int r = 0; r < 4; ++r)
        acc2[j][r] += bvs + bf2f(Res[(row0 + 16*wr + 4*gr + r) * D_ + col]);
    }
  }
  float mean[4], rsv[4];
#pragma unroll
  for (int r = 0; r < 4; ++r) {
    float s = 0.f;
#pragma unroll
    for (int j = 0; j < 5; ++j)
      if (colb + 16*j + cl < D_) s += acc2[j][r];
    s += __shfl_xor(s, 1, 64); s += __shfl_xor(s, 2, 64);
    s += __shfl_xor(s, 4, 64); s += __shfl_xor(s, 8, 64);
    if (cl == 0) LNb[(wr*2 + wc)*16 + 4*gr + r] = s;
  }
  __syncthreads();
#pragma unroll
  for (int r = 0; r < 4; ++r) {
    float tot = LNb[(wr*2 + 0)*16 + 4*gr + r] + LNb[(wr*2 + 1)*16 + 4*gr + r];
    mean[r] = tot * (1.f / (float)D_);
  }
#pragma unroll
  for (int r = 0; r < 4; ++r) {
    float s2 = 0.f;
#pragma unroll
    for (int j = 0; j < 5; ++j) {
      int col = colb + 16*j + cl;
      if (col < D_) { float dv = acc2[j][r] - mean[r]; s2 += dv*dv; }
    }
    s2 += __shfl_xor(s2, 1, 64); s2 += __shfl_xor(s2, 2, 64);
    s2 += __shfl_xor(s2, 4, 64); s2 += __shfl_xor(s2, 8, 64);
    if (cl == 0) LNb[128 + (wr*2 + wc)*16 + 4*gr + r] = s2;
  }
  __syncthreads();
#pragma unroll
  for (int r = 0; r < 4; ++r) {
    float tot2 = LNb[128 + (wr*2 + 0)*16 + 4*gr + r]
               + LNb[128 + (wr*2 + 1)*16 + 4*gr + r];
    rsv[r] = rsqrtf(tot2 * (1.f / (float)D_) + 1e-5f);
  }
#pragma unroll
  for (int j = 0; j < 5; ++j) {
    int col = colb + 16*j + cl;
    if (col < D_) {
      float gv = g[col], bv2 = bb[col];
#pragma unroll
      for (int r = 0; r < 4; ++r)
        Y[(row0 + 16*wr + 4*gr + r) * D_ + col] =
            f2bf((acc2[j][r] - mean[r]) * rsv[r] * gv + bv2);
    }
  }
}

/* ------------------------------------------------------------------ */
/* Temporal attention v2 (round-5 proven): MFMA swapped-operand.      */
__global__ __launch_bounds__(256) void k_attn_t2(
    const ushort* __restrict__ qg, const ushort* __restrict__ kg,
    const ushort* __restrict__ vg, bf* __restrict__ a) {
  int id = blockIdx.x; int b = id / N_; int n = id % N_;
  __shared__ ushort Ksh[4][16][40];
  __shared__ ushort Qsh[4][16][40];
  __shared__ ushort Vth[4][40][16];
  int tid = threadIdx.x;
  for (int i = tid; i < 1280; i += 256) {
    ((unsigned*)Ksh)[i] = 0u; ((unsigned*)Qsh)[i] = 0u; ((unsigned*)Vth)[i] = 0u;
  }
  __syncthreads();
  for (int i = tid; i < 4*12*19; i += 256) {
    int h = i / 228, r = i % 228, l = r / 19, t2 = r % 19;
    long off = ((long)(b*L_ + l) * N_ + n) * D_ + h*HD_ + 2*t2;
    *(unsigned*)&Ksh[h][l][2*t2] = *(const unsigned*)(kg + off);
    *(unsigned*)&Qsh[h][l][2*t2] = *(const unsigned*)(qg + off);
  }
  for (int i = tid; i < 4*12*19; i += 256) {
    int h = i / 228, r = i % 228, l = r / 19, t2 = r % 19;
    long off = ((long)(b*L_ + l) * N_ + n) * D_ + h*HD_ + 2*t2;
    unsigned u = *(const unsigned*)(vg + off);
    Vth[h][2*t2][l]     = (ushort)(u & 0xffffu);
    Vth[h][2*t2 + 1][l] = (ushort)(u >> 16);
  }
  __syncthreads();
  int lane = tid & 63, w = tid >> 6;
  int cl = lane & 15, gr = lane >> 4;
  const short8 z8 = {0,0,0,0,0,0,0,0};
  short8 a00 = *(const short8*)&Ksh[w][cl][8*gr];
  short8 qB0 = *(const short8*)&Qsh[w][cl][8*gr];
  short8 a01 = (gr == 0) ? *(const short8*)&Ksh[w][cl][32] : z8;
  short8 qB1 = (gr == 0) ? *(const short8*)&Qsh[w][cl][32] : z8;
  float4v sa = (float4v){0,0,0,0};
  sa = __builtin_amdgcn_mfma_f32_16x16x32_bf16(a00, qB0, sa, 0, 0, 0);
  sa = __builtin_amdgcn_mfma_f32_16x16x32_bf16(a01, qB1, sa, 0, 0, 0);
  float p[4];
#pragma unroll
  for (int r = 0; r < 4; ++r) {
    float xv = (4*gr + r < 12) ? sa[r]*C2_ : -1e30f;
    p[r] = __builtin_exp2f(fminf(xv, 80.f));
  }
  float sum_ = (p[0] + p[1]) + (p[2] + p[3]);
  sum_ += __shfl_xor(sum_, 16, 64);
  sum_ += __shfl_xor(sum_, 32, 64);
  unsigned u0 = pk_bf(p[0], p[1]);
  unsigned u1 = pk_bf(p[2], p[3]);
  int srcA = cl + 32*(gr & 1);
  int srcB = srcA + 16;
  unsigned w0 = __shfl(u0, srcA, 64), w1 = __shfl(u1, srcA, 64);
  unsigned w2 = __shfl(u0, srcB, 64), w3 = __shfl(u1, srcB, 64);
  union { unsigned u[4]; short8 v; } pbu;
  bool gv = gr < 2;
  pbu.u[0] = gv ? w0 : 0u; pbu.u[1] = gv ? w1 : 0u;
  pbu.u[2] = gv ? w2 : 0u; pbu.u[3] = gv ? w3 : 0u;
  short8 pB = pbu.v;
  float4v accO[3];
#pragma unroll
  for (int dt = 0; dt < 3; ++dt) {
    short8 aV = (gv && (dt < 2 || cl < 8))
        ? *(const short8*)&Vth[w][16*dt + cl][8*gr] : z8;
    accO[dt] = (float4v){0,0,0,0};
    accO[dt] = __builtin_amdgcn_mfma_f32_16x16x32_bf16(aV, pB, accO[dt], 0, 0, 0);
  }
  if (cl < 12) {
    float inv = 1.f / sum_;
    bf* ap = a + ((long)(b*L_ + cl) * N_ + n) * D_ + w*HD_;
#pragma unroll
    for (int dt = 0; dt < 2; ++dt) {
      *(unsigned*)(ap + 16*dt + 4*gr)     = pk_bf(accO[dt][0]*inv, accO[dt][1]*inv);
      *(unsigned*)(ap + 16*dt + 4*gr + 2) = pk_bf(accO[dt][2]*inv, accO[dt][3]*inv);
    }
    if (gr == 0) {
      *(unsigned*)(ap + 32) = pk_bf(accO[2][0]*inv, accO[2][1]*inv);
      *(unsigned*)(ap + 34) = pk_bf(accO[2][2]*inv, accO[2][3]*inv);
    } else if (gr == 1) {
      *(unsigned*)(ap + 36) = pk_bf(accO[2][0]*inv, accO[2][1]*inv);
    }
  }
}

/* ------------------------------------------------------------------ */
/* Spatial attention v6 (round-5 proven).                             */
__global__ __launch_bounds__(512) void k_attn_s6(
    const ushort* __restrict__ qg, const ushort* __restrict__ kg,
    const ushort* __restrict__ vg, bf* __restrict__ a) {
  __shared__ ushort Ks[360][40];
  __shared__ ushort Vt[38][392];
  int tid = threadIdx.x;
  int lane = tid & 63, w = tid >> 6;
  int cl = lane & 15, gr = lane >> 4;
  bool g0 = (gr == 0);
  const short8 z8 = {0,0,0,0,0,0,0,0};

  for (int uu = 0; uu < 2; ++uu) {
    int id = blockIdx.x * 2 + uu;
    int h = id & 3; int s = id >> 2;
    int b = s / L_; int l = s % L_;
    long base = (long)(b*L_ + l) * N_;
    if (uu) __syncthreads();
    for (int i = tid; i < 360*20; i += 512) {
      int j = i / 20, t2 = i % 20;
      unsigned u = 0u;
      if (j < N_ && t2 < 19)
        u = *(const unsigned*)(kg + (base + j)*D_ + h*HD_ + 2*t2);
      *(unsigned*)&Ks[j][2*t2] = u;
    }
    for (int i = tid; i < N_*19; i += 512) {
      int j = i / 19, t2 = i % 19;
      unsigned u = *(const unsigned*)(vg + (base + j)*D_ + h*HD_ + 2*t2);
      Vt[2*t2][j]     = (ushort)(u & 0xffffu);
      Vt[2*t2 + 1][j] = (ushort)(u >> 16);
    }
    for (int i = tid; i < 38*26; i += 512)
      Vt[i / 26][N_ + i % 26] = 0;
    __syncthreads();

    for (int qt = w; qt < 23; qt += 8) {
      const ushort* qp = qg + (base + 16*qt + cl) * D_ + h*HD_;
      short8 qB0 = ld_g8(qp + 8*gr);
      short8 qB1 = ld_g8(qp + 32 + 8*gr);
      float sum_ = 0.f;
      float4v accO[3];
      accO[0] = (float4v){0,0,0,0};
      accO[1] = (float4v){0,0,0,0};
      accO[2] = (float4v){0,0,0,0};
#pragma unroll 1
      for (int pr = 0; pr < 11; ++pr) {
        int k0 = 32*pr;
        int kr0 = k0 + cl;
        int kr1 = k0 + 16 + cl;
        float4v s0a = (float4v){0,0,0,0}, s1a = (float4v){0,0,0,0};
        {
          short8 a00 = *(const short8*)&Ks[kr0][8*gr];
          short8 a10 = *(const short8*)&Ks[kr1][8*gr];
          __builtin_amdgcn_s_setprio(1);
          s0a = __builtin_amdgcn_mfma_f32_16x16x32_bf16(a00, qB0, s0a, 0, 0, 0);
          s1a = __builtin_amdgcn_mfma_f32_16x16x32_bf16(a10, qB0, s1a, 0, 0, 0);
          short8 a01 = g0 ? *(const short8*)&Ks[kr0][32] : z8;
          short8 a11 = g0 ? *(const short8*)&Ks[kr1][32] : z8;
          s0a = __builtin_amdgcn_mfma_f32_16x16x32_bf16(a01, qB1, s0a, 0, 0, 0);
          s1a = __builtin_amdgcn_mfma_f32_16x16x32_bf16(a11, qB1, s1a, 0, 0, 0);
          __builtin_amdgcn_s_setprio(0);
        }
        float p0[4], p1[4];
#pragma unroll
        for (int r = 0; r < 4; ++r) {
          p0[r] = __builtin_exp2f(fminf(s0a[r]*C2_, 80.f));
          p1[r] = __builtin_exp2f(fminf(s1a[r]*C2_, 80.f));
        }
        sum_ += (p0[0] + p0[1]) + (p0[2] + p0[3])
              + (p1[0] + p1[1]) + (p1[2] + p1[3]);
        unsigned u0 = pk_bf(p0[0], p0[1]);
        unsigned u1 = pk_bf(p0[2], p0[3]);
        unsigned u2 = pk_bf(p1[0], p1[1]);
        unsigned u3 = pk_bf(p1[2], p1[3]);
        int srcA = cl + 16*((2*gr) & 3);
        int srcB = srcA + 16;
        unsigned a0 = __shfl(u0, srcA, 64), b0 = __shfl(u1, srcA, 64);
        unsigned c0 = __shfl(u0, srcB, 64), d0 = __shfl(u1, srcB, 64);
        unsigned a2 = __shfl(u2, srcA, 64), b2 = __shfl(u3, srcA, 64);
        unsigned c2 = __shfl(u2, srcB, 64), d2 = __shfl(u3, srcB, 64);
        bool lo = gr < 2;
        union { unsigned u[4]; short8 v; } pbu;
        pbu.u[0] = lo ? a0 : a2;
        pbu.u[1] = lo ? b0 : b2;
        pbu.u[2] = lo ? c0 : c2;
        pbu.u[3] = lo ? d0 : d2;
        short8 pB = pbu.v;
        __builtin_amdgcn_s_setprio(1);
#pragma unroll
        for (int dt = 0; dt < 3; ++dt) {
          short8 aV = (dt < 2 || cl < 6)
              ? *(const short8*)&Vt[16*dt + cl][k0 + 8*gr] : z8;
          accO[dt] = __builtin_amdgcn_mfma_f32_16x16x32_bf16(aV, pB, accO[dt], 0, 0, 0);
        }
        __builtin_amdgcn_s_setprio(0);
      }
      { /* tail tile: keys 352..357 */
        int k0 = 352;
        int kr0 = k0 + cl; if (kr0 > 359) kr0 = 359;
        float4v s0a = (float4v){0,0,0,0};
        {
          short8 a00 = *(const short8*)&Ks[kr0][8*gr];
          s0a = __builtin_amdgcn_mfma_f32_16x16x32_bf16(a00, qB0, s0a, 0, 0, 0);
          short8 a01 = g0 ? *(const short8*)&Ks[kr0][32] : z8;
          s0a = __builtin_amdgcn_mfma_f32_16x16x32_bf16(a01, qB1, s0a, 0, 0, 0);
        }
        float p0[4];
#pragma unroll
        for (int r = 0; r < 4; ++r) {
          float xv = (4*gr + r < 6) ? s0a[r]*C2_ : -1e30f;
          p0[r] = __builtin_exp2f(fminf(xv, 80.f));
        }
        sum_ += (p0[0] + p0[1]) + (p0[2] + p0[3]);
        unsigned u0 = pk_bf(p0[0], p0[1]);
        unsigned u1 = pk_bf(p0[2], p0[3]);
        int srcA = cl + 16*((2*gr) & 3);
        int srcB = srcA + 16;
        unsigned a0 = __shfl(u0, srcA, 64), b0 = __shfl(u1, srcA, 64);
        unsigned c0 = __shfl(u0, srcB, 64), d0 = __shfl(u1, srcB, 64);
        bool lo = gr < 2;
        union { unsigned u[4]; short8 v; } pbu;
        pbu.u[0] = lo ? a0 : 0u;
        pbu.u[1] = lo ? b0 : 0u;
        pbu.u[2] = lo ? c0 : 0u;
        pbu.u[3] = lo ? d0 : 0u;
        short8 pB = pbu.v;
#pragma unroll
        for (int dt = 0; dt < 3; ++dt) {
          short8 aV = (dt < 2 || cl < 6)
              ? *(const short8*)&Vt[16*dt + cl][k0 + 8*gr] : z8;
          accO[dt] = __builtin_amdgcn_mfma_f32_16x16x32_bf16(aV, pB, accO[dt], 0, 0, 0);
        }
      }
      sum_ += __shfl_xor(sum_, 16, 64);
      sum_ += __shfl_xor(sum_, 32, 64);
      int qi = 16*qt + cl;
      if (qi < N_) {
        float inv = 1.f / sum_;
        bf* ap = a + (base + qi)*D_ + h*HD_;
#pragma unroll
        for (int dt = 0; dt < 2; ++dt) {
          *(unsigned*)(ap + 16*dt + 4*gr)     = pk_bf(accO[dt][0]*inv, accO[dt][1]*inv);
          *(unsigned*)(ap + 16*dt + 4*gr + 2) = pk_bf(accO[dt][2]*inv, accO[dt][3]*inv);
        }
        if (gr == 0) {
          *(unsigned*)(ap + 32) = pk_bf(accO[2][0]*inv, accO[2][1]*inv);
          *(unsigned*)(ap + 34) = pk_bf(accO[2][2]*inv, accO[2][3]*inv);
        } else if (gr == 1) {
          *(unsigned*)(ap + 36) = pk_bf(accO[2][0]*inv, accO[2][1]*inv);
        }
      }
    }
  }
}

/* ------------------------------------------------------------------ */
__global__ __launch_bounds__(256) void k_evtpool(
    const float* __restrict__ marker, const void* __restrict__ doy_mask,
    const float* __restrict__ evt_h, float* __restrict__ evtp) {
  __shared__ int hasF32, hasBig;
  if (threadIdx.x == 0) { hasF32 = 0; hasBig = 0; }
  __syncthreads();
  const unsigned* mw = (const unsigned*)doy_mask;
  for (int w = threadIdx.x; w < 732; w += 256) {
    unsigned u = mw[w];
    if (u == 0x3F800000u) hasF32 = 1;
    else if (u > 1u) hasBig = 1;
  }
  __syncthreads();
  int fmt = hasF32 ? 2 : (hasBig ? 1 : 0);
  int b = blockIdx.x;
  float m3 = marker[((b*L_ + (L_-1))*N_ + 0)*4 + 3];
  int doy = (int)(m3 * 365.f); doy = doy < 0 ? 0 : (doy > 365 ? 365 : doy);
  int j = threadIdx.x;
  float mx = -1e30f;
  for (int kx = 0; kx < 8; ++kx) {
    bool mk;
    if (fmt == 2)      mk = ((const float*)doy_mask)[doy*8 + kx] != 0.f;
    else if (fmt == 1) mk = ((const unsigned char*)doy_mask)[doy*8 + kx] != 0;
    else               mk = ((const int*)doy_mask)[doy*8 + kx] != 0;
    if (mk) mx = fmaxf(mx, evt_h[(b*8 + kx)*256 + j]);
  }
  evtp[b*256 + j] = mx;
}

/* ------------------------------------------------------------------ */
__global__ __launch_bounds__(192) void k_final3(
    const bf* __restrict__ x, const float* __restrict__ wcomb,
    const float* __restrict__ wevtsum, const float* __restrict__ evtp,
    const float* __restrict__ b_mm, const float* __restrict__ b_ts,
    float* __restrict__ out) {
  int id = blockIdx.x; int b = id / N_; int n = id % N_;
  __shared__ float xs[1824];
  __shared__ float part[16][12];
  int tid = threadIdx.x;
  for (int e = tid; e < 912; e += 192) {
    int l = e / 76, du = e % 76;
    unsigned u = *(const unsigned*)((const ushort*)x +
        (((long)(b*L_ + l) * N_ + n) * 152 + 2*du));
    xs[l*152 + 2*du]     = lo_bf(u);
    xs[l*152 + 2*du + 1] = hi_bf(u);
  }
  __syncthreads();
  int g2 = tid / 12, p = tid % 12;
  float acc = 0.f;
  for (int e = g2; e < 1824; e += 16)
    acc += xs[e] * wcomb[e*12 + p];
  part[g2][p] = acc;
  __syncthreads();
  if (tid < 12) {
    float s = b_mm[tid] + b_ts[tid];
    for (int e = 0; e < 256; ++e) s += evtp[b*256 + e] * wevtsum[e*12 + tid];
    for (int gg = 0; gg < 16; ++gg) s += part[gg][tid];
    out[(b*12 + tid) * N_ + n] = s;
  }
}

/* ------------------------------------------------------------------ */
extern "C" void kernel_launch(void* const* d_in, const int* in_sizes, int n_in,
                              void* d_out, int out_size, void* d_ws, size_t ws_size,
                              hipStream_t stream) {
  static const int expect[32] = {
    68736, 274944, 72, 24, 3456, 168, 343680,
    138624, 912, 138624, 912, 138624, 912, 138624, 912,
    233472, 1536, 233472, 912,
    912, 912, 912, 912,
    4195328, 262144, 256,
    58752, 12, 21888, 12,
    2928, 2928 };
  int nb = (out_size + 255)/256;
  if (n_in != 32) {
    k_beacon<<<nb, 256, 0, stream>>>((float*)d_out, out_size, 998.f);
    return;
  }
  for (int i = 0; i < 32; ++i) {
    if (in_sizes[i] != expect[i]) {
      k_beacon<<<nb, 256, 0, stream>>>((float*)d_out, out_size, 1000.f + i);
      return;
    }
  }
  if (out_size != 68736) {
    k_beacon<<<nb, 256, 0, stream>>>((float*)d_out, out_size, 997.f);
    return;
  }

  const float* var_x  = (const float*)d_in[0];
  const float* marker = (const float*)d_in[1];
  const float* W_in   = (const float*)d_in[2];
  const float* b_in   = (const float*)d_in[3];
  const float* tod    = (const float*)d_in[4];
  const float* dow    = (const float*)d_in[5];
  const float* adap   = (const float*)d_in[6];
  const float* Wq = (const float*)d_in[7];  const float* bq = (const float*)d_in[8];
  const float* Wk = (const float*)d_in[9];  const float* bk = (const float*)d_in[10];
  const float* Wv = (const float*)d_in[11]; const float* bv = (const float*)d_in[12];
  const float* Wo = (const float*)d_in[13]; const float* bo = (const float*)d_in[14];
  const float* W1 = (const float*)d_in[15]; const float* b1 = (const float*)d_in[16];
  const float* W2 = (const float*)d_in[17]; const float* b2 = (const float*)d_in[18];
  const float* g1 = (const float*)d_in[19]; const float* be1 = (const float*)d_in[20];
  const float* g2 = (const float*)d_in[21]; const float* be2 = (const float*)d_in[22];
  const float* emb   = (const float*)d_in[23];
  const float* W_evt = (const float*)d_in[24]; const float* b_evt = (const float*)d_in[25];
  const float* W_mm  = (const float*)d_in[26]; const float* b_mm  = (const float*)d_in[27];
  const float* W_ts  = (const float*)d_in[28]; const float* b_ts  = (const float*)d_in[29];
  const int* doyi = (const int*)d_in[30];
  const void* doym = d_in[31];

  const long TD = (long)TOK_ * D_;
  size_t need = (size_t)TD * 2 * 5
              + (size_t)(32768 + 4096 + 3072 + 21888) * 4
              + 2764800
              + 4096;
  if (ws_size < need) {
    k_beacon<<<nb, 256, 0, stream>>>((float*)d_out, out_size, (float)(ws_size >> 20));
    return;
  }

  bf* x = (bf*)d_ws;
  bf* q = x + TD;
  bf* k = q + TD;
  bf* v = k + TD;
  bf* a = v + TD;
  float* evt_h   = (float*)(a + TD);
  float* evtp    = evt_h + 32768;
  float* wevtsum = evtp + 4096;
  float* wcomb   = wevtsum + 3072;
  ushort* wprep  = (ushort*)(wcomb + 21888);

  k_prep<<<PREP_B, 256, 0, stream>>>(
      Wq, Wk, Wv, Wo, W1, W2, (unsigned*)wprep,
      var_x, marker, W_in, b_in, tod, dow, adap, x,
      doyi, emb, W_evt, b_evt, evt_h,
      W_mm, W_ts, wcomb, wevtsum);
  k_evtpool<<<16, 256, 0, stream>>>(marker, doym, evt_h, evtp);
  for (int i = 0; i < 6; ++i) {
    const ushort* pl = wprep + (size_t)i * 230400;
    /* fused QKV projection (64-tok blocks) */
    k_gemm7<152,152,3,64,1,false,false><<<TOK_/64, 512, 0, stream>>>(
        x, pl, bq + i*152, bk + i*152, bv + i*152,
        nullptr, nullptr, nullptr, q, k, v);
    if (i < 3)
      k_attn_t2<<<B_*N_, 256, 0, stream>>>(
          (const ushort*)q, (const ushort*)k, (const ushort*)v, a);
    else
      k_attn_s6<<<B_*L_*2, 512, 0, stream>>>(
          (const ushort*)q, (const ushort*)k, (const ushort*)v, a);
    /* o-proj + residual(x) + LN1 -> k (h)  (128-tok blocks) */
    k_gemm7<152,152,1,128,1,false,true><<<TOK_/128, 512, 0, stream>>>(
        a, pl + 96000, bo + i*152, nullptr, nullptr,
        x, g1 + i*152, be1 + i*152, k, nullptr, nullptr);
    /* fused FFN: x = LN2( relu(k@W1+b1)@W2 + b2 + k ) */
    k_ffn<<<TOK_/64, 512, 0, stream>>>(
        k, pl + 128000, pl + 179200, b1 + i*256, b2 + i*152,
        k, g2 + i*152, be2 + i*152, x);
  }
  k_final3<<<B_*N_, 192, 0, stream>>>(x, wcomb, wevtsum, evtp, b_mm, b_ts,
                                      (float*)d_out);
}

// Round 9
// 1076.905 us; speedup vs baseline: 4.6391x; 1.0395x over previous
//
#include <hip/hip_runtime.h>
#include <hip/hip_bf16.h>

using bf = __hip_bfloat16;

#define B_   16
#define L_   12
#define N_   358
#define D_   152
#define TOK_ (B_*L_*N_)   /* 68736 */
#define FF_  256
#define HD_  38
#define SCALE_ 0.16222142113076254f  /* 38^-0.5 */
#define C2_   0.23403921469340696f   /* SCALE_ * log2(e) */

__device__ __forceinline__ float bf2f(bf x) { return __bfloat162float(x); }
__device__ __forceinline__ bf f2bf(float f) { return __float2bfloat16(f); }
__device__ __forceinline__ float lo_bf(unsigned u) { return __uint_as_float(u << 16); }
__device__ __forceinline__ float hi_bf(unsigned u) { return __uint_as_float(u & 0xffff0000u); }
__device__ __forceinline__ unsigned pk_bf(float a, float b) {
  union { bf h; unsigned short u; } A, Bu;
  A.h = f2bf(a); Bu.h = f2bf(b);
  return ((unsigned)Bu.u << 16) | A.u;
}
__device__ __forceinline__ ushort f2bf_u(float f) {
  union { bf h; ushort u; } t; t.h = f2bf(f); return t.u;
}

using short8  = __attribute__((ext_vector_type(8))) short;
using float4v = __attribute__((ext_vector_type(4))) float;

/* async global->LDS, 16B per lane; dst is wave-uniform base (HW adds lane*16) */
__device__ __forceinline__ void gl_lds16(const void* g, void* l) {
  __builtin_amdgcn_global_load_lds(
      (const __attribute__((address_space(1))) void*)g,
      (__attribute__((address_space(3))) void*)l, 16, 0, 0);
}

/* copy SUBCB bytes global->LDS; 8 waves interleave 1024B blocks */
template<int SUBCB>
__device__ __forceinline__ void issue_w8(const char* gsrc, ushort* lds, int w, int lane) {
  constexpr int TB = SUBCB >> 10;
  constexpr int TAIL = SUBCB & 1023;
#pragma unroll
  for (int blk0 = 0; blk0 < TB; blk0 += 8) {
    int blk = blk0 + w;
    if (blk < TB)
      gl_lds16(gsrc + blk*1024 + (size_t)lane*16, (char*)lds + blk*1024);
  }
  if (TAIL) {
    if (w == (TB & 7) && lane < TAIL/16)
      gl_lds16(gsrc + TB*1024 + (size_t)lane*16, (char*)lds + TB*1024);
  }
}

/* per-wave count of gl_lds16 issues done by issue_w8<SUBCB> (wave-uniform) */
template<int SUBCB>
__device__ __forceinline__ int issue_cnt(int w) {
  constexpr int TB = SUBCB >> 10;
  constexpr int TAIL = SUBCB & 1023;
  int n = (TB > 8 && w < TB - 8) ? 2 : 1;
  if (TAIL && w == (TB & 7)) n += 1;
  return n;
}

/* counted-vmcnt wait: keep newest n loads in flight (n in {1,2,3}) */
__device__ __forceinline__ void vm_wait(int n) {
  if (n == 1)      asm volatile("s_waitcnt vmcnt(1)" ::: "memory");
  else if (n == 2) asm volatile("s_waitcnt vmcnt(2)" ::: "memory");
  else             asm volatile("s_waitcnt vmcnt(3)" ::: "memory");
}

/* 16B logical load from a 4B-aligned (not necessarily 16B-aligned) address */
__device__ __forceinline__ short8 ld_g8(const ushort* p) {
  union { unsigned u[4]; short8 v; } t;
  t.u[0] = *(const unsigned*)(p);
  t.u[1] = *(const unsigned*)(p + 2);
  t.u[2] = *(const unsigned*)(p + 4);
  t.u[3] = *(const unsigned*)(p + 6);
  return t.v;
}

/* ------------------------------------------------------------------ */
__global__ void k_beacon(float* out, int n, float val) {
  int i = blockIdx.x * 256 + threadIdx.x;
  if (i < n) out[i] = val;
}

/* ================= fused prep: wprep | embed | evt1 | wcomb ======= */
#define WPREP_B 2700
#define EMB_B   269
#define EVT_B   128
#define WC_B    86
#define PREP_B  (WPREP_B + EMB_B + EVT_B + WC_B)   /* 3183 */

__device__ void d_wprep(int bid, int tid,
    const float* __restrict__ Wq, const float* __restrict__ Wk,
    const float* __restrict__ Wv, const float* __restrict__ Wo,
    const float* __restrict__ W1, const float* __restrict__ W2,
    unsigned* __restrict__ out) {
  int i = bid * 256 + tid;
  if (i >= 6*115200) return;
  int layer = i / 115200, r = i % 115200;
  const float* src; int K, Nd, d, up, c;
  if (r < 48000) {
    c = r / 9600; int rr = r % 9600; int m = rr / 3200; int r2 = rr % 3200;
    d = r2 / 20; up = r2 % 20;
    src = (m == 0 ? Wq : (m == 1 ? Wk : Wv)) + layer*23104; K = 152; Nd = 152;
  } else if (r < 64000) {
    int rr = r - 48000; c = rr / 3200; int r2 = rr % 3200;
    d = r2 / 20; up = r2 % 20;
    src = Wo + layer*23104; K = 152; Nd = 152;
  } else if (r < 89600) {
    int rr = r - 64000; c = rr / 5120; int r2 = rr % 5120;
    d = r2 / 20; up = r2 % 20;
    src = W1 + layer*38912; K = 152; Nd = 256;
  } else {
    int rr = r - 89600; c = rr / 3200; int r2 = rr % 3200;
    d = r2 / 20; up = r2 % 20;
    src = W2 + layer*38912; K = 256; Nd = 152;
  }
  float v0 = 0.f, v1 = 0.f;
  int k0 = 32*c + 2*up;
  if (up < 16 && d < Nd) {
    if (k0 < K)     v0 = src[(long)k0*Nd + d];
    if (k0 + 1 < K) v1 = src[(long)(k0+1)*Nd + d];
  }
  out[i] = pk_bf(v0, v1);
}

__device__ void d_embed(int bid, int tid,
    const float* __restrict__ var_x, const float* __restrict__ marker,
    const float* __restrict__ W_in, const float* __restrict__ b_in,
    const float* __restrict__ tod_emb, const float* __restrict__ dow_emb,
    const float* __restrict__ adap, bf* __restrict__ x) {
  int t = bid * 256 + tid;
  if (t >= TOK_) return;
  int n = t % N_;
  int l = (t / N_) % L_;
  float var = var_x[t];
  float m0 = marker[t*4 + 0];
  float m1 = marker[t*4 + 1];
  int tod = (int)(m0 * 144.f); tod = tod < 0 ? 0 : (tod > 143 ? 143 : tod);
  int dw  = (int)(m1 * 7.f);   dw  = dw  < 0 ? 0 : (dw  > 6   ? 6   : dw);
  bf* xp = x + (long)t * D_;
  for (int d = 0; d < 24; ++d)
    xp[d] = f2bf(var * W_in[d] + m0 * W_in[24 + d] + m1 * W_in[48 + d] + b_in[d]);
  for (int d = 0; d < 24; ++d) xp[24 + d] = f2bf(tod_emb[tod*24 + d]);
  for (int d = 0; d < 24; ++d) xp[48 + d] = f2bf(dow_emb[dw*24 + d]);
  for (int d = 0; d < 80; ++d) xp[72 + d] = f2bf(adap[(l*N_ + n)*80 + d]);
}

__device__ void d_evt1(int bk, int tid,
    const float* __restrict__ marker, const int* __restrict__ doy_idx,
    const float* __restrict__ emb, const float* __restrict__ W_evt,
    const float* __restrict__ b_evt, float* __restrict__ evt_h) {
  int b = bk >> 3; int ks = bk & 7;
  float m3 = marker[((b*L_ + (L_-1))*N_ + 0)*4 + 3];
  int doy = (int)(m3 * 365.f); doy = doy < 0 ? 0 : (doy > 365 ? 365 : doy);
  int idx = doy_idx[doy*8 + ks];
  if (idx < 0 || idx > 4096) idx = 0;
  int d = tid;
  float acc = b_evt[d];
  const float* er = emb + (long)idx * 1024;
  for (int e = 0; e < 1024; ++e)
    acc += er[e] * W_evt[e*256 + d];
  evt_h[bk*256 + d] = acc;
}

__device__ void d_wcomb(int bid, int tid,
    const float* __restrict__ W_mm, const float* __restrict__ W_ts,
    float* __restrict__ wcomb, float* __restrict__ wevtsum) {
  int i = bid * 256 + tid;
  if (i < 1824*12) {
    int r = i / 12, p = i % 12, l = r / 152, d = r % 152;
    wcomb[i] = W_mm[(l*408 + 256 + d)*12 + p] + W_ts[i];
  }
  if (i < 256*12) {
    int e = i / 12, p = i % 12;
    float s = 0.f;
    for (int l = 0; l < 12; ++l) s += W_mm[(l*408 + e)*12 + p];
    wevtsum[i] = s;
  }
}

__global__ __launch_bounds__(256) void k_prep(
    const float* Wq, const float* Wk, const float* Wv, const float* Wo,
    const float* W1, const float* W2, unsigned* wout,
    const float* var_x, const float* marker, const float* W_in,
    const float* b_in, const float* tod_emb, const float* dow_emb,
    const float* adap, bf* x,
    const int* doyi, const float* emb, const float* W_evt,
    const float* b_evt, float* evt_h,
    const float* W_mm, const float* W_ts, float* wcomb, float* wevtsum) {
  int bid = blockIdx.x, tid = threadIdx.x;
  if (bid < WPREP_B)
    d_wprep(bid, tid, Wq, Wk, Wv, Wo, W1, W2, wout);
  else if (bid < WPREP_B + EMB_B)
    d_embed(bid - WPREP_B, tid, var_x, marker, W_in, b_in, tod_emb, dow_emb, adap, x);
  else if (bid < WPREP_B + EMB_B + EVT_B)
    d_evt1(bid - WPREP_B - EMB_B, tid, marker, doyi, emb, W_evt, b_evt, evt_h);
  else
    d_wcomb(bid - WPREP_B - EMB_B - EVT_B, tid, W_mm, W_ts, wcomb, wevtsum);
}

/* ------------------------------------------------------------------ */
/* GEMM v8 (round-7 proven): counted-vmcnt two-barrier K-loop.        */
template<int K, int Nd, int NW, int TOKB, int CSPLIT, bool RELU, bool LN>
__global__ __launch_bounds__(512) void k_gemm7(
    const bf* __restrict__ X, const ushort* __restrict__ Wg,
    const float* __restrict__ bi0, const float* __restrict__ bi1,
    const float* __restrict__ bi2, const bf* __restrict__ Res,
    const float* __restrict__ g, const float* __restrict__ bb,
    bf* __restrict__ Y0, bf* __restrict__ Y1, bf* __restrict__ Y2) {
  constexpr int NJ   = (Nd + 15) / 16;
  constexpr int NdP  = NJ * 16;
  constexpr int KC   = (K + 31) / 32;
  constexpr int G    = NW * CSPLIT;
  constexpr int S    = KC * G;
  constexpr int IR   = NdP / CSPLIT;
  constexpr int SUB_USH = IR * 40;
  constexpr int SUBCB   = SUB_USH * 2;
  constexpr int NJW  = IR / 32;
  constexpr int MR   = TOKB / 64;
  constexpr bool GLX = (K == 152);
  constexpr int XSTR = GLX ? K : (K + 8);
  __shared__ __align__(16) ushort Xs[TOKB * XSTR + 8];
  __shared__ __align__(16) ushort Wb[2 * SUB_USH];
  long row0 = (long)blockIdx.x * TOKB;
  int tid = threadIdx.x;
  int lane = tid & 63, w = tid >> 6;
  int cl = lane & 15, gr = lane >> 4;
  int wr = w >> 1, wc = w & 1;
  if constexpr (GLX) {
    constexpr int TBX = TOKB * K * 2 / 1024;
    const char* Xgc = (const char*)(X + row0 * K);
#pragma unroll
    for (int b0 = 0; b0 < TBX; b0 += 8) {
      int blk = b0 + w;
      if (blk < TBX)
        gl_lds16(Xgc + blk*1024 + (size_t)lane*16, (char*)Xs + blk*1024);
    }
  } else {
    const char* Xgc = (const char*)(X + row0 * K);
    for (int i = tid; i < TOKB*(K/8); i += 512) {
      int r = i / (K/8), c = i % (K/8);
      *(short8*)&Xs[r*XSTR + 8*c] = *(const short8*)(Xgc + r*(K*2) + c*16);
    }
    __syncthreads();
  }
  const char* gW = (const char*)Wg;
  issue_w8<SUBCB>(gW, Wb, w, lane);
  const int nw = issue_cnt<SUBCB>(w);
  float4v acc[G][MR][NJW];
#pragma unroll
  for (int gi = 0; gi < G; ++gi)
#pragma unroll
    for (int mi = 0; mi < MR; ++mi)
#pragma unroll
      for (int j = 0; j < NJW; ++j) acc[gi][mi][j] = (float4v){0.f,0.f,0.f,0.f};
#pragma unroll
  for (int s = 0; s < S; ++s) {
    if (s + 1 < S) {
      issue_w8<SUBCB>(gW + (size_t)(s+1)*SUBCB, Wb + ((s+1)&1)*SUB_USH, w, lane);
      vm_wait(nw);
    } else {
      asm volatile("s_waitcnt vmcnt(0)" ::: "memory");
    }
    __builtin_amdgcn_s_barrier();
    int kc = (s / G) * 32;
    const ushort* wb = Wb + (s&1)*SUB_USH;
    short8 af[MR];
#pragma unroll
    for (int mi = 0; mi < MR; ++mi)
      af[mi] = *(const short8*)&Xs[((TOKB/4)*wr + 16*mi + cl)*XSTR + kc + 8*gr];
#pragma unroll
    for (int j = 0; j < NJW; ++j) {
      short8 bv = *(const short8*)&wb[((IR/2)*wc + 16*j + cl)*40 + 8*gr];
#pragma unroll
      for (int mi = 0; mi < MR; ++mi)
        acc[s % G][mi][j] =
            __builtin_amdgcn_mfma_f32_16x16x32_bf16(af[mi], bv, acc[s % G][mi][j], 0, 0, 0);
    }
    asm volatile("s_waitcnt lgkmcnt(0)" ::: "memory");
    __builtin_amdgcn_s_barrier();
  }
  if constexpr (!LN) {
#pragma unroll
    for (int gi = 0; gi < G; ++gi) {
      bf* Y = (NW > 1) ? (gi == 0 ? Y0 : (gi == 1 ? Y1 : Y2)) : Y0;
      const float* bp = (NW > 1) ? (gi == 0 ? bi0 : (gi == 1 ? bi1 : bi2)) : bi0;
      int colb = (CSPLIT > 1 ? IR*gi : 0) + (IR/2)*wc;
#pragma unroll
      for (int j = 0; j < NJW; ++j) {
        int col = colb + 16*j + cl;
        if (col < Nd) {
          float bvs = bp[col];
#pragma unroll
          for (int mi = 0; mi < MR; ++mi) {
            long rw = row0 + (TOKB/4)*wr + 16*mi + 4*gr;
#pragma unroll
            for (int r = 0; r < 4; ++r) {
              float val = acc[gi][mi][j][r] + bvs;
              if (RELU) val = fmaxf(val, 0.f);
              Y[(rw + r) * Nd + col] = f2bf(val);
            }
          }
        }
      }
    }
  } else {
    float* LNb = (float*)Wb;
    int colb = (IR/2)*wc;
#pragma unroll
    for (int j = 0; j < NJW; ++j) {
      int col = colb + 16*j + cl;
      if (col < Nd) {
        float bvs = bi0[col];
#pragma unroll
        for (int mi = 0; mi < MR; ++mi) {
          long rw = row0 + (TOKB/4)*wr + 16*mi + 4*gr;
#pragma unroll
          for (int r = 0; r < 4; ++r)
            acc[0][mi][j][r] += bvs + bf2f(Res[(rw + r) * Nd + col]);
        }
      }
    }
    float mean[MR][4], rs[MR][4];
#pragma unroll
    for (int mi = 0; mi < MR; ++mi)
#pragma unroll
      for (int r = 0; r < 4; ++r) {
        float s = 0.f;
#pragma unroll
        for (int j = 0; j < NJW; ++j) s += acc[0][mi][j][r];
        s += __shfl_xor(s, 1, 64); s += __shfl_xor(s, 2, 64);
        s += __shfl_xor(s, 4, 64); s += __shfl_xor(s, 8, 64);
        if (cl == 0) LNb[((wr*MR + mi)*2 + wc)*16 + 4*gr + r] = s;
      }
    __syncthreads();
#pragma unroll
    for (int mi = 0; mi < MR; ++mi)
#pragma unroll
      for (int r = 0; r < 4; ++r) {
        float tot = LNb[((wr*MR + mi)*2 + 0)*16 + 4*gr + r]
                  + LNb[((wr*MR + mi)*2 + 1)*16 + 4*gr + r];
        mean[mi][r] = tot * (1.f / (float)Nd);
      }
#pragma unroll
    for (int mi = 0; mi < MR; ++mi)
#pragma unroll
      for (int r = 0; r < 4; ++r) {
        float s2 = 0.f;
#pragma unroll
        for (int j = 0; j < NJW; ++j) {
          int col = colb + 16*j + cl;
          if (col < Nd) {
            float dv = acc[0][mi][j][r] - mean[mi][r];
            s2 += dv*dv;
          }
        }
        s2 += __shfl_xor(s2, 1, 64); s2 += __shfl_xor(s2, 2, 64);
        s2 += __shfl_xor(s2, 4, 64); s2 += __shfl_xor(s2, 8, 64);
        if (cl == 0) LNb[256 + ((wr*MR + mi)*2 + wc)*16 + 4*gr + r] = s2;
      }
    __syncthreads();
#pragma unroll
    for (int mi = 0; mi < MR; ++mi)
#pragma unroll
      for (int r = 0; r < 4; ++r) {
        float tot2 = LNb[256 + ((wr*MR + mi)*2 + 0)*16 + 4*gr + r]
                   + LNb[256 + ((wr*MR + mi)*2 + 1)*16 + 4*gr + r];
        rs[mi][r] = rsqrtf(tot2 * (1.f / (float)Nd) + 1e-5f);
      }
#pragma unroll
    for (int j = 0; j < NJW; ++j) {
      int col = colb + 16*j + cl;
      if (col < Nd) {
        float gv = g[col], bv2 = bb[col];
#pragma unroll
        for (int mi = 0; mi < MR; ++mi) {
          long rw = row0 + (TOKB/4)*wr + 16*mi + 4*gr;
#pragma unroll
          for (int r = 0; r < 4; ++r)
            Y0[(rw + r) * Nd + col] =
                f2bf((acc[0][mi][j][r] - mean[mi][r]) * rs[mi][r] * gv + bv2);
        }
      }
    }
  }
}

/* ------------------------------------------------------------------ */
/* Fused FFN v2 (round-7 proven).                                     */
__global__ __launch_bounds__(512) void k_ffn(
    const bf* __restrict__ X, const ushort* __restrict__ W1g,
    const ushort* __restrict__ W2g,
    const float* __restrict__ b1, const float* __restrict__ b2,
    const bf* __restrict__ Res, const float* __restrict__ g,
    const float* __restrict__ bb, bf* __restrict__ Y) {
  constexpr int S1 = 10, SUB1 = 5120;
  constexpr int S2 = 8,  SUB2 = 6400;
  constexpr int HSTR = 260;
  __shared__ __align__(16) ushort S_[29440];
  ushort* Xs  = S_;
  ushort* W1b = S_ + 9728;
  ushort* Hs  = S_;
  ushort* W2b = S_ + 16640;
  long row0 = (long)blockIdx.x * 64;
  int tid = threadIdx.x, lane = tid & 63, w = tid >> 6;
  int cl = lane & 15, gr = lane >> 4;
  int wr = w >> 1, wc = w & 1;
  {
    const char* Xgc = (const char*)(X + row0 * 152);
#pragma unroll
    for (int b0 = 0; b0 < 19; b0 += 8) {
      int blk = b0 + w;
      if (blk < 19)
        gl_lds16(Xgc + blk*1024 + (size_t)lane*16, (char*)Xs + blk*1024);
    }
  }
  issue_w8<SUB1*2>((const char*)W1g, W1b, w, lane);
  const int nw1 = issue_cnt<SUB1*2>(w);
  const int nw2 = issue_cnt<SUB2*2>(w);
  float4v acc1[2][4];
#pragma unroll
  for (int g2 = 0; g2 < 2; ++g2)
#pragma unroll
    for (int j = 0; j < 4; ++j) acc1[g2][j] = (float4v){0.f,0.f,0.f,0.f};
#pragma unroll
  for (int s = 0; s < S1; ++s) {
    if (s + 1 < S1) {
      issue_w8<SUB1*2>((const char*)W1g + (size_t)(s+1)*SUB1*2,
                       W1b + ((s+1)&1)*SUB1, w, lane);
      vm_wait(nw1);
    } else {
      asm volatile("s_waitcnt vmcnt(0)" ::: "memory");
    }
    __builtin_amdgcn_s_barrier();
    int kc = (s / 2) * 32;
    const ushort* wb = W1b + (s&1)*SUB1;
    short8 af = *(const short8*)&Xs[(16*wr + cl)*152 + kc + 8*gr];
#pragma unroll
    for (int j = 0; j < 4; ++j) {
      short8 bv = *(const short8*)&wb[(64*wc + 16*j + cl)*40 + 8*gr];
      acc1[s&1][j] =
          __builtin_amdgcn_mfma_f32_16x16x32_bf16(af, bv, acc1[s&1][j], 0, 0, 0);
    }
    asm volatile("s_waitcnt lgkmcnt(0)" ::: "memory");
    __builtin_amdgcn_s_barrier();
  }
#pragma unroll
  for (int g2 = 0; g2 < 2; ++g2)
#pragma unroll
    for (int j = 0; j < 4; ++j) {
      int col = g2*128 + 64*wc + 16*j + cl;
      float bvs = b1[col];
#pragma unroll
      for (int r = 0; r < 4; ++r) {
        int row = 16*wr + 4*gr + r;
        Hs[row*HSTR + col] = f2bf_u(fmaxf(acc1[g2][j][r] + bvs, 0.f));
      }
    }
  issue_w8<SUB2*2>((const char*)W2g, W2b, w, lane);
  asm volatile("s_waitcnt lgkmcnt(0)" ::: "memory");
  __builtin_amdgcn_s_barrier();
  float4v acc2[5];
#pragma unroll
  for (int j = 0; j < 5; ++j) acc2[j] = (float4v){0.f,0.f,0.f,0.f};
#pragma unroll
  for (int s = 0; s < S2; ++s) {
    if (s + 1 < S2) {
      issue_w8<SUB2*2>((const char*)W2g + (size_t)(s+1)*SUB2*2,
                       W2b + ((s+1)&1)*SUB2, w, lane);
      vm_wait(nw2);
    } else {
      asm volatile("s_waitcnt vmcnt(0)" ::: "memory");
    }
    __builtin_amdgcn_s_barrier();
    int kc = s * 32;
    const ushort* wb = W2b + (s&1)*SUB2;
    short8 af = *(const short8*)&Hs[(16*wr + cl)*HSTR + kc + 8*gr];
#pragma unroll
    for (int j = 0; j < 5; ++j) {
      short8 bv = *(const short8*)&wb[(80*wc + 16*j + cl)*40 + 8*gr];
      acc2[j] =
          __builtin_amdgcn_mfma_f32_16x16x32_bf16(af, bv, acc2[j], 0, 0, 0);
    }
    asm volatile("s_waitcnt lgkmcnt(0)" ::: "memory");
    __builtin_amdgcn_s_barrier();
  }
  float* LNb = (float*)W2b;
  int colb = 80*wc;
#pragma unroll
  for (int j = 0; j < 5; ++j) {
    int col = colb + 16*j + cl;
    if (col < D_) {
      float bvs = b2[col];
#pragma unroll
      for (int r = 0; r < 4; ++r)
        acc2[j][r] += bvs + bf2f(Res[(row0 + 16*wr + 4*gr + r) * D_ + col]);
    }
  }
  float mean[4], rsv[4];
#pragma unroll
  for (int r = 0; r < 4; ++r) {
    float s = 0.f;
#pragma unroll
    for (int j = 0; j < 5; ++j)
      if (colb + 16*j + cl < D_) s += acc2[j][r];
    s += __shfl_xor(s, 1, 64); s += __shfl_xor(s, 2, 64);
    s += __shfl_xor(s, 4, 64); s += __shfl_xor(s, 8, 64);
    if (cl == 0) LNb[(wr*2 + wc)*16 + 4*gr + r] = s;
  }
  __syncthreads();
#pragma unroll
  for (int r = 0; r < 4; ++r) {
    float tot = LNb[(wr*2 + 0)*16 + 4*gr + r] + LNb[(wr*2 + 1)*16 + 4*gr + r];
    mean[r] = tot * (1.f / (float)D_);
  }
#pragma unroll
  for (int r = 0; r < 4; ++r) {
    float s2 = 0.f;
#pragma unroll
    for (int j = 0; j < 5; ++j) {
      int col = colb + 16*j + cl;
      if (col < D_) { float dv = acc2[j][r] - mean[r]; s2 += dv*dv; }
    }
    s2 += __shfl_xor(s2, 1, 64); s2 += __shfl_xor(s2, 2, 64);
    s2 += __shfl_xor(s2, 4, 64); s2 += __shfl_xor(s2, 8, 64);
    if (cl == 0) LNb[128 + (wr*2 + wc)*16 + 4*gr + r] = s2;
  }
  __syncthreads();
#pragma unroll
  for (int r = 0; r < 4; ++r) {
    float tot2 = LNb[128 + (wr*2 + 0)*16 + 4*gr + r]
               + LNb[128 + (wr*2 + 1)*16 + 4*gr + r];
    rsv[r] = rsqrtf(tot2 * (1.f / (float)D_) + 1e-5f);
  }
#pragma unroll
  for (int j = 0; j < 5; ++j) {
    int col = colb + 16*j + cl;
    if (col < D_) {
      float gv = g[col], bv2 = bb[col];
#pragma unroll
      for (int r = 0; r < 4; ++r)
        Y[(row0 + 16*wr + 4*gr + r) * D_ + col] =
            f2bf((acc2[j][r] - mean[r]) * rsv[r] * gv + bv2);
    }
  }
}

/* ------------------------------------------------------------------ */
/* Temporal attention v2 (round-5 proven): MFMA swapped-operand.      */
__global__ __launch_bounds__(256) void k_attn_t2(
    const ushort* __restrict__ qg, const ushort* __restrict__ kg,
    const ushort* __restrict__ vg, bf* __restrict__ a) {
  int id = blockIdx.x; int b = id / N_; int n = id % N_;
  __shared__ ushort Ksh[4][16][40];
  __shared__ ushort Qsh[4][16][40];
  __shared__ ushort Vth[4][40][16];
  int tid = threadIdx.x;
  for (int i = tid; i < 1280; i += 256) {
    ((unsigned*)Ksh)[i] = 0u; ((unsigned*)Qsh)[i] = 0u; ((unsigned*)Vth)[i] = 0u;
  }
  __syncthreads();
  for (int i = tid; i < 4*12*19; i += 256) {
    int h = i / 228, r = i % 228, l = r / 19, t2 = r % 19;
    long off = ((long)(b*L_ + l) * N_ + n) * D_ + h*HD_ + 2*t2;
    *(unsigned*)&Ksh[h][l][2*t2] = *(const unsigned*)(kg + off);
    *(unsigned*)&Qsh[h][l][2*t2] = *(const unsigned*)(qg + off);
  }
  for (int i = tid; i < 4*12*19; i += 256) {
    int h = i / 228, r = i % 228, l = r / 19, t2 = r % 19;
    long off = ((long)(b*L_ + l) * N_ + n) * D_ + h*HD_ + 2*t2;
    unsigned u = *(const unsigned*)(vg + off);
    Vth[h][2*t2][l]     = (ushort)(u & 0xffffu);
    Vth[h][2*t2 + 1][l] = (ushort)(u >> 16);
  }
  __syncthreads();
  int lane = tid & 63, w = tid >> 6;
  int cl = lane & 15, gr = lane >> 4;
  const short8 z8 = {0,0,0,0,0,0,0,0};
  short8 a00 = *(const short8*)&Ksh[w][cl][8*gr];
  short8 qB0 = *(const short8*)&Qsh[w][cl][8*gr];
  short8 a01 = (gr == 0) ? *(const short8*)&Ksh[w][cl][32] : z8;
  short8 qB1 = (gr == 0) ? *(const short8*)&Qsh[w][cl][32] : z8;
  float4v sa = (float4v){0,0,0,0};
  sa = __builtin_amdgcn_mfma_f32_16x16x32_bf16(a00, qB0, sa, 0, 0, 0);
  sa = __builtin_amdgcn_mfma_f32_16x16x32_bf16(a01, qB1, sa, 0, 0, 0);
  float p[4];
#pragma unroll
  for (int r = 0; r < 4; ++r) {
    float xv = (4*gr + r < 12) ? sa[r]*C2_ : -1e30f;
    p[r] = __builtin_exp2f(fminf(xv, 80.f));
  }
  float sum_ = (p[0] + p[1]) + (p[2] + p[3]);
  sum_ += __shfl_xor(sum_, 16, 64);
  sum_ += __shfl_xor(sum_, 32, 64);
  unsigned u0 = pk_bf(p[0], p[1]);
  unsigned u1 = pk_bf(p[2], p[3]);
  int srcA = cl + 32*(gr & 1);
  int srcB = srcA + 16;
  unsigned w0 = __shfl(u0, srcA, 64), w1 = __shfl(u1, srcA, 64);
  unsigned w2 = __shfl(u0, srcB, 64), w3 = __shfl(u1, srcB, 64);
  union { unsigned u[4]; short8 v; } pbu;
  bool gv = gr < 2;
  pbu.u[0] = gv ? w0 : 0u; pbu.u[1] = gv ? w1 : 0u;
  pbu.u[2] = gv ? w2 : 0u; pbu.u[3] = gv ? w3 : 0u;
  short8 pB = pbu.v;
  float4v accO[3];
#pragma unroll
  for (int dt = 0; dt < 3; ++dt) {
    short8 aV = (gv && (dt < 2 || cl < 8))
        ? *(const short8*)&Vth[w][16*dt + cl][8*gr] : z8;
    accO[dt] = (float4v){0,0,0,0};
    accO[dt] = __builtin_amdgcn_mfma_f32_16x16x32_bf16(aV, pB, accO[dt], 0, 0, 0);
  }
  if (cl < 12) {
    float inv = 1.f / sum_;
    bf* ap = a + ((long)(b*L_ + cl) * N_ + n) * D_ + w*HD_;
#pragma unroll
    for (int dt = 0; dt < 2; ++dt) {
      *(unsigned*)(ap + 16*dt + 4*gr)     = pk_bf(accO[dt][0]*inv, accO[dt][1]*inv);
      *(unsigned*)(ap + 16*dt + 4*gr + 2) = pk_bf(accO[dt][2]*inv, accO[dt][3]*inv);
    }
    if (gr == 0) {
      *(unsigned*)(ap + 32) = pk_bf(accO[2][0]*inv, accO[2][1]*inv);
      *(unsigned*)(ap + 34) = pk_bf(accO[2][2]*inv, accO[2][3]*inv);
    } else if (gr == 1) {
      *(unsigned*)(ap + 36) = pk_bf(accO[2][0]*inv, accO[2][1]*inv);
    }
  }
}

/* ------------------------------------------------------------------ */
/* Spatial attention v6b: round-5-proven s6 body, ONE (b,l,h) unit per
   block (grid 768 = 3x256: exact CU balance + cross-block stage/compute
   overlap; s6's 2-unit pairing serialized them behind a barrier).    */
__global__ __launch_bounds__(512) void k_attn_s6(
    const ushort* __restrict__ qg, const ushort* __restrict__ kg,
    const ushort* __restrict__ vg, bf* __restrict__ a) {
  __shared__ ushort Ks[360][40];
  __shared__ ushort Vt[38][392];
  int tid = threadIdx.x;
  int lane = tid & 63, w = tid >> 6;
  int cl = lane & 15, gr = lane >> 4;
  bool g0 = (gr == 0);
  const short8 z8 = {0,0,0,0,0,0,0,0};

  int id = blockIdx.x;
  int h = id & 3; int s = id >> 2;
  int b = s / L_; int l = s % L_;
  long base = (long)(b*L_ + l) * N_;
  for (int i = tid; i < 360*20; i += 512) {
    int j = i / 20, t2 = i % 20;
    unsigned u = 0u;
    if (j < N_ && t2 < 19)
      u = *(const unsigned*)(kg + (base + j)*D_ + h*HD_ + 2*t2);
    *(unsigned*)&Ks[j][2*t2] = u;
  }
  for (int i = tid; i < N_*19; i += 512) {
    int j = i / 19, t2 = i % 19;
    unsigned u = *(const unsigned*)(vg + (base + j)*D_ + h*HD_ + 2*t2);
    Vt[2*t2][j]     = (ushort)(u & 0xffffu);
    Vt[2*t2 + 1][j] = (ushort)(u >> 16);
  }
  for (int i = tid; i < 38*26; i += 512)
    Vt[i / 26][N_ + i % 26] = 0;
  __syncthreads();

  for (int qt = w; qt < 23; qt += 8) {
    const ushort* qp = qg + (base + 16*qt + cl) * D_ + h*HD_;
    short8 qB0 = ld_g8(qp + 8*gr);
    short8 qB1 = ld_g8(qp + 32 + 8*gr);
    float sum_ = 0.f;
    float4v accO[3];
    accO[0] = (float4v){0,0,0,0};
    accO[1] = (float4v){0,0,0,0};
    accO[2] = (float4v){0,0,0,0};
#pragma unroll 1
    for (int pr = 0; pr < 11; ++pr) {
      int k0 = 32*pr;
      int kr0 = k0 + cl;
      int kr1 = k0 + 16 + cl;
      float4v s0a = (float4v){0,0,0,0}, s1a = (float4v){0,0,0,0};
      {
        short8 a00 = *(const short8*)&Ks[kr0][8*gr];
        short8 a10 = *(const short8*)&Ks[kr1][8*gr];
        __builtin_amdgcn_s_setprio(1);
        s0a = __builtin_amdgcn_mfma_f32_16x16x32_bf16(a00, qB0, s0a, 0, 0, 0);
        s1a = __builtin_amdgcn_mfma_f32_16x16x32_bf16(a10, qB0, s1a, 0, 0, 0);
        short8 a01 = g0 ? *(const short8*)&Ks[kr0][32] : z8;
        short8 a11 = g0 ? *(const short8*)&Ks[kr1][32] : z8;
        s0a = __builtin_amdgcn_mfma_f32_16x16x32_bf16(a01, qB1, s0a, 0, 0, 0);
        s1a = __builtin_amdgcn_mfma_f32_16x16x32_bf16(a11, qB1, s1a, 0, 0, 0);
        __builtin_amdgcn_s_setprio(0);
      }
      float p0[4], p1[4];
#pragma unroll
      for (int r = 0; r < 4; ++r) {
        p0[r] = __builtin_exp2f(fminf(s0a[r]*C2_, 80.f));
        p1[r] = __builtin_exp2f(fminf(s1a[r]*C2_, 80.f));
      }
      sum_ += (p0[0] + p0[1]) + (p0[2] + p0[3])
            + (p1[0] + p1[1]) + (p1[2] + p1[3]);
      unsigned u0 = pk_bf(p0[0], p0[1]);
      unsigned u1 = pk_bf(p0[2], p0[3]);
      unsigned u2 = pk_bf(p1[0], p1[1]);
      unsigned u3 = pk_bf(p1[2], p1[3]);
      int srcA = cl + 16*((2*gr) & 3);
      int srcB = srcA + 16;
      unsigned a0 = __shfl(u0, srcA, 64), b0 = __shfl(u1, srcA, 64);
      unsigned c0 = __shfl(u0, srcB, 64), d0 = __shfl(u1, srcB, 64);
      unsigned a2 = __shfl(u2, srcA, 64), b2 = __shfl(u3, srcA, 64);
      unsigned c2 = __shfl(u2, srcB, 64), d2 = __shfl(u3, srcB, 64);
      bool lo = gr < 2;
      union { unsigned u[4]; short8 v; } pbu;
      pbu.u[0] = lo ? a0 : a2;
      pbu.u[1] = lo ? b0 : b2;
      pbu.u[2] = lo ? c0 : c2;
      pbu.u[3] = lo ? d0 : d2;
      short8 pB = pbu.v;
      __builtin_amdgcn_s_setprio(1);
#pragma unroll
      for (int dt = 0; dt < 3; ++dt) {
        short8 aV = (dt < 2 || cl < 6)
            ? *(const short8*)&Vt[16*dt + cl][k0 + 8*gr] : z8;
        accO[dt] = __builtin_amdgcn_mfma_f32_16x16x32_bf16(aV, pB, accO[dt], 0, 0, 0);
      }
      __builtin_amdgcn_s_setprio(0);
    }
    { /* tail tile: keys 352..357 */
      int k0 = 352;
      int kr0 = k0 + cl; if (kr0 > 359) kr0 = 359;
      float4v s0a = (float4v){0,0,0,0};
      {
        short8 a00 = *(const short8*)&Ks[kr0][8*gr];
        s0a = __builtin_amdgcn_mfma_f32_16x16x32_bf16(a00, qB0, s0a, 0, 0, 0);
        short8 a01 = g0 ? *(const short8*)&Ks[kr0][32] : z8;
        s0a = __builtin_amdgcn_mfma_f32_16x16x32_bf16(a01, qB1, s0a, 0, 0, 0);
      }
      float p0[4];
#pragma unroll
      for (int r = 0; r < 4; ++r) {
        float xv = (4*gr + r < 6) ? s0a[r]*C2_ : -1e30f;
        p0[r] = __builtin_exp2f(fminf(xv, 80.f));
      }
      sum_ += (p0[0] + p0[1]) + (p0[2] + p0[3]);
      unsigned u0 = pk_bf(p0[0], p0[1]);
      unsigned u1 = pk_bf(p0[2], p0[3]);
      int srcA = cl + 16*((2*gr) & 3);
      int srcB = srcA + 16;
      unsigned a0 = __shfl(u0, srcA, 64), b0 = __shfl(u1, srcA, 64);
      unsigned c0 = __shfl(u0, srcB, 64), d0 = __shfl(u1, srcB, 64);
      bool lo = gr < 2;
      union { unsigned u[4]; short8 v; } pbu;
      pbu.u[0] = lo ? a0 : 0u;
      pbu.u[1] = lo ? b0 : 0u;
      pbu.u[2] = lo ? c0 : 0u;
      pbu.u[3] = lo ? d0 : 0u;
      short8 pB = pbu.v;
#pragma unroll
      for (int dt = 0; dt < 3; ++dt) {
        short8 aV = (dt < 2 || cl < 6)
            ? *(const short8*)&Vt[16*dt + cl][k0 + 8*gr] : z8;
        accO[dt] = __builtin_amdgcn_mfma_f32_16x16x32_bf16(aV, pB, accO[dt], 0, 0, 0);
      }
    }
    sum_ += __shfl_xor(sum_, 16, 64);
    sum_ += __shfl_xor(sum_, 32, 64);
    int qi = 16*qt + cl;
    if (qi < N_) {
      float inv = 1.f / sum_;
      bf* ap = a + (base + qi)*D_ + h*HD_;
#pragma unroll
      for (int dt = 0; dt < 2; ++dt) {
        *(unsigned*)(ap + 16*dt + 4*gr)     = pk_bf(accO[dt][0]*inv, accO[dt][1]*inv);
        *(unsigned*)(ap + 16*dt + 4*gr + 2) = pk_bf(accO[dt][2]*inv, accO[dt][3]*inv);
      }
      if (gr == 0) {
        *(unsigned*)(ap + 32) = pk_bf(accO[2][0]*inv, accO[2][1]*inv);
        *(unsigned*)(ap + 34) = pk_bf(accO[2][2]*inv, accO[2][3]*inv);
      } else if (gr == 1) {
        *(unsigned*)(ap + 36) = pk_bf(accO[2][0]*inv, accO[2][1]*inv);
      }
    }
  }
}

/* ------------------------------------------------------------------ */
__global__ __launch_bounds__(256) void k_evtpool(
    const float* __restrict__ marker, const void* __restrict__ doy_mask,
    const float* __restrict__ evt_h, float* __restrict__ evtp) {
  __shared__ int hasF32, hasBig;
  if (threadIdx.x == 0) { hasF32 = 0; hasBig = 0; }
  __syncthreads();
  const unsigned* mw = (const unsigned*)doy_mask;
  for (int w = threadIdx.x; w < 732; w += 256) {
    unsigned u = mw[w];
    if (u == 0x3F800000u) hasF32 = 1;
    else if (u > 1u) hasBig = 1;
  }
  __syncthreads();
  int fmt = hasF32 ? 2 : (hasBig ? 1 : 0);
  int b = blockIdx.x;
  float m3 = marker[((b*L_ + (L_-1))*N_ + 0)*4 + 3];
  int doy = (int)(m3 * 365.f); doy = doy < 0 ? 0 : (doy > 365 ? 365 : doy);
  int j = threadIdx.x;
  float mx = -1e30f;
  for (int kx = 0; kx < 8; ++kx) {
    bool mk;
    if (fmt == 2)      mk = ((const float*)doy_mask)[doy*8 + kx] != 0.f;
    else if (fmt == 1) mk = ((const unsigned char*)doy_mask)[doy*8 + kx] != 0;
    else               mk = ((const int*)doy_mask)[doy*8 + kx] != 0;
    if (mk) mx = fmaxf(mx, evt_h[(b*8 + kx)*256 + j]);
  }
  evtp[b*256 + j] = mx;
}

/* ------------------------------------------------------------------ */
__global__ __launch_bounds__(192) void k_final3(
    const bf* __restrict__ x, const float* __restrict__ wcomb,
    const float* __restrict__ wevtsum, const float* __restrict__ evtp,
    const float* __restrict__ b_mm, const float* __restrict__ b_ts,
    float* __restrict__ out) {
  int id = blockIdx.x; int b = id / N_; int n = id % N_;
  __shared__ float xs[1824];
  __shared__ float part[16][12];
  int tid = threadIdx.x;
  for (int e = tid; e < 912; e += 192) {
    int l = e / 76, du = e % 76;
    unsigned u = *(const unsigned*)((const ushort*)x +
        (((long)(b*L_ + l) * N_ + n) * 152 + 2*du));
    xs[l*152 + 2*du]     = lo_bf(u);
    xs[l*152 + 2*du + 1] = hi_bf(u);
  }
  __syncthreads();
  int g2 = tid / 12, p = tid % 12;
  float acc = 0.f;
  for (int e = g2; e < 1824; e += 16)
    acc += xs[e] * wcomb[e*12 + p];
  part[g2][p] = acc;
  __syncthreads();
  if (tid < 12) {
    float s = b_mm[tid] + b_ts[tid];
    for (int e = 0; e < 256; ++e) s += evtp[b*256 + e] * wevtsum[e*12 + tid];
    for (int gg = 0; gg < 16; ++gg) s += part[gg][tid];
    out[(b*12 + tid) * N_ + n] = s;
  }
}

/* ------------------------------------------------------------------ */
extern "C" void kernel_launch(void* const* d_in, const int* in_sizes, int n_in,
                              void* d_out, int out_size, void* d_ws, size_t ws_size,
                              hipStream_t stream) {
  static const int expect[32] = {
    68736, 274944, 72, 24, 3456, 168, 343680,
    138624, 912, 138624, 912, 138624, 912, 138624, 912,
    233472, 1536, 233472, 912,
    912, 912, 912, 912,
    4195328, 262144, 256,
    58752, 12, 21888, 12,
    2928, 2928 };
  int nb = (out_size + 255)/256;
  if (n_in != 32) {
    k_beacon<<<nb, 256, 0, stream>>>((float*)d_out, out_size, 998.f);
    return;
  }
  for (int i = 0; i < 32; ++i) {
    if (in_sizes[i] != expect[i]) {
      k_beacon<<<nb, 256, 0, stream>>>((float*)d_out, out_size, 1000.f + i);
      return;
    }
  }
  if (out_size != 68736) {
    k_beacon<<<nb, 256, 0, stream>>>((float*)d_out, out_size, 997.f);
    return;
  }

  const float* var_x  = (const float*)d_in[0];
  const float* marker = (const float*)d_in[1];
  const float* W_in   = (const float*)d_in[2];
  const float* b_in   = (const float*)d_in[3];
  const float* tod    = (const float*)d_in[4];
  const float* dow    = (const float*)d_in[5];
  const float* adap   = (const float*)d_in[6];
  const float* Wq = (const float*)d_in[7];  const float* bq = (const float*)d_in[8];
  const float* Wk = (const float*)d_in[9];  const float* bk = (const float*)d_in[10];
  const float* Wv = (const float*)d_in[11]; const float* bv = (const float*)d_in[12];
  const float* Wo = (const float*)d_in[13]; const float* bo = (const float*)d_in[14];
  const float* W1 = (const float*)d_in[15]; const float* b1 = (const float*)d_in[16];
  const float* W2 = (const float*)d_in[17]; const float* b2 = (const float*)d_in[18];
  const float* g1 = (const float*)d_in[19]; const float* be1 = (const float*)d_in[20];
  const float* g2 = (const float*)d_in[21]; const float* be2 = (const float*)d_in[22];
  const float* emb   = (const float*)d_in[23];
  const float* W_evt = (const float*)d_in[24]; const float* b_evt = (const float*)d_in[25];
  const float* W_mm  = (const float*)d_in[26]; const float* b_mm  = (const float*)d_in[27];
  const float* W_ts  = (const float*)d_in[28]; const float* b_ts  = (const float*)d_in[29];
  const int* doyi = (const int*)d_in[30];
  const void* doym = d_in[31];

  const long TD = (long)TOK_ * D_;
  size_t need = (size_t)TD * 2 * 5
              + (size_t)(32768 + 4096 + 3072 + 21888) * 4
              + 2764800
              + 4096;
  if (ws_size < need) {
    k_beacon<<<nb, 256, 0, stream>>>((float*)d_out, out_size, (float)(ws_size >> 20));
    return;
  }

  bf* x = (bf*)d_ws;
  bf* q = x + TD;
  bf* k = q + TD;
  bf* v = k + TD;
  bf* a = v + TD;
  float* evt_h   = (float*)(a + TD);
  float* evtp    = evt_h + 32768;
  float* wevtsum = evtp + 4096;
  float* wcomb   = wevtsum + 3072;
  ushort* wprep  = (ushort*)(wcomb + 21888);

  k_prep<<<PREP_B, 256, 0, stream>>>(
      Wq, Wk, Wv, Wo, W1, W2, (unsigned*)wprep,
      var_x, marker, W_in, b_in, tod, dow, adap, x,
      doyi, emb, W_evt, b_evt, evt_h,
      W_mm, W_ts, wcomb, wevtsum);
  k_evtpool<<<16, 256, 0, stream>>>(marker, doym, evt_h, evtp);
  for (int i = 0; i < 6; ++i) {
    const ushort* pl = wprep + (size_t)i * 230400;
    /* fused QKV projection (64-tok blocks) */
    k_gemm7<152,152,3,64,1,false,false><<<TOK_/64, 512, 0, stream>>>(
        x, pl, bq + i*152, bk + i*152, bv + i*152,
        nullptr, nullptr, nullptr, q, k, v);
    if (i < 3)
      k_attn_t2<<<B_*N_, 256, 0, stream>>>(
          (const ushort*)q, (const ushort*)k, (const ushort*)v, a);
    else
      k_attn_s6<<<B_*L_*4, 512, 0, stream>>>(
          (const ushort*)q, (const ushort*)k, (const ushort*)v, a);
    /* o-proj + residual(x) + LN1 -> k (h)  (128-tok blocks) */
    k_gemm7<152,152,1,128,1,false,true><<<TOK_/128, 512, 0, stream>>>(
        a, pl + 96000, bo + i*152, nullptr, nullptr,
        x, g1 + i*152, be1 + i*152, k, nullptr, nullptr);
    /* fused FFN: x = LN2( relu(k@W1+b1)@W2 + b2 + k ) */
    k_ffn<<<TOK_/64, 512, 0, stream>>>(
        k, pl + 128000, pl + 179200, b1 + i*256, b2 + i*152,
        k, g2 + i*152, be2 + i*152, x);
  }
  k_final3<<<B_*N_, 192, 0, stream>>>(x, wcomb, wevtsum, evtp, b_mm, b_ts,
                                      (float*)d_out);
}

// Round 11
// 1008.102 us; speedup vs baseline: 4.9557x; 1.0683x over previous
//
#include <hip/hip_runtime.h>
#include <hip/hip_bf16.h>

using bf = __hip_bfloat16;

#define B_   16
#define L_   12
#define N_   358
#define D_   152
#define TOK_ (B_*L_*N_)   /* 68736 */
#define FF_  256
#define HD_  38
#define SCALE_ 0.16222142113076254f  /* 38^-0.5 */
#define C2_   0.23403921469340696f   /* SCALE_ * log2(e) */

__device__ __forceinline__ float bf2f(bf x) { return __bfloat162float(x); }
__device__ __forceinline__ bf f2bf(float f) { return __float2bfloat16(f); }
__device__ __forceinline__ float lo_bf(unsigned u) { return __uint_as_float(u << 16); }
__device__ __forceinline__ float hi_bf(unsigned u) { return __uint_as_float(u & 0xffff0000u); }
__device__ __forceinline__ unsigned pk_bf(float a, float b) {
  union { bf h; unsigned short u; } A, Bu;
  A.h = f2bf(a); Bu.h = f2bf(b);
  return ((unsigned)Bu.u << 16) | A.u;
}
__device__ __forceinline__ ushort f2bf_u(float f) {
  union { bf h; ushort u; } t; t.h = f2bf(f); return t.u;
}

using short8  = __attribute__((ext_vector_type(8))) short;
using float4v = __attribute__((ext_vector_type(4))) float;

/* async global->LDS, 16B per lane; dst is wave-uniform base (HW adds lane*16) */
__device__ __forceinline__ void gl_lds16(const void* g, void* l) {
  __builtin_amdgcn_global_load_lds(
      (const __attribute__((address_space(1))) void*)g,
      (__attribute__((address_space(3))) void*)l, 16, 0, 0);
}

/* copy SUBCB bytes global->LDS; 8 waves interleave 1024B blocks */
template<int SUBCB>
__device__ __forceinline__ void issue_w8(const char* gsrc, ushort* lds, int w, int lane) {
  constexpr int TB = SUBCB >> 10;
  constexpr int TAIL = SUBCB & 1023;
#pragma unroll
  for (int blk0 = 0; blk0 < TB; blk0 += 8) {
    int blk = blk0 + w;
    if (blk < TB)
      gl_lds16(gsrc + blk*1024 + (size_t)lane*16, (char*)lds + blk*1024);
  }
  if (TAIL) {
    if (w == (TB & 7) && lane < TAIL/16)
      gl_lds16(gsrc + TB*1024 + (size_t)lane*16, (char*)lds + TB*1024);
  }
}

/* per-wave count of gl_lds16 issues done by issue_w8<SUBCB> (wave-uniform) */
template<int SUBCB>
__device__ __forceinline__ int issue_cnt(int w) {
  constexpr int TB = SUBCB >> 10;
  constexpr int TAIL = SUBCB & 1023;
  int n = (TB > 8 && w < TB - 8) ? 2 : 1;
  if (TAIL && w == (TB & 7)) n += 1;
  return n;
}

/* counted-vmcnt wait: keep newest n loads in flight (n in {1,2,3}) */
__device__ __forceinline__ void vm_wait(int n) {
  if (n == 1)      asm volatile("s_waitcnt vmcnt(1)" ::: "memory");
  else if (n == 2) asm volatile("s_waitcnt vmcnt(2)" ::: "memory");
  else             asm volatile("s_waitcnt vmcnt(3)" ::: "memory");
}

/* 16B logical load from a 4B-aligned (not necessarily 16B-aligned) address */
__device__ __forceinline__ short8 ld_g8(const ushort* p) {
  union { unsigned u[4]; short8 v; } t;
  t.u[0] = *(const unsigned*)(p);
  t.u[1] = *(const unsigned*)(p + 2);
  t.u[2] = *(const unsigned*)(p + 4);
  t.u[3] = *(const unsigned*)(p + 6);
  return t.v;
}

/* ------------------------------------------------------------------ */
__global__ void k_beacon(float* out, int n, float val) {
  int i = blockIdx.x * 256 + threadIdx.x;
  if (i < n) out[i] = val;
}

/* ================= fused prep: wprep | embed | evt1 | wcomb ======= */
#define WPREP_B 2700
#define EMB_B   269
#define EVT_B   128
#define WC_B    86
#define PREP_B  (WPREP_B + EMB_B + EVT_B + WC_B)   /* 3183 */

__device__ void d_wprep(int bid, int tid,
    const float* __restrict__ Wq, const float* __restrict__ Wk,
    const float* __restrict__ Wv, const float* __restrict__ Wo,
    const float* __restrict__ W1, const float* __restrict__ W2,
    unsigned* __restrict__ out) {
  int i = bid * 256 + tid;
  if (i >= 6*115200) return;
  int layer = i / 115200, r = i % 115200;
  const float* src; int K, Nd, d, up, c;
  if (r < 48000) {
    c = r / 9600; int rr = r % 9600; int m = rr / 3200; int r2 = rr % 3200;
    d = r2 / 20; up = r2 % 20;
    src = (m == 0 ? Wq : (m == 1 ? Wk : Wv)) + layer*23104; K = 152; Nd = 152;
  } else if (r < 64000) {
    int rr = r - 48000; c = rr / 3200; int r2 = rr % 3200;
    d = r2 / 20; up = r2 % 20;
    src = Wo + layer*23104; K = 152; Nd = 152;
  } else if (r < 89600) {
    int rr = r - 64000; c = rr / 5120; int r2 = rr % 5120;
    d = r2 / 20; up = r2 % 20;
    src = W1 + layer*38912; K = 152; Nd = 256;
  } else {
    int rr = r - 89600; c = rr / 3200; int r2 = rr % 3200;
    d = r2 / 20; up = r2 % 20;
    src = W2 + layer*38912; K = 256; Nd = 152;
  }
  float v0 = 0.f, v1 = 0.f;
  int k0 = 32*c + 2*up;
  if (up < 16 && d < Nd) {
    if (k0 < K)     v0 = src[(long)k0*Nd + d];
    if (k0 + 1 < K) v1 = src[(long)(k0+1)*Nd + d];
  }
  out[i] = pk_bf(v0, v1);
}

__device__ void d_embed(int bid, int tid,
    const float* __restrict__ var_x, const float* __restrict__ marker,
    const float* __restrict__ W_in, const float* __restrict__ b_in,
    const float* __restrict__ tod_emb, const float* __restrict__ dow_emb,
    const float* __restrict__ adap, bf* __restrict__ x) {
  int t = bid * 256 + tid;
  if (t >= TOK_) return;
  int n = t % N_;
  int l = (t / N_) % L_;
  float var = var_x[t];
  float m0 = marker[t*4 + 0];
  float m1 = marker[t*4 + 1];
  int tod = (int)(m0 * 144.f); tod = tod < 0 ? 0 : (tod > 143 ? 143 : tod);
  int dw  = (int)(m1 * 7.f);   dw  = dw  < 0 ? 0 : (dw  > 6   ? 6   : dw);
  bf* xp = x + (long)t * D_;
  for (int d = 0; d < 24; ++d)
    xp[d] = f2bf(var * W_in[d] + m0 * W_in[24 + d] + m1 * W_in[48 + d] + b_in[d]);
  for (int d = 0; d < 24; ++d) xp[24 + d] = f2bf(tod_emb[tod*24 + d]);
  for (int d = 0; d < 24; ++d) xp[48 + d] = f2bf(dow_emb[dw*24 + d]);
  for (int d = 0; d < 80; ++d) xp[72 + d] = f2bf(adap[(l*N_ + n)*80 + d]);
}

__device__ void d_evt1(int bk, int tid,
    const float* __restrict__ marker, const int* __restrict__ doy_idx,
    const float* __restrict__ emb, const float* __restrict__ W_evt,
    const float* __restrict__ b_evt, float* __restrict__ evt_h) {
  int b = bk >> 3; int ks = bk & 7;
  float m3 = marker[((b*L_ + (L_-1))*N_ + 0)*4 + 3];
  int doy = (int)(m3 * 365.f); doy = doy < 0 ? 0 : (doy > 365 ? 365 : doy);
  int idx = doy_idx[doy*8 + ks];
  if (idx < 0 || idx > 4096) idx = 0;
  int d = tid;
  float acc = b_evt[d];
  const float* er = emb + (long)idx * 1024;
  for (int e = 0; e < 1024; ++e)
    acc += er[e] * W_evt[e*256 + d];
  evt_h[bk*256 + d] = acc;
}

__device__ void d_wcomb(int bid, int tid,
    const float* __restrict__ W_mm, const float* __restrict__ W_ts,
    float* __restrict__ wcomb, float* __restrict__ wevtsum) {
  int i = bid * 256 + tid;
  if (i < 1824*12) {
    int r = i / 12, p = i % 12, l = r / 152, d = r % 152;
    wcomb[i] = W_mm[(l*408 + 256 + d)*12 + p] + W_ts[i];
  }
  if (i < 256*12) {
    int e = i / 12, p = i % 12;
    float s = 0.f;
    for (int l = 0; l < 12; ++l) s += W_mm[(l*408 + e)*12 + p];
    wevtsum[i] = s;
  }
}

__global__ __launch_bounds__(256) void k_prep(
    const float* Wq, const float* Wk, const float* Wv, const float* Wo,
    const float* W1, const float* W2, unsigned* wout,
    const float* var_x, const float* marker, const float* W_in,
    const float* b_in, const float* tod_emb, const float* dow_emb,
    const float* adap, bf* x,
    const int* doyi, const float* emb, const float* W_evt,
    const float* b_evt, float* evt_h,
    const float* W_mm, const float* W_ts, float* wcomb, float* wevtsum) {
  int bid = blockIdx.x, tid = threadIdx.x;
  if (bid < WPREP_B)
    d_wprep(bid, tid, Wq, Wk, Wv, Wo, W1, W2, wout);
  else if (bid < WPREP_B + EMB_B)
    d_embed(bid - WPREP_B, tid, var_x, marker, W_in, b_in, tod_emb, dow_emb, adap, x);
  else if (bid < WPREP_B + EMB_B + EVT_B)
    d_evt1(bid - WPREP_B - EMB_B, tid, marker, doyi, emb, W_evt, b_evt, evt_h);
  else
    d_wcomb(bid - WPREP_B - EMB_B - EVT_B, tid, W_mm, W_ts, wcomb, wevtsum);
}

/* ------------------------------------------------------------------ */
/* GEMM v8 (round-7/9 proven): counted-vmcnt two-barrier K-loop.
   Used only for the fused QKV projection (unchanged from round 9).   */
template<int K, int Nd, int NW, int TOKB, int CSPLIT, bool RELU, bool LN>
__global__ __launch_bounds__(512) void k_gemm7(
    const bf* __restrict__ X, const ushort* __restrict__ Wg,
    const float* __restrict__ bi0, const float* __restrict__ bi1,
    const float* __restrict__ bi2, const bf* __restrict__ Res,
    const float* __restrict__ g, const float* __restrict__ bb,
    bf* __restrict__ Y0, bf* __restrict__ Y1, bf* __restrict__ Y2) {
  constexpr int NJ   = (Nd + 15) / 16;
  constexpr int NdP  = NJ * 16;
  constexpr int KC   = (K + 31) / 32;
  constexpr int G    = NW * CSPLIT;
  constexpr int S    = KC * G;
  constexpr int IR   = NdP / CSPLIT;
  constexpr int SUB_USH = IR * 40;
  constexpr int SUBCB   = SUB_USH * 2;
  constexpr int NJW  = IR / 32;
  constexpr int MR   = TOKB / 64;
  constexpr bool GLX = (K == 152);
  constexpr int XSTR = GLX ? K : (K + 8);
  __shared__ __align__(16) ushort Xs[TOKB * XSTR + 8];
  __shared__ __align__(16) ushort Wb[2 * SUB_USH];
  long row0 = (long)blockIdx.x * TOKB;
  int tid = threadIdx.x;
  int lane = tid & 63, w = tid >> 6;
  int cl = lane & 15, gr = lane >> 4;
  int wr = w >> 1, wc = w & 1;
  if constexpr (GLX) {
    constexpr int TBX = TOKB * K * 2 / 1024;
    const char* Xgc = (const char*)(X + row0 * K);
#pragma unroll
    for (int b0 = 0; b0 < TBX; b0 += 8) {
      int blk = b0 + w;
      if (blk < TBX)
        gl_lds16(Xgc + blk*1024 + (size_t)lane*16, (char*)Xs + blk*1024);
    }
  } else {
    const char* Xgc = (const char*)(X + row0 * K);
    for (int i = tid; i < TOKB*(K/8); i += 512) {
      int r = i / (K/8), c = i % (K/8);
      *(short8*)&Xs[r*XSTR + 8*c] = *(const short8*)(Xgc + r*(K*2) + c*16);
    }
    __syncthreads();
  }
  const char* gW = (const char*)Wg;
  issue_w8<SUBCB>(gW, Wb, w, lane);
  const int nw = issue_cnt<SUBCB>(w);
  float4v acc[G][MR][NJW];
#pragma unroll
  for (int gi = 0; gi < G; ++gi)
#pragma unroll
    for (int mi = 0; mi < MR; ++mi)
#pragma unroll
      for (int j = 0; j < NJW; ++j) acc[gi][mi][j] = (float4v){0.f,0.f,0.f,0.f};
#pragma unroll
  for (int s = 0; s < S; ++s) {
    if (s + 1 < S) {
      issue_w8<SUBCB>(gW + (size_t)(s+1)*SUBCB, Wb + ((s+1)&1)*SUB_USH, w, lane);
      vm_wait(nw);
    } else {
      asm volatile("s_waitcnt vmcnt(0)" ::: "memory");
    }
    __builtin_amdgcn_s_barrier();
    int kc = (s / G) * 32;
    const ushort* wb = Wb + (s&1)*SUB_USH;
    short8 af[MR];
#pragma unroll
    for (int mi = 0; mi < MR; ++mi)
      af[mi] = *(const short8*)&Xs[((TOKB/4)*wr + 16*mi + cl)*XSTR + kc + 8*gr];
#pragma unroll
    for (int j = 0; j < NJW; ++j) {
      short8 bv = *(const short8*)&wb[((IR/2)*wc + 16*j + cl)*40 + 8*gr];
#pragma unroll
      for (int mi = 0; mi < MR; ++mi)
        acc[s % G][mi][j] =
            __builtin_amdgcn_mfma_f32_16x16x32_bf16(af[mi], bv, acc[s % G][mi][j], 0, 0, 0);
    }
    asm volatile("s_waitcnt lgkmcnt(0)" ::: "memory");
    __builtin_amdgcn_s_barrier();
  }
  if constexpr (!LN) {
#pragma unroll
    for (int gi = 0; gi < G; ++gi) {
      bf* Y = (NW > 1) ? (gi == 0 ? Y0 : (gi == 1 ? Y1 : Y2)) : Y0;
      const float* bp = (NW > 1) ? (gi == 0 ? bi0 : (gi == 1 ? bi1 : bi2)) : bi0;
      int colb = (CSPLIT > 1 ? IR*gi : 0) + (IR/2)*wc;
#pragma unroll
      for (int j = 0; j < NJW; ++j) {
        int col = colb + 16*j + cl;
        if (col < Nd) {
          float bvs = bp[col];
#pragma unroll
          for (int mi = 0; mi < MR; ++mi) {
            long rw = row0 + (TOKB/4)*wr + 16*mi + 4*gr;
#pragma unroll
            for (int r = 0; r < 4; ++r) {
              float val = acc[gi][mi][j][r] + bvs;
              if (RELU) val = fmaxf(val, 0.f);
              Y[(rw + r) * Nd + col] = f2bf(val);
            }
          }
        }
      }
    }
  } else {
    float* LNb = (float*)Wb;
    int colb = (IR/2)*wc;
#pragma unroll
    for (int j = 0; j < NJW; ++j) {
      int col = colb + 16*j + cl;
      if (col < Nd) {
        float bvs = bi0[col];
#pragma unroll
        for (int mi = 0; mi < MR; ++mi) {
          long rw = row0 + (TOKB/4)*wr + 16*mi + 4*gr;
#pragma unroll
          for (int r = 0; r < 4; ++r)
            acc[0][mi][j][r] += bvs + bf2f(Res[(rw + r) * Nd + col]);
        }
      }
    }
    float mean[MR][4], rs[MR][4];
#pragma unroll
    for (int mi = 0; mi < MR; ++mi)
#pragma unroll
      for (int r = 0; r < 4; ++r) {
        float s = 0.f;
#pragma unroll
        for (int j = 0; j < NJW; ++j) s += acc[0][mi][j][r];
        s += __shfl_xor(s, 1, 64); s += __shfl_xor(s, 2, 64);
        s += __shfl_xor(s, 4, 64); s += __shfl_xor(s, 8, 64);
        if (cl == 0) LNb[((wr*MR + mi)*2 + wc)*16 + 4*gr + r] = s;
      }
    __syncthreads();
#pragma unroll
    for (int mi = 0; mi < MR; ++mi)
#pragma unroll
      for (int r = 0; r < 4; ++r) {
        float tot = LNb[((wr*MR + mi)*2 + 0)*16 + 4*gr + r]
                  + LNb[((wr*MR + mi)*2 + 1)*16 + 4*gr + r];
        mean[mi][r] = tot * (1.f / (float)Nd);
      }
#pragma unroll
    for (int mi = 0; mi < MR; ++mi)
#pragma unroll
      for (int r = 0; r < 4; ++r) {
        float s2 = 0.f;
#pragma unroll
        for (int j = 0; j < NJW; ++j) {
          int col = colb + 16*j + cl;
          if (col < Nd) {
            float dv = acc[0][mi][j][r] - mean[mi][r];
            s2 += dv*dv;
          }
        }
        s2 += __shfl_xor(s2, 1, 64); s2 += __shfl_xor(s2, 2, 64);
        s2 += __shfl_xor(s2, 4, 64); s2 += __shfl_xor(s2, 8, 64);
        if (cl == 0) LNb[256 + ((wr*MR + mi)*2 + wc)*16 + 4*gr + r] = s2;
      }
    __syncthreads();
#pragma unroll
    for (int mi = 0; mi < MR; ++mi)
#pragma unroll
      for (int r = 0; r < 4; ++r) {
        float tot2 = LNb[256 + ((wr*MR + mi)*2 + 0)*16 + 4*gr + r]
                   + LNb[256 + ((wr*MR + mi)*2 + 1)*16 + 4*gr + r];
        rs[mi][r] = rsqrtf(tot2 * (1.f / (float)Nd) + 1e-5f);
      }
#pragma unroll
    for (int j = 0; j < NJW; ++j) {
      int col = colb + 16*j + cl;
      if (col < Nd) {
        float gv = g[col], bv2 = bb[col];
#pragma unroll
        for (int mi = 0; mi < MR; ++mi) {
          long rw = row0 + (TOKB/4)*wr + 16*mi + 4*gr;
#pragma unroll
          for (int r = 0; r < 4; ++r)
            Y0[(rw + r) * Nd + col] =
                f2bf((acc[0][mi][j][r] - mean[mi][r]) * rs[mi][r] * gv + bv2);
        }
      }
    }
  }
}

/* ------------------------------------------------------------------ */
/* k_layer3: fused Wo-GEMM + LN1 + FF1 + ReLU + FF2 + LN2 for 64 toks.
   ALL synchronization = __syncthreads() (the round-5/6 k_ffn proven
   primitive: per-wave vmcnt+lgkmcnt drain at each barrier, so the
   single-barrier-per-step double-buffer is race-free by construction).
   h1 (LN1 output) never touches global: bf16 into the A-tile LDS slot
   (dead) for FF1's A-frags + a packed bf16 register copy for the LN2
   residual (bit-identical to the old global round-trip).
   Arena (58880 B): P1 Xs[64][152]@0 | W0b 2x6400@9728 | LNb1@22528
                    P2 Hs1=Xs@0      | W1b 2x5120@9728
                    P3 Hs2[64][260]@0| W2b 2x6400@16640                */
__global__ __launch_bounds__(512) void k_layer3(
    const bf* __restrict__ A, const bf* __restrict__ Xres,
    const ushort* __restrict__ Wog, const ushort* __restrict__ W1g,
    const ushort* __restrict__ W2g,
    const float* __restrict__ bo, const float* __restrict__ b1,
    const float* __restrict__ b2,
    const float* __restrict__ g1v, const float* __restrict__ be1,
    const float* __restrict__ g2v, const float* __restrict__ be2,
    bf* __restrict__ Y) {
  constexpr int S0 = 5,  SUB0 = 6400;
  constexpr int S1 = 10, SUB1 = 5120;
  constexpr int S2 = 8,  SUB2 = 6400;
  constexpr int HSTR = 260;
  __shared__ __align__(16) ushort S_[29440];
  ushort* Xs  = S_;
  ushort* W0b = S_ + 9728;
  ushort* W1b = S_ + 9728;
  ushort* Hs2 = S_;
  ushort* W2b = S_ + 16640;
  float*  LNb1 = (float*)(S_ + 22528);
  long row0 = (long)blockIdx.x * 64;
  int tid = threadIdx.x, lane = tid & 63, w = tid >> 6;
  int cl = lane & 15, gr = lane >> 4;
  int wr = w >> 1, wc = w & 1;
  int colb = 80*wc;
  /* ---- P1: stage A-tile + Wo chunk0; single-barrier dbuf loop ---- */
  {
    const char* Agc = (const char*)(A + row0 * 152);
#pragma unroll
    for (int b0 = 0; b0 < 19; b0 += 8) {
      int blk = b0 + w;
      if (blk < 19)
        gl_lds16(Agc + blk*1024 + (size_t)lane*16, (char*)Xs + blk*1024);
    }
  }
  issue_w8<SUB0*2>((const char*)Wog, W0b, w, lane);
  __syncthreads();                 /* A + Wo chunk0 resident */
  float4v acc0[5];
#pragma unroll
  for (int j = 0; j < 5; ++j) acc0[j] = (float4v){0.f,0.f,0.f,0.f};
#pragma unroll
  for (int s = 0; s < S0; ++s) {
    if (s + 1 < S0)
      issue_w8<SUB0*2>((const char*)Wog + (size_t)(s+1)*SUB0*2,
                       W0b + ((s+1)&1)*SUB0, w, lane);
    int kc = s * 32;
    const ushort* wb = W0b + (s&1)*SUB0;
    short8 af = *(const short8*)&Xs[(16*wr + cl)*152 + kc + 8*gr];
#pragma unroll
    for (int j = 0; j < 5; ++j) {
      short8 bv = *(const short8*)&wb[(80*wc + 16*j + cl)*40 + 8*gr];
      acc0[j] =
          __builtin_amdgcn_mfma_f32_16x16x32_bf16(af, bv, acc0[j], 0, 0, 0);
    }
    __syncthreads();               /* reads done; chunk s+1 DMA complete */
  }
  /* ---- LN1: residual(x) + layernorm; h1 -> Xs(bf16) + reg copy ---- */
#pragma unroll
  for (int j = 0; j < 5; ++j) {
    int col = colb + 16*j + cl;
    if (col < D_) {
      float bvs = bo[col];
#pragma unroll
      for (int r = 0; r < 4; ++r)
        acc0[j][r] += bvs + bf2f(Xres[(row0 + 16*wr + 4*gr + r) * D_ + col]);
    }
  }
  float mean1[4], rsv1[4];
#pragma unroll
  for (int r = 0; r < 4; ++r) {
    float s = 0.f;
#pragma unroll
    for (int j = 0; j < 5; ++j)
      if (colb + 16*j + cl < D_) s += acc0[j][r];
    s += __shfl_xor(s, 1, 64); s += __shfl_xor(s, 2, 64);
    s += __shfl_xor(s, 4, 64); s += __shfl_xor(s, 8, 64);
    if (cl == 0) LNb1[(wr*2 + wc)*16 + 4*gr + r] = s;
  }
  __syncthreads();
#pragma unroll
  for (int r = 0; r < 4; ++r) {
    float tot = LNb1[(wr*2 + 0)*16 + 4*gr + r] + LNb1[(wr*2 + 1)*16 + 4*gr + r];
    mean1[r] = tot * (1.f / (float)D_);
  }
#pragma unroll
  for (int r = 0; r < 4; ++r) {
    float s2 = 0.f;
#pragma unroll
    for (int j = 0; j < 5; ++j) {
      int col = colb + 16*j + cl;
      if (col < D_) { float dv = acc0[j][r] - mean1[r]; s2 += dv*dv; }
    }
    s2 += __shfl_xor(s2, 1, 64); s2 += __shfl_xor(s2, 2, 64);
    s2 += __shfl_xor(s2, 4, 64); s2 += __shfl_xor(s2, 8, 64);
    if (cl == 0) LNb1[128 + (wr*2 + wc)*16 + 4*gr + r] = s2;
  }
  __syncthreads();
#pragma unroll
  for (int r = 0; r < 4; ++r) {
    float tot2 = LNb1[128 + (wr*2 + 0)*16 + 4*gr + r]
               + LNb1[128 + (wr*2 + 1)*16 + 4*gr + r];
    rsv1[r] = rsqrtf(tot2 * (1.f / (float)D_) + 1e-5f);
  }
  unsigned hres[5][2];     /* bf16 h1 packed: bit-exact LN2 residual */
#pragma unroll
  for (int j = 0; j < 5; ++j) {
    int col = colb + 16*j + cl;
    if (col < D_) {
      float gv = g1v[col], bv2 = be1[col];
      ushort u[4];
#pragma unroll
      for (int r = 0; r < 4; ++r) {
        u[r] = f2bf_u((acc0[j][r] - mean1[r]) * rsv1[r] * gv + bv2);
        Xs[(16*wr + 4*gr + r)*152 + col] = u[r];   /* Hs1 (A dead) */
      }
      hres[j][0] = (unsigned)u[0] | ((unsigned)u[1] << 16);
      hres[j][1] = (unsigned)u[2] | ((unsigned)u[3] << 16);
    } else {
      hres[j][0] = 0u; hres[j][1] = 0u;
    }
  }
  issue_w8<SUB1*2>((const char*)W1g, W1b, w, lane);
  __syncthreads();            /* Hs1 visible + W1 chunk0 resident */
  /* ---- P2: FF1 (round-6 k_ffn loop, A from Hs1) ---- */
  float4v acc1[2][4];
#pragma unroll
  for (int g2 = 0; g2 < 2; ++g2)
#pragma unroll
    for (int j = 0; j < 4; ++j) acc1[g2][j] = (float4v){0.f,0.f,0.f,0.f};
#pragma unroll
  for (int s = 0; s < S1; ++s) {
    if (s + 1 < S1)
      issue_w8<SUB1*2>((const char*)W1g + (size_t)(s+1)*SUB1*2,
                       W1b + ((s+1)&1)*SUB1, w, lane);
    int kc = (s / 2) * 32;
    const ushort* wb = W1b + (s&1)*SUB1;
    short8 af = *(const short8*)&Xs[(16*wr + cl)*152 + kc + 8*gr];
#pragma unroll
    for (int j = 0; j < 4; ++j) {
      short8 bv = *(const short8*)&wb[(64*wc + 16*j + cl)*40 + 8*gr];
      acc1[s&1][j] =
          __builtin_amdgcn_mfma_f32_16x16x32_bf16(af, bv, acc1[s&1][j], 0, 0, 0);
    }
    __syncthreads();
  }
  /* h2 = relu(acc1+b1) -> Hs2 (overwrites Hs1/W1b: dead) */
#pragma unroll
  for (int g2 = 0; g2 < 2; ++g2)
#pragma unroll
    for (int j = 0; j < 4; ++j) {
      int col = g2*128 + 64*wc + 16*j + cl;
      float bvs = b1[col];
#pragma unroll
      for (int r = 0; r < 4; ++r) {
        int row = 16*wr + 4*gr + r;
        Hs2[row*HSTR + col] = f2bf_u(fmaxf(acc1[g2][j][r] + bvs, 0.f));
      }
    }
  issue_w8<SUB2*2>((const char*)W2g, W2b, w, lane);
  __syncthreads();            /* Hs2 visible + W2 chunk0 resident */
  /* ---- P3: FF2 (round-6 k_ffn loop) ---- */
  float4v acc2[5];
#pragma unroll
  for (int j = 0; j < 5; ++j) acc2[j] = (float4v){0.f,0.f,0.f,0.f};
#pragma unroll
  for (int s = 0; s < S2; ++s) {
    if (s + 1 < S2)
      issue_w8<SUB2*2>((const char*)W2g + (size_t)(s+1)*SUB2*2,
                       W2b + ((s+1)&1)*SUB2, w, lane);
    int kc = s * 32;
    const ushort* wb = W2b + (s&1)*SUB2;
    short8 af = *(const short8*)&Hs2[(16*wr + cl)*HSTR + kc + 8*gr];
#pragma unroll
    for (int j = 0; j < 5; ++j) {
      short8 bv = *(const short8*)&wb[(80*wc + 16*j + cl)*40 + 8*gr];
      acc2[j] =
          __builtin_amdgcn_mfma_f32_16x16x32_bf16(af, bv, acc2[j], 0, 0, 0);
    }
    __syncthreads();
  }
  /* residual(h1 from regs) + LN2 epilogue */
  float* LNb = (float*)W2b;
#pragma unroll
  for (int j = 0; j < 5; ++j) {
    int col = colb + 16*j + cl;
    if (col < D_) {
      float bvs = b2[col];
#pragma unroll
      for (int r = 0; r < 4; ++r)
        acc2[j][r] += bvs + ((r & 1) ? hi_bf(hres[j][r>>1]) : lo_bf(hres[j][r>>1]));
    }
  }
  float mean[4], rsv[4];
#pragma unroll
  for (int r = 0; r < 4; ++r) {
    float s = 0.f;
#pragma unroll
    for (int j = 0; j < 5; ++j)
      if (colb + 16*j + cl < D_) s += acc2[j][r];
    s += __shfl_xor(s, 1, 64); s += __shfl_xor(s, 2, 64);
    s += __shfl_xor(s, 4, 64); s += __shfl_xor(s, 8, 64);
    if (cl == 0) LNb[(wr*2 + wc)*16 + 4*gr + r] = s;
  }
  __syncthreads();
#pragma unroll
  for (int r = 0; r < 4; ++r) {
    float tot = LNb[(wr*2 + 0)*16 + 4*gr + r] + LNb[(wr*2 + 1)*16 + 4*gr + r];
    mean[r] = tot * (1.f / (float)D_);
  }
#pragma unroll
  for (int r = 0; r < 4; ++r) {
    float s2 = 0.f;
#pragma unroll
    for (int j = 0; j < 5; ++j) {
      int col = colb + 16*j + cl;
      if (col < D_) { float dv = acc2[j][r] - mean[r]; s2 += dv*dv; }
    }
    s2 += __shfl_xor(s2, 1, 64); s2 += __shfl_xor(s2, 2, 64);
    s2 += __shfl_xor(s2, 4, 64); s2 += __shfl_xor(s2, 8, 64);
    if (cl == 0) LNb[128 + (wr*2 + wc)*16 + 4*gr + r] = s2;
  }
  __syncthreads();
#pragma unroll
  for (int r = 0; r < 4; ++r) {
    float tot2 = LNb[128 + (wr*2 + 0)*16 + 4*gr + r]
               + LNb[128 + (wr*2 + 1)*16 + 4*gr + r];
    rsv[r] = rsqrtf(tot2 * (1.f / (float)D_) + 1e-5f);
  }
#pragma unroll
  for (int j = 0; j < 5; ++j) {
    int col = colb + 16*j + cl;
    if (col < D_) {
      float gv = g2v[col], bv2 = be2[col];
#pragma unroll
      for (int r = 0; r < 4; ++r)
        Y[(row0 + 16*wr + 4*gr + r) * D_ + col] =
            f2bf((acc2[j][r] - mean[r]) * rsv[r] * gv + bv2);
    }
  }
}

/* ------------------------------------------------------------------ */
/* Temporal attention v2 (round-5 proven): MFMA swapped-operand.      */
__global__ __launch_bounds__(256) void k_attn_t2(
    const ushort* __restrict__ qg, const ushort* __restrict__ kg,
    const ushort* __restrict__ vg, bf* __restrict__ a) {
  int id = blockIdx.x; int b = id / N_; int n = id % N_;
  __shared__ ushort Ksh[4][16][40];
  __shared__ ushort Qsh[4][16][40];
  __shared__ ushort Vth[4][40][16];
  int tid = threadIdx.x;
  for (int i = tid; i < 1280; i += 256) {
    ((unsigned*)Ksh)[i] = 0u; ((unsigned*)Qsh)[i] = 0u; ((unsigned*)Vth)[i] = 0u;
  }
  __syncthreads();
  for (int i = tid; i < 4*12*19; i += 256) {
    int h = i / 228, r = i % 228, l = r / 19, t2 = r % 19;
    long off = ((long)(b*L_ + l) * N_ + n) * D_ + h*HD_ + 2*t2;
    *(unsigned*)&Ksh[h][l][2*t2] = *(const unsigned*)(kg + off);
    *(unsigned*)&Qsh[h][l][2*t2] = *(const unsigned*)(qg + off);
  }
  for (int i = tid; i < 4*12*19; i += 256) {
    int h = i / 228, r = i % 228, l = r / 19, t2 = r % 19;
    long off = ((long)(b*L_ + l) * N_ + n) * D_ + h*HD_ + 2*t2;
    unsigned u = *(const unsigned*)(vg + off);
    Vth[h][2*t2][l]     = (ushort)(u & 0xffffu);
    Vth[h][2*t2 + 1][l] = (ushort)(u >> 16);
  }
  __syncthreads();
  int lane = tid & 63, w = tid >> 6;
  int cl = lane & 15, gr = lane >> 4;
  const short8 z8 = {0,0,0,0,0,0,0,0};
  short8 a00 = *(const short8*)&Ksh[w][cl][8*gr];
  short8 qB0 = *(const short8*)&Qsh[w][cl][8*gr];
  short8 a01 = (gr == 0) ? *(const short8*)&Ksh[w][cl][32] : z8;
  short8 qB1 = (gr == 0) ? *(const short8*)&Qsh[w][cl][32] : z8;
  float4v sa = (float4v){0,0,0,0};
  sa = __builtin_amdgcn_mfma_f32_16x16x32_bf16(a00, qB0, sa, 0, 0, 0);
  sa = __builtin_amdgcn_mfma_f32_16x16x32_bf16(a01, qB1, sa, 0, 0, 0);
  float p[4];
#pragma unroll
  for (int r = 0; r < 4; ++r) {
    float xv = (4*gr + r < 12) ? sa[r]*C2_ : -1e30f;
    p[r] = __builtin_exp2f(fminf(xv, 80.f));
  }
  float sum_ = (p[0] + p[1]) + (p[2] + p[3]);
  sum_ += __shfl_xor(sum_, 16, 64);
  sum_ += __shfl_xor(sum_, 32, 64);
  unsigned u0 = pk_bf(p[0], p[1]);
  unsigned u1 = pk_bf(p[2], p[3]);
  int srcA = cl + 32*(gr & 1);
  int srcB = srcA + 16;
  unsigned w0 = __shfl(u0, srcA, 64), w1 = __shfl(u1, srcA, 64);
  unsigned w2 = __shfl(u0, srcB, 64), w3 = __shfl(u1, srcB, 64);
  union { unsigned u[4]; short8 v; } pbu;
  bool gv = gr < 2;
  pbu.u[0] = gv ? w0 : 0u; pbu.u[1] = gv ? w1 : 0u;
  pbu.u[2] = gv ? w2 : 0u; pbu.u[3] = gv ? w3 : 0u;
  short8 pB = pbu.v;
  float4v accO[3];
#pragma unroll
  for (int dt = 0; dt < 3; ++dt) {
    short8 aV = (gv && (dt < 2 || cl < 8))
        ? *(const short8*)&Vth[w][16*dt + cl][8*gr] : z8;
    accO[dt] = (float4v){0,0,0,0};
    accO[dt] = __builtin_amdgcn_mfma_f32_16x16x32_bf16(aV, pB, accO[dt], 0, 0, 0);
  }
  if (cl < 12) {
    float inv = 1.f / sum_;
    bf* ap = a + ((long)(b*L_ + cl) * N_ + n) * D_ + w*HD_;
#pragma unroll
    for (int dt = 0; dt < 2; ++dt) {
      *(unsigned*)(ap + 16*dt + 4*gr)     = pk_bf(accO[dt][0]*inv, accO[dt][1]*inv);
      *(unsigned*)(ap + 16*dt + 4*gr + 2) = pk_bf(accO[dt][2]*inv, accO[dt][3]*inv);
    }
    if (gr == 0) {
      *(unsigned*)(ap + 32) = pk_bf(accO[2][0]*inv, accO[2][1]*inv);
      *(unsigned*)(ap + 34) = pk_bf(accO[2][2]*inv, accO[2][3]*inv);
    } else if (gr == 1) {
      *(unsigned*)(ap + 36) = pk_bf(accO[2][0]*inv, accO[2][1]*inv);
    }
  }
}

/* ------------------------------------------------------------------ */
/* Spatial attention v6b (round-9 proven): one (b,l,h) unit per block. */
__global__ __launch_bounds__(512) void k_attn_s6(
    const ushort* __restrict__ qg, const ushort* __restrict__ kg,
    const ushort* __restrict__ vg, bf* __restrict__ a) {
  __shared__ ushort Ks[360][40];
  __shared__ ushort Vt[38][392];
  int tid = threadIdx.x;
  int lane = tid & 63, w = tid >> 6;
  int cl = lane & 15, gr = lane >> 4;
  bool g0 = (gr == 0);
  const short8 z8 = {0,0,0,0,0,0,0,0};

  int id = blockIdx.x;
  int h = id & 3; int s = id >> 2;
  int b = s / L_; int l = s % L_;
  long base = (long)(b*L_ + l) * N_;
  for (int i = tid; i < 360*20; i += 512) {
    int j = i / 20, t2 = i % 20;
    unsigned u = 0u;
    if (j < N_ && t2 < 19)
      u = *(const unsigned*)(kg + (base + j)*D_ + h*HD_ + 2*t2);
    *(unsigned*)&Ks[j][2*t2] = u;
  }
  for (int i = tid; i < N_*19; i += 512) {
    int j = i / 19, t2 = i % 19;
    unsigned u = *(const unsigned*)(vg + (base + j)*D_ + h*HD_ + 2*t2);
    Vt[2*t2][j]     = (ushort)(u & 0xffffu);
    Vt[2*t2 + 1][j] = (ushort)(u >> 16);
  }
  for (int i = tid; i < 38*26; i += 512)
    Vt[i / 26][N_ + i % 26] = 0;
  __syncthreads();

  for (int qt = w; qt < 23; qt += 8) {
    const ushort* qp = qg + (base + 16*qt + cl) * D_ + h*HD_;
    short8 qB0 = ld_g8(qp + 8*gr);
    short8 qB1 = ld_g8(qp + 32 + 8*gr);
    float sum_ = 0.f;
    float4v accO[3];
    accO[0] = (float4v){0,0,0,0};
    accO[1] = (float4v){0,0,0,0};
    accO[2] = (float4v){0,0,0,0};
#pragma unroll 1
    for (int pr = 0; pr < 11; ++pr) {
      int k0 = 32*pr;
      int kr0 = k0 + cl;
      int kr1 = k0 + 16 + cl;
      float4v s0a = (float4v){0,0,0,0}, s1a = (float4v){0,0,0,0};
      {
        short8 a00 = *(const short8*)&Ks[kr0][8*gr];
        short8 a10 = *(const short8*)&Ks[kr1][8*gr];
        __builtin_amdgcn_s_setprio(1);
        s0a = __builtin_amdgcn_mfma_f32_16x16x32_bf16(a00, qB0, s0a, 0, 0, 0);
        s1a = __builtin_amdgcn_mfma_f32_16x16x32_bf16(a10, qB0, s1a, 0, 0, 0);
        short8 a01 = g0 ? *(const short8*)&Ks[kr0][32] : z8;
        short8 a11 = g0 ? *(const short8*)&Ks[kr1][32] : z8;
        s0a = __builtin_amdgcn_mfma_f32_16x16x32_bf16(a01, qB1, s0a, 0, 0, 0);
        s1a = __builtin_amdgcn_mfma_f32_16x16x32_bf16(a11, qB1, s1a, 0, 0, 0);
        __builtin_amdgcn_s_setprio(0);
      }
      float p0[4], p1[4];
#pragma unroll
      for (int r = 0; r < 4; ++r) {
        p0[r] = __builtin_exp2f(fminf(s0a[r]*C2_, 80.f));
        p1[r] = __builtin_exp2f(fminf(s1a[r]*C2_, 80.f));
      }
      sum_ += (p0[0] + p0[1]) + (p0[2] + p0[3])
            + (p1[0] + p1[1]) + (p1[2] + p1[3]);
      unsigned u0 = pk_bf(p0[0], p0[1]);
      unsigned u1 = pk_bf(p0[2], p0[3]);
      unsigned u2 = pk_bf(p1[0], p1[1]);
      unsigned u3 = pk_bf(p1[2], p1[3]);
      int srcA = cl + 16*((2*gr) & 3);
      int srcB = srcA + 16;
      unsigned a0 = __shfl(u0, srcA, 64), b0 = __shfl(u1, srcA, 64);
      unsigned c0 = __shfl(u0, srcB, 64), d0 = __shfl(u1, srcB, 64);
      unsigned a2 = __shfl(u2, srcA, 64), b2 = __shfl(u3, srcA, 64);
      unsigned c2 = __shfl(u2, srcB, 64), d2 = __shfl(u3, srcB, 64);
      bool lo = gr < 2;
      union { unsigned u[4]; short8 v; } pbu;
      pbu.u[0] = lo ? a0 : a2;
      pbu.u[1] = lo ? b0 : b2;
      pbu.u[2] = lo ? c0 : c2;
      pbu.u[3] = lo ? d0 : d2;
      short8 pB = pbu.v;
      __builtin_amdgcn_s_setprio(1);
#pragma unroll
      for (int dt = 0; dt < 3; ++dt) {
        short8 aV = (dt < 2 || cl < 6)
            ? *(const short8*)&Vt[16*dt + cl][k0 + 8*gr] : z8;
        accO[dt] = __builtin_amdgcn_mfma_f32_16x16x32_bf16(aV, pB, accO[dt], 0, 0, 0);
      }
      __builtin_amdgcn_s_setprio(0);
    }
    { /* tail tile: keys 352..357 */
      int k0 = 352;
      int kr0 = k0 + cl; if (kr0 > 359) kr0 = 359;
      float4v s0a = (float4v){0,0,0,0};
      {
        short8 a00 = *(const short8*)&Ks[kr0][8*gr];
        s0a = __builtin_amdgcn_mfma_f32_16x16x32_bf16(a00, qB0, s0a, 0, 0, 0);
        short8 a01 = g0 ? *(const short8*)&Ks[kr0][32] : z8;
        s0a = __builtin_amdgcn_mfma_f32_16x16x32_bf16(a01, qB1, s0a, 0, 0, 0);
      }
      float p0[4];
#pragma unroll
      for (int r = 0; r < 4; ++r) {
        float xv = (4*gr + r < 6) ? s0a[r]*C2_ : -1e30f;
        p0[r] = __builtin_exp2f(fminf(xv, 80.f));
      }
      sum_ += (p0[0] + p0[1]) + (p0[2] + p0[3]);
      unsigned u0 = pk_bf(p0[0], p0[1]);
      unsigned u1 = pk_bf(p0[2], p0[3]);
      int srcA = cl + 16*((2*gr) & 3);
      int srcB = srcA + 16;
      unsigned a0 = __shfl(u0, srcA, 64), b0 = __shfl(u1, srcA, 64);
      unsigned c0 = __shfl(u0, srcB, 64), d0 = __shfl(u1, srcB, 64);
      bool lo = gr < 2;
      union { unsigned u[4]; short8 v; } pbu;
      pbu.u[0] = lo ? a0 : 0u;
      pbu.u[1] = lo ? b0 : 0u;
      pbu.u[2] = lo ? c0 : 0u;
      pbu.u[3] = lo ? d0 : 0u;
      short8 pB = pbu.v;
#pragma unroll
      for (int dt = 0; dt < 3; ++dt) {
        short8 aV = (dt < 2 || cl < 6)
            ? *(const short8*)&Vt[16*dt + cl][k0 + 8*gr] : z8;
        accO[dt] = __builtin_amdgcn_mfma_f32_16x16x32_bf16(aV, pB, accO[dt], 0, 0, 0);
      }
    }
    sum_ += __shfl_xor(sum_, 16, 64);
    sum_ += __shfl_xor(sum_, 32, 64);
    int qi = 16*qt + cl;
    if (qi < N_) {
      float inv = 1.f / sum_;
      bf* ap = a + (base + qi)*D_ + h*HD_;
#pragma unroll
      for (int dt = 0; dt < 2; ++dt) {
        *(unsigned*)(ap + 16*dt + 4*gr)     = pk_bf(accO[dt][0]*inv, accO[dt][1]*inv);
        *(unsigned*)(ap + 16*dt + 4*gr + 2) = pk_bf(accO[dt][2]*inv, accO[dt][3]*inv);
      }
      if (gr == 0) {
        *(unsigned*)(ap + 32) = pk_bf(accO[2][0]*inv, accO[2][1]*inv);
        *(unsigned*)(ap + 34) = pk_bf(accO[2][2]*inv, accO[2][3]*inv);
      } else if (gr == 1) {
        *(unsigned*)(ap + 36) = pk_bf(accO[2][0]*inv, accO[2][1]*inv);
      }
    }
  }
}

/* ------------------------------------------------------------------ */
__global__ __launch_bounds__(256) void k_evtpool(
    const float* __restrict__ marker, const void* __restrict__ doy_mask,
    const float* __restrict__ evt_h, float* __restrict__ evtp) {
  __shared__ int hasF32, hasBig;
  if (threadIdx.x == 0) { hasF32 = 0; hasBig = 0; }
  __syncthreads();
  const unsigned* mw = (const unsigned*)doy_mask;
  for (int w = threadIdx.x; w < 732; w += 256) {
    unsigned u = mw[w];
    if (u == 0x3F800000u) hasF32 = 1;
    else if (u > 1u) hasBig = 1;
  }
  __syncthreads();
  int fmt = hasF32 ? 2 : (hasBig ? 1 : 0);
  int b = blockIdx.x;
  float m3 = marker[((b*L_ + (L_-1))*N_ + 0)*4 + 3];
  int doy = (int)(m3 * 365.f); doy = doy < 0 ? 0 : (doy > 365 ? 365 : doy);
  int j = threadIdx.x;
  float mx = -1e30f;
  for (int kx = 0; kx < 8; ++kx) {
    bool mk;
    if (fmt == 2)      mk = ((const float*)doy_mask)[doy*8 + kx] != 0.f;
    else if (fmt == 1) mk = ((const unsigned char*)doy_mask)[doy*8 + kx] != 0;
    else               mk = ((const int*)doy_mask)[doy*8 + kx] != 0;
    if (mk) mx = fmaxf(mx, evt_h[(b*8 + kx)*256 + j]);
  }
  evtp[b*256 + j] = mx;
}

/* ------------------------------------------------------------------ */
__global__ __launch_bounds__(192) void k_final3(
    const bf* __restrict__ x, const float* __restrict__ wcomb,
    const float* __restrict__ wevtsum, const float* __restrict__ evtp,
    const float* __restrict__ b_mm, const float* __restrict__ b_ts,
    float* __restrict__ out) {
  int id = blockIdx.x; int b = id / N_; int n = id % N_;
  __shared__ float xs[1824];
  __shared__ float part[16][12];
  int tid = threadIdx.x;
  for (int e = tid; e < 912; e += 192) {
    int l = e / 76, du = e % 76;
    unsigned u = *(const unsigned*)((const ushort*)x +
        (((long)(b*L_ + l) * N_ + n) * 152 + 2*du));
    xs[l*152 + 2*du]     = lo_bf(u);
    xs[l*152 + 2*du + 1] = hi_bf(u);
  }
  __syncthreads();
  int g2 = tid / 12, p = tid % 12;
  float acc = 0.f;
  for (int e = g2; e < 1824; e += 16)
    acc += xs[e] * wcomb[e*12 + p];
  part[g2][p] = acc;
  __syncthreads();
  if (tid < 12) {
    float s = b_mm[tid] + b_ts[tid];
    for (int e = 0; e < 256; ++e) s += evtp[b*256 + e] * wevtsum[e*12 + tid];
    for (int gg = 0; gg < 16; ++gg) s += part[gg][tid];
    out[(b*12 + tid) * N_ + n] = s;
  }
}

/* ------------------------------------------------------------------ */
extern "C" void kernel_launch(void* const* d_in, const int* in_sizes, int n_in,
                              void* d_out, int out_size, void* d_ws, size_t ws_size,
                              hipStream_t stream) {
  static const int expect[32] = {
    68736, 274944, 72, 24, 3456, 168, 343680,
    138624, 912, 138624, 912, 138624, 912, 138624, 912,
    233472, 1536, 233472, 912,
    912, 912, 912, 912,
    4195328, 262144, 256,
    58752, 12, 21888, 12,
    2928, 2928 };
  int nb = (out_size + 255)/256;
  if (n_in != 32) {
    k_beacon<<<nb, 256, 0, stream>>>((float*)d_out, out_size, 998.f);
    return;
  }
  for (int i = 0; i < 32; ++i) {
    if (in_sizes[i] != expect[i]) {
      k_beacon<<<nb, 256, 0, stream>>>((float*)d_out, out_size, 1000.f + i);
      return;
    }
  }
  if (out_size != 68736) {
    k_beacon<<<nb, 256, 0, stream>>>((float*)d_out, out_size, 997.f);
    return;
  }

  const float* var_x  = (const float*)d_in[0];
  const float* marker = (const float*)d_in[1];
  const float* W_in   = (const float*)d_in[2];
  const float* b_in   = (const float*)d_in[3];
  const float* tod    = (const float*)d_in[4];
  const float* dow    = (const float*)d_in[5];
  const float* adap   = (const float*)d_in[6];
  const float* Wq = (const float*)d_in[7];  const float* bq = (const float*)d_in[8];
  const float* Wk = (const float*)d_in[9];  const float* bk = (const float*)d_in[10];
  const float* Wv = (const float*)d_in[11]; const float* bv = (const float*)d_in[12];
  const float* Wo = (const float*)d_in[13]; const float* bo = (const float*)d_in[14];
  const float* W1 = (const float*)d_in[15]; const float* b1 = (const float*)d_in[16];
  const float* W2 = (const float*)d_in[17]; const float* b2 = (const float*)d_in[18];
  const float* g1 = (const float*)d_in[19]; const float* be1 = (const float*)d_in[20];
  const float* g2 = (const float*)d_in[21]; const float* be2 = (const float*)d_in[22];
  const float* emb   = (const float*)d_in[23];
  const float* W_evt = (const float*)d_in[24]; const float* b_evt = (const float*)d_in[25];
  const float* W_mm  = (const float*)d_in[26]; const float* b_mm  = (const float*)d_in[27];
  const float* W_ts  = (const float*)d_in[28]; const float* b_ts  = (const float*)d_in[29];
  const int* doyi = (const int*)d_in[30];
  const void* doym = d_in[31];

  const long TD = (long)TOK_ * D_;
  size_t need = (size_t)TD * 2 * 5
              + (size_t)(32768 + 4096 + 3072 + 21888) * 4
              + 2764800
              + 4096;
  if (ws_size < need) {
    k_beacon<<<nb, 256, 0, stream>>>((float*)d_out, out_size, (float)(ws_size >> 20));
    return;
  }

  bf* x = (bf*)d_ws;
  bf* q = x + TD;
  bf* k = q + TD;
  bf* v = k + TD;
  bf* a = v + TD;
  float* evt_h   = (float*)(a + TD);
  float* evtp    = evt_h + 32768;
  float* wevtsum = evtp + 4096;
  float* wcomb   = wevtsum + 3072;
  ushort* wprep  = (ushort*)(wcomb + 21888);

  k_prep<<<PREP_B, 256, 0, stream>>>(
      Wq, Wk, Wv, Wo, W1, W2, (unsigned*)wprep,
      var_x, marker, W_in, b_in, tod, dow, adap, x,
      doyi, emb, W_evt, b_evt, evt_h,
      W_mm, W_ts, wcomb, wevtsum);
  k_evtpool<<<16, 256, 0, stream>>>(marker, doym, evt_h, evtp);
  for (int i = 0; i < 6; ++i) {
    const ushort* pl = wprep + (size_t)i * 230400;
    /* fused QKV projection (64-tok blocks) */
    k_gemm7<152,152,3,64,1,false,false><<<TOK_/64, 512, 0, stream>>>(
        x, pl, bq + i*152, bk + i*152, bv + i*152,
        nullptr, nullptr, nullptr, q, k, v);
    if (i < 3)
      k_attn_t2<<<B_*N_, 256, 0, stream>>>(
          (const ushort*)q, (const ushort*)k, (const ushort*)v, a);
    else
      k_attn_s6<<<B_*L_*4, 512, 0, stream>>>(
          (const ushort*)q, (const ushort*)k, (const ushort*)v, a);
    /* fused Wo+LN1+FFN+LN2: x = LN2( FF(LN1(a@Wo + bo + x)) + h ) */
    k_layer3<<<TOK_/64, 512, 0, stream>>>(
        a, x, pl + 96000, pl + 128000, pl + 179200,
        bo + i*152, b1 + i*256, b2 + i*152,
        g1 + i*152, be1 + i*152, g2 + i*152, be2 + i*152, x);
  }
  k_final3<<<B_*N_, 192, 0, stream>>>(x, wcomb, wevtsum, evtp, b_mm, b_ts,
                                      (float*)d_out);
}